// Round 10
// baseline (804.267 us; speedup 1.0000x reference)
//
#include <hip/hip_runtime.h>
#include <hip/hip_bf16.h>

typedef unsigned short ushort_t;
typedef __attribute__((ext_vector_type(8))) __bf16 bf16x8;
typedef __attribute__((ext_vector_type(4))) float f32x4;
typedef __attribute__((ext_vector_type(16))) float f32x16;
typedef __attribute__((ext_vector_type(2))) unsigned u32x2;
typedef __attribute__((ext_vector_type(4))) unsigned u32x4;

#define B_ 8
#define T_ 340
#define M_ 32
#define H_ 512
#define NH_ 8
#define DH_ 64
#define INFO_ 1020
#define L_ 1084
#define LP_ 1088
#define MROWS 8672
#define MPAD 8704
#define HMLP 2048

__device__ __forceinline__ ushort_t f2bf(float f) {
  unsigned u = __builtin_bit_cast(unsigned, f);
  unsigned r = (u + 0x7fffu + ((u >> 16) & 1u)) >> 16;
  return (ushort_t)r;
}

__device__ __forceinline__ float bflo(unsigned u) {
  return __builtin_bit_cast(float, u << 16);
}
__device__ __forceinline__ float bfhi(unsigned u) {
  return __builtin_bit_cast(float, u & 0xffff0000u);
}

__device__ __forceinline__ unsigned cvtpk_bf16(float lo, float hi) {
  unsigned r;
  asm volatile("v_cvt_pk_bf16_f32 %0, %1, %2" : "=v"(r) : "v"(lo), "v"(hi));
  return r;
}

__device__ __forceinline__ void gload16(const ushort_t* g, ushort_t* l) {
  __builtin_amdgcn_global_load_lds((const __attribute__((address_space(1))) unsigned*)g,
                                   (__attribute__((address_space(3))) unsigned*)l, 16, 0, 0);
}

// ---------------- zero pads (Q/K l-pads, Vt l-pads, Ob row-pads) ----------------
__global__ __launch_bounds__(256) void zero_pads_kernel(ushort_t* Qb, ushort_t* Kb,
                                                        ushort_t* Vt, ushort_t* Ob) {
  int idx = blockIdx.x * 256 + threadIdx.x;
  if (idx < 16384) {
    int bh = idx >> 8;
    int rest = idx & 255;
    int l = L_ + (rest >> 6);
    int d = rest & 63;
    size_t o = ((size_t)bh * LP_ + l) * DH_ + d;
    Qb[o] = 0;
    Kb[o] = 0;
    Vt[((size_t)bh * DH_ + d) * LP_ + l] = 0;
  } else if (idx < 32768) {
    int j = idx - 16384;
    Ob[(size_t)MROWS * H_ + j] = 0;
  }
}

// ---------------- f32 -> bf16 convert, 8 elems/thread ----------------
__global__ __launch_bounds__(256) void cvt8_kernel(const float* __restrict__ src,
                                                   ushort_t* __restrict__ dst, int n8) {
  int i = blockIdx.x * 256 + threadIdx.x;
  if (i >= n8) return;
  f32x4 a = ((const f32x4*)src)[2 * i];
  f32x4 b = ((const f32x4*)src)[2 * i + 1];
  u32x4 o;
  o.x = cvtpk_bf16(a[0], a[1]);
  o.y = cvtpk_bf16(a[2], a[3]);
  o.z = cvtpk_bf16(b[0], b[1]);
  o.w = cvtpk_bf16(b[2], b[3]);
  ((u32x4*)dst)[i] = o;
}

// ---------------- Wq/Wk/Wv -> concatenated bf16 [nb][1536][512], 8/thread ----------
__global__ __launch_bounds__(256) void cvtqkv_kernel(const float* __restrict__ q,
                                                     const float* __restrict__ k,
                                                     const float* __restrict__ v,
                                                     ushort_t* __restrict__ dst) {
  int i8 = blockIdx.x * 256 + threadIdx.x;
  if (i8 >= 131072) return;  // 4*512*512/8
  int i = i8 * 8;
  int nb = i >> 18;
  int rem = i & 262143;
  size_t base8 = ((size_t)nb * 786432 + rem) >> 3;
  const float* srcs[3] = {q, k, v};
#pragma unroll
  for (int w = 0; w < 3; w++) {
    f32x4 a = ((const f32x4*)srcs[w])[2 * i8];
    f32x4 b = ((const f32x4*)srcs[w])[2 * i8 + 1];
    u32x4 o;
    o.x = cvtpk_bf16(a[0], a[1]);
    o.y = cvtpk_bf16(a[2], a[3]);
    o.z = cvtpk_bf16(b[0], b[1]);
    o.w = cvtpk_bf16(b[2], b[3]);
    ((u32x4*)dst)[base8 + (size_t)w * 32768] = o;  // 262144/8
  }
}

__global__ __launch_bounds__(256) void biascat_kernel(const float* __restrict__ bq,
                                                      const float* __restrict__ bk,
                                                      const float* __restrict__ bv,
                                                      float* __restrict__ dst) {
  int i = blockIdx.x * 256 + threadIdx.x;
  if (i < 2048) {
    int nb = i >> 9, r = i & 511;
    float* d = dst + nb * 1536;
    d[r] = bq[i];
    d[512 + r] = bk[i];
    d[1024 + r] = bv[i];
  }
}

// ---------------- embedding + initial LN (bf16 residual out) ----------------
__global__ __launch_bounds__(256) void embed_ln_kernel(
    const float* __restrict__ returns, const float* __restrict__ actions,
    const float* __restrict__ t_table, const float* __restrict__ s_table,
    const float* __restrict__ Wr, const float* __restrict__ br,
    const float* __restrict__ Wa, const float* __restrict__ ba,
    const float* __restrict__ g, const float* __restrict__ be,
    const float* __restrict__ read_mem, const float* __restrict__ mem_tok,
    const int* __restrict__ states, const int* __restrict__ timestep,
    ushort_t* __restrict__ Xb) {
  const int row = blockIdx.x;
  const int tid = threadIdx.x;
  if (row >= MROWS) {
    Xb[(size_t)row * H_ + tid] = 0;
    Xb[(size_t)row * H_ + tid + 256] = 0;
    return;
  }
  const int b = row / L_, l = row - b * L_;
  float v[2];
#pragma unroll
  for (int s2 = 0; s2 < 2; s2++) {
    int hh = tid + s2 * 256;
    float val;
    if (l < M_) {
      val = read_mem[(size_t)l * H_ + hh];
    } else if (l >= M_ + INFO_) {
      val = mem_tok[(size_t)(l - M_ - INFO_) * H_ + hh];
    } else {
      int ii = l - M_;
      int t = ii / 3, c = ii - t * 3;
      int bt = b * T_ + t;
      if (c == 1) {
        val = s_table[(size_t)states[bt] * H_ + hh];
      } else {
        float te = t_table[(size_t)timestep[bt] * H_ + hh];
        val = (c == 0 ? returns[bt] * Wr[hh] + br[hh] : actions[bt] * Wa[hh] + ba[hh]) + te;
      }
    }
    v[s2] = val;
  }
  float sum = v[0] + v[1], sq = v[0] * v[0] + v[1] * v[1];
  __shared__ float sa[4], sb[4];
#pragma unroll
  for (int o = 1; o < 64; o <<= 1) {
    sum += __shfl_xor(sum, o);
    sq += __shfl_xor(sq, o);
  }
  int wv = tid >> 6, lane = tid & 63;
  if (lane == 0) { sa[wv] = sum; sb[wv] = sq; }
  __syncthreads();
  sum = sa[0] + sa[1] + sa[2] + sa[3];
  sq = sb[0] + sb[1] + sb[2] + sb[3];
  float mu = sum * (1.0f / H_);
  float var = sq * (1.0f / H_) - mu * mu;
  float rstd = rsqrtf(var + 1e-5f);
#pragma unroll
  for (int s2 = 0; s2 < 2; s2++) {
    int hh = tid + s2 * 256;
    float y = (v[s2] - mu) * rstd * g[hh] + be[hh];
    Xb[(size_t)row * H_ + hh] = f2bf(y);
  }
}

// ---------------- fused residual-add + LN, bf16 in-place ----------------
__global__ __launch_bounds__(256) void ln_add_kernel(ushort_t* __restrict__ Xb,
                                                     const ushort_t* __restrict__ Y,
                                                     const float* __restrict__ g,
                                                     const float* __restrict__ be) {
  const int row = blockIdx.x;
  const int tid = threadIdx.x;
  unsigned* xr = (unsigned*)(Xb + (size_t)row * H_);
  if (row >= MROWS) {
    xr[tid] = 0;
    return;
  }
  const unsigned* yr = (const unsigned*)(Y + (size_t)row * H_);
  unsigned xu = xr[tid], yu = yr[tid];
  float v0 = bflo(xu) + bflo(yu);
  float v1 = bfhi(xu) + bfhi(yu);
  float sum = v0 + v1, sq = v0 * v0 + v1 * v1;
  __shared__ float sa[4], sb[4];
#pragma unroll
  for (int o = 1; o < 64; o <<= 1) {
    sum += __shfl_xor(sum, o);
    sq += __shfl_xor(sq, o);
  }
  int wv = tid >> 6, lane = tid & 63;
  if (lane == 0) { sa[wv] = sum; sb[wv] = sq; }
  __syncthreads();
  sum = sa[0] + sa[1] + sa[2] + sa[3];
  sq = sb[0] + sb[1] + sb[2] + sb[3];
  float mu = sum * (1.0f / H_);
  float var = sq * (1.0f / H_) - mu * mu;
  float rstd = rsqrtf(var + 1e-5f);
  float g0 = g[2 * tid], g1v = g[2 * tid + 1];
  float b0 = be[2 * tid], b1v = be[2 * tid + 1];
  float n0 = (v0 - mu) * rstd * g0 + b0;
  float n1 = (v1 - mu) * rstd * g1v + b1v;
  xr[tid] = cvtpk_bf16(n0, n1);
}

// ---------------- GEMM: 128x64 tile, BK=64, TRIPLE-buffered LDS (depth-2 prefetch),
// counted vmcnt(12), XOR swizzle, chunked XCD mapping.
// MODE 0: fused QKV, N=1536 -> Q(scaled)->(b,h,l,d), K->(b,h,l,d), V packed->(b,h,d,l)
// MODE 2: bf16 o0[m,n] = acc + bias          (Y for fused resid+LN)
// MODE 3: bf16 o0[m,n] = gelu(acc + bias), N=2048
template <int MODE>
__global__ __launch_bounds__(256, 2) void gemm_kernel(const ushort_t* __restrict__ A,
                                                      const ushort_t* __restrict__ W,
                                                      const float* __restrict__ bias,
                                                      void* __restrict__ o0,
                                                      void* __restrict__ o1,
                                                      void* __restrict__ o2, int Ntiles,
                                                      int K) {
  __shared__ ushort_t As[3][8192];
  __shared__ ushort_t Bs[3][4096];
  const int tid = threadIdx.x;
  const int job = (blockIdx.x & 7) * (gridDim.x >> 3) + (blockIdx.x >> 3);
  const int bx = job % Ntiles, by = job / Ntiles;
  const int m0 = by * 128, n0 = bx * 64;
  const int lane = tid & 63, wv = tid >> 6;
  const int wr = wv >> 1, wc = wv & 1;
  f32x4 acc[4][2] = {};

  const int srow = lane >> 3;
  const int kg = (lane & 7) ^ srow;
  const ushort_t* Asrc[4];
  const ushort_t* Bsrc[2];
#pragma unroll
  for (int g2 = 0; g2 < 4; g2++) {
    int row = wv * 32 + g2 * 8 + srow;
    Asrc[g2] = A + (size_t)(m0 + row) * K + kg * 8;
  }
#pragma unroll
  for (int g2 = 0; g2 < 2; g2++) {
    int row = wv * 16 + g2 * 8 + srow;
    Bsrc[g2] = W + (size_t)(n0 + row) * K + kg * 8;
  }

  const int NT = K >> 6;

  auto stage = [&](int kt, int buf) {
    const int k0 = kt << 6;
    ushort_t* la = &As[buf][wv * 2048];
    ushort_t* lb = &Bs[buf][wv * 1024];
#pragma unroll
    for (int g2 = 0; g2 < 4; g2++) gload16(Asrc[g2] + k0, la + g2 * 512);
#pragma unroll
    for (int g2 = 0; g2 < 2; g2++) gload16(Bsrc[g2] + k0, lb + g2 * 512);
  };

  stage(0, 0);
  if (NT > 1) stage(1, 1);

  const int q = lane >> 4, lr = lane & 15;
  const int s0 = q ^ (lr & 7);
  const int s1 = (4 + q) ^ (lr & 7);

  auto compute_tile = [&](int cur) {
    bf16x8 af[4][2], bfr[2][2];
#pragma unroll
    for (int mi = 0; mi < 4; mi++) {
      const ushort_t* rp = &As[cur][(wr * 64 + mi * 16 + lr) * 64];
      af[mi][0] = *(const bf16x8*)(rp + s0 * 8);
      af[mi][1] = *(const bf16x8*)(rp + s1 * 8);
    }
#pragma unroll
    for (int ni = 0; ni < 2; ni++) {
      const ushort_t* rp = &Bs[cur][(wc * 32 + ni * 16 + lr) * 64];
      bfr[ni][0] = *(const bf16x8*)(rp + s0 * 8);
      bfr[ni][1] = *(const bf16x8*)(rp + s1 * 8);
    }
#pragma unroll
    for (int kc = 0; kc < 2; kc++)
#pragma unroll
      for (int mi = 0; mi < 4; mi++)
#pragma unroll
        for (int ni = 0; ni < 2; ni++)
          acc[mi][ni] =
              __builtin_amdgcn_mfma_f32_16x16x32_bf16(af[mi][kc], bfr[ni][kc], acc[mi][ni], 0, 0, 0);
  };

  for (int kt = 0; kt < NT; kt++) {
    const int nxt2 = kt + 2;
    if (nxt2 < NT) stage(nxt2, nxt2 % 3);
    // wait only for the OLDEST tile's 6 loads; up to 12 stay in flight (depth-2)
    if (nxt2 < NT) {
      asm volatile("s_waitcnt vmcnt(12)" ::: "memory");
    } else if (kt + 1 < NT) {
      asm volatile("s_waitcnt vmcnt(6)" ::: "memory");
    } else {
      asm volatile("s_waitcnt vmcnt(0)" ::: "memory");
    }
    __builtin_amdgcn_s_barrier();
    asm volatile("" ::: "memory");
    compute_tile(kt % 3);
    asm volatile("" ::: "memory");
    __builtin_amdgcn_s_barrier();
  }

  // epilogue: 4-row groups are 4-aligned; L_=1084 and MROWS are multiples of 4,
  // so a group never crosses a batch boundary or the MROWS edge.
#pragma unroll
  for (int mi = 0; mi < 4; mi++) {
    const int mbase = m0 + wr * 64 + mi * 16 + ((lane >> 4) << 2);
    const bool mok = mbase < MROWS;
    int bb = 0, lbase = 0;
    if (MODE == 0) {
      bb = mbase / L_;
      lbase = mbase - bb * L_;
    }
#pragma unroll
    for (int ni = 0; ni < 2; ni++) {
      const int n = n0 + wc * 32 + ni * 16 + (lane & 15);
      float v[4];
#pragma unroll
      for (int r = 0; r < 4; r++) v[r] = acc[mi][ni][r] + bias[n];
      if (MODE == 0) {
        if (mok) {
          const int which = n >> 9, nn = n & 511;
          const int hh = nn >> 6, d = nn & 63;
          if (which == 0) {
            ushort_t* o = (ushort_t*)o0 + (((size_t)(bb * NH_ + hh)) * LP_ + lbase) * DH_ + d;
#pragma unroll
            for (int r = 0; r < 4; r++)
              o[(size_t)r * DH_] = f2bf(v[r] * 0.18033688011112043f);
          } else if (which == 1) {
            ushort_t* o = (ushort_t*)o1 + (((size_t)(bb * NH_ + hh)) * LP_ + lbase) * DH_ + d;
#pragma unroll
            for (int r = 0; r < 4; r++) o[(size_t)r * DH_] = f2bf(v[r]);
          } else {
            u32x2 w2;
            w2.x = cvtpk_bf16(v[0], v[1]);
            w2.y = cvtpk_bf16(v[2], v[3]);
            *(u32x2*)((ushort_t*)o2 + (((size_t)(bb * NH_ + hh)) * DH_ + d) * LP_ + lbase) = w2;
          }
        }
      } else if (MODE == 2) {
        if (mok) {
#pragma unroll
          for (int r = 0; r < 4; r++)
            ((ushort_t*)o0)[(size_t)(mbase + r) * H_ + n] = f2bf(v[r]);
        }
      } else {
#pragma unroll
        for (int r = 0; r < 4; r++) {
          float ge = 0.5f * v[r] * (1.0f + erff(v[r] * 0.70710678f));
          ((ushort_t*)o0)[(size_t)(mbase + r) * HMLP + n] = f2bf(ge);
        }
      }
    }
  }
}

// ---------------- flash attention v5: LDS-staged K/V, TRIPLE buffer depth-2 ----------
__global__ __launch_bounds__(256, 3) void attn_kernel(const ushort_t* __restrict__ Qb,
                                                      const ushort_t* __restrict__ Kb,
                                                      const ushort_t* __restrict__ Vt,
                                                      ushort_t* __restrict__ Ob) {
  __shared__ ushort_t Klds[3][2048];
  __shared__ ushort_t Vlds[3][2048];
  const int tid = threadIdx.x;
  const int lane = tid & 63, wv = tid >> 6;
  const int xcd = blockIdx.x & 7, slot = blockIdx.x >> 3;
  const int g = slot >> 3, bhi = slot & 7;
  const int bh = (bhi << 3) | xcd;
  const int t = 33 - 4 * g - wv;
  const bool active = (t >= 0);
  const int b = bh >> 3, h = bh & 7;
  const int qb = t * 32;
  const int lq = lane & 31, hi = lane >> 5;
  const int nk_own = active ? ((t == 33) ? 34 : (t + 1)) : 0;
  const int nkmax = (g == 0) ? 34 : (34 - 4 * g);
  const int cmask = (t == 0) ? -1 : (nk_own - 1);
  const int i = qb + lq;

  const ushort_t* Qp = Qb + (size_t)bh * LP_ * DH_;
  const ushort_t* Kp = Kb + (size_t)bh * LP_ * DH_;
  const ushort_t* Vp = Vt + (size_t)bh * DH_ * LP_;

  const ushort_t* KsrcB =
      Kp + (size_t)(8 * wv + (lane >> 3)) * DH_ + (((lane & 7) ^ ((lane >> 3) & 7)) * 8);
  const ushort_t* VsrcB =
      Vp + (size_t)(16 * wv + (lane >> 2)) * LP_ + (((lane & 3) ^ ((lane >> 3) & 3)) * 8);

  auto stageKV = [&](int c, int buf) {
    gload16(KsrcB + (size_t)c * 2048, &Klds[buf][wv * 512]);
    gload16(VsrcB + c * 32, &Vlds[buf][wv * 512]);
  };

  stageKV(0, 0);
  if (nkmax > 1) stageKV(1, 1);

  bf16x8 qf[4];
  if (active) {
#pragma unroll
    for (int dc = 0; dc < 4; dc++)
      qf[dc] = *(const bf16x8*)(Qp + (size_t)(qb + lq) * DH_ + dc * 16 + hi * 8);
  }

  f32x16 o0 = {}, o1 = {};
  float lsum = 0.f;

  int koff[4], voff[4];
#pragma unroll
  for (int dc = 0; dc < 4; dc++) koff[dc] = lq * 64 + (((dc * 2 + hi) ^ (lq & 7)) * 8);
#pragma unroll
  for (int f = 0; f < 4; f++) {
    int dt = f >> 1, cc = f & 1;
    voff[f] = (dt * 32 + lq) * 32 + ((((cc * 2 + hi) ^ ((lq >> 1) & 3))) * 8);
  }

  for (int c = 0; c < nkmax; c++) {
    const int cur = c % 3;
    const int n2 = c + 2;
    if (n2 < nkmax) stageKV(n2, n2 % 3);
    if (n2 < nkmax) {
      asm volatile("s_waitcnt vmcnt(4)" ::: "memory");
    } else if (c + 1 < nkmax) {
      asm volatile("s_waitcnt vmcnt(2)" ::: "memory");
    } else {
      asm volatile("s_waitcnt vmcnt(0)" ::: "memory");
    }
    __builtin_amdgcn_s_barrier();
    asm volatile("" ::: "memory");

    if (c < nk_own) {
      bf16x8 kf[4], vf[4];
#pragma unroll
      for (int dc = 0; dc < 4; dc++) kf[dc] = *(const bf16x8*)&Klds[cur][koff[dc]];
#pragma unroll
      for (int f = 0; f < 4; f++) vf[f] = *(const bf16x8*)&Vlds[cur][voff[f]];

      f32x16 s = {};
#pragma unroll
      for (int dc = 0; dc < 4; dc++)
        s = __builtin_amdgcn_mfma_f32_32x32x16_bf16(kf[dc], qf[dc], s, 0, 0, 0);
      float p[16];
      if (c == cmask) {
#pragma unroll
        for (int r = 0; r < 16; r++) {
          int jcol = c * 32 + (r & 3) + 8 * (r >> 2) + 4 * hi;
          bool ok = (jcol < L_) && ((jcol < M_) || (i >= M_ + INFO_) || (jcol <= i));
          p[r] = ok ? __builtin_amdgcn_exp2f(s[r]) : 0.f;
        }
      } else {
#pragma unroll
        for (int r = 0; r < 16; r++) p[r] = __builtin_amdgcn_exp2f(s[r]);
      }
      float u0 = (p[0] + p[1]) + (p[2] + p[3]);
      float u1 = (p[4] + p[5]) + (p[6] + p[7]);
      float u2 = (p[8] + p[9]) + (p[10] + p[11]);
      float u3 = (p[12] + p[13]) + (p[14] + p[15]);
      lsum += (u0 + u1) + (u2 + u3);
      bf16x8 pf[2];
#pragma unroll
      for (int cc = 0; cc < 2; cc++) {
        unsigned A01 = cvtpk_bf16(p[8 * cc + 0], p[8 * cc + 1]);
        unsigned A23 = cvtpk_bf16(p[8 * cc + 2], p[8 * cc + 3]);
        unsigned B45 = cvtpk_bf16(p[8 * cc + 4], p[8 * cc + 5]);
        unsigned B67 = cvtpk_bf16(p[8 * cc + 6], p[8 * cc + 7]);
        u32x2 r0 = __builtin_amdgcn_permlane32_swap(A01, B45, false, false);
        u32x2 r1 = __builtin_amdgcn_permlane32_swap(A23, B67, false, false);
        u32x4 w = {r0.x, r1.x, r0.y, r1.y};
        pf[cc] = __builtin_bit_cast(bf16x8, w);
      }
      o0 = __builtin_amdgcn_mfma_f32_32x32x16_bf16(vf[0], pf[0], o0, 0, 0, 0);
      o0 = __builtin_amdgcn_mfma_f32_32x32x16_bf16(vf[1], pf[1], o0, 0, 0, 0);
      o1 = __builtin_amdgcn_mfma_f32_32x32x16_bf16(vf[2], pf[0], o1, 0, 0, 0);
      o1 = __builtin_amdgcn_mfma_f32_32x32x16_bf16(vf[3], pf[1], o1, 0, 0, 0);
    }
    asm volatile("" ::: "memory");
    __builtin_amdgcn_s_barrier();
  }

  if (active) {
    u32x2 tt = __builtin_amdgcn_permlane32_swap(__builtin_bit_cast(unsigned, lsum),
                                                __builtin_bit_cast(unsigned, lsum), false, false);
    lsum = __builtin_bit_cast(float, tt.x) + __builtin_bit_cast(float, tt.y);
    if (i < L_) {
      const float inv = 1.0f / lsum;
      ushort_t* orow = Ob + ((size_t)(b * L_ + i)) * H_ + h * DH_;
#pragma unroll
      for (int dt = 0; dt < 2; dt++) {
#pragma unroll
        for (int q2 = 0; q2 < 4; q2++) {
          float v0 = (dt ? o1[4 * q2 + 0] : o0[4 * q2 + 0]) * inv;
          float v1 = (dt ? o1[4 * q2 + 1] : o0[4 * q2 + 1]) * inv;
          float v2 = (dt ? o1[4 * q2 + 2] : o0[4 * q2 + 2]) * inv;
          float v3 = (dt ? o1[4 * q2 + 3] : o0[4 * q2 + 3]) * inv;
          int dbase = dt * 32 + 8 * q2 + 4 * hi;
          *(unsigned*)(orow + dbase) = cvtpk_bf16(v0, v1);
          *(unsigned*)(orow + dbase + 2) = cvtpk_bf16(v2, v3);
        }
      }
    }
  }
}

// ---------------- heads (bf16 residual input) ----------------
__global__ __launch_bounds__(64) void logits_kernel(const ushort_t* __restrict__ Xb,
                                                    const float* __restrict__ Wp,
                                                    const float* __restrict__ bp,
                                                    float* __restrict__ out) {
  const int bt = blockIdx.x;
  const int b = bt / T_, t = bt - b * T_;
  const int lane = threadIdx.x;
  const ushort_t* xr = Xb + ((size_t)(b * L_ + M_ + 3 * t + 1)) * H_ + lane * 8;
  u32x4 xv = *(const u32x4*)xr;
  float x0[8];
#pragma unroll
  for (int ii = 0; ii < 4; ii++) {
    unsigned u = xv[ii];
    x0[2 * ii] = bflo(u);
    x0[2 * ii + 1] = bfhi(u);
  }
#pragma unroll
  for (int a = 0; a < 4; a++) {
    const float* wr2 = Wp + (size_t)a * H_ + lane * 8;
    float p = 0.f;
#pragma unroll
    for (int ii = 0; ii < 8; ii++) p += x0[ii] * wr2[ii];
#pragma unroll
    for (int o = 1; o < 64; o <<= 1) p += __shfl_xor(p, o);
    if (lane == 0) out[(size_t)bt * 4 + a] = p + bp[a];
  }
}

__global__ __launch_bounds__(256) void memout_kernel(const ushort_t* __restrict__ Xb,
                                                     float* __restrict__ out) {
  int idx = blockIdx.x * 256 + threadIdx.x;
  if (idx < B_ * M_ * H_ / 2) {
    int e = idx * 2;
    int b = e >> 14;
    int rest = e & 16383;
    int r = rest >> 9;
    int hh = rest & 511;
    unsigned u = *(const unsigned*)&Xb[((size_t)(b * L_ + M_ + INFO_ + r)) * H_ + hh];
    out[e] = bflo(u);
    out[e + 1] = bfhi(u);
  }
}

// ---------------- launcher ----------------
extern "C" void kernel_launch(void* const* d_in, const int* in_sizes, int n_in, void* d_out,
                              int out_size, void* d_ws, size_t ws_size, hipStream_t stream) {
  const float* returns = (const float*)d_in[0];
  const float* actions = (const float*)d_in[1];
  const float* t_table = (const float*)d_in[2];
  const float* s_table = (const float*)d_in[3];
  const float* Wr = (const float*)d_in[4];
  const float* br = (const float*)d_in[5];
  const float* Wa = (const float*)d_in[6];
  const float* ba = (const float*)d_in[7];
  const float* ln_e_g = (const float*)d_in[8];
  const float* ln_e_b = (const float*)d_in[9];
  const float* read_mem = (const float*)d_in[10];
  const float* mem_tok = (const float*)d_in[11];
  const float* Wq = (const float*)d_in[12];
  const float* bq = (const float*)d_in[13];
  const float* Wk = (const float*)d_in[14];
  const float* bk = (const float*)d_in[15];
  const float* Wv = (const float*)d_in[16];
  const float* bv = (const float*)d_in[17];
  const float* Wo = (const float*)d_in[18];
  const float* bo = (const float*)d_in[19];
  const float* W1 = (const float*)d_in[20];
  const float* b1 = (const float*)d_in[21];
  const float* W2 = (const float*)d_in[22];
  const float* b2 = (const float*)d_in[23];
  const float* g1 = (const float*)d_in[24];
  const float* be1 = (const float*)d_in[25];
  const float* g2 = (const float*)d_in[26];
  const float* be2 = (const float*)d_in[27];
  const float* Wp = (const float*)d_in[28];
  const float* bp = (const float*)d_in[29];
  const int* states = (const int*)d_in[30];
  const int* timestep = (const int*)d_in[31];

  char* ws = (char*)d_ws;
  size_t off = 0;
  auto alloc = [&](size_t bytes) -> char* {
    char* p = ws + off;
    off += (bytes + 255) & ~(size_t)255;
    return p;
  };
  ushort_t* Xb = (ushort_t*)alloc((size_t)MPAD * H_ * 2);
  ushort_t* Y = (ushort_t*)alloc((size_t)MPAD * H_ * 2);
  ushort_t* Qb = (ushort_t*)alloc((size_t)B_ * NH_ * LP_ * DH_ * 2);
  ushort_t* Kb2 = (ushort_t*)alloc((size_t)B_ * NH_ * LP_ * DH_ * 2);
  ushort_t* Vt = (ushort_t*)alloc((size_t)B_ * NH_ * DH_ * LP_ * 2);
  ushort_t* Ob = (ushort_t*)alloc((size_t)MPAD * H_ * 2);
  ushort_t* Hm = (ushort_t*)alloc((size_t)MPAD * HMLP * 2);
  ushort_t* Wqkvb = (ushort_t*)alloc((size_t)4 * 1536 * 512 * 2);
  ushort_t* Wob = (ushort_t*)alloc((size_t)4 * 512 * 512 * 2);
  ushort_t* W1b = (ushort_t*)alloc((size_t)4 * 2048 * 512 * 2);
  ushort_t* W2b = (ushort_t*)alloc((size_t)4 * 512 * 2048 * 2);
  float* biascat = (float*)alloc((size_t)4 * 1536 * 4);

  zero_pads_kernel<<<128, 256, 0, stream>>>(Qb, Kb2, Vt, Ob);
  cvtqkv_kernel<<<512, 256, 0, stream>>>(Wq, Wk, Wv, Wqkvb);
  biascat_kernel<<<8, 256, 0, stream>>>(bq, bk, bv, biascat);
  cvt8_kernel<<<512, 256, 0, stream>>>(Wo, Wob, 4 * 512 * 512 / 8);
  cvt8_kernel<<<2048, 256, 0, stream>>>(W1, W1b, 4 * 2048 * 512 / 8);
  cvt8_kernel<<<2048, 256, 0, stream>>>(W2, W2b, 4 * 512 * 2048 / 8);

  embed_ln_kernel<<<MPAD, 256, 0, stream>>>(returns, actions, t_table, s_table, Wr, br, Wa,
                                            ba, ln_e_g, ln_e_b, read_mem, mem_tok, states,
                                            timestep, Xb);

  for (int nb = 0; nb < 4; ++nb) {
    const size_t wo512 = (size_t)nb * 512 * 512;
    const size_t woqkv = (size_t)nb * 1536 * 512;
    const size_t wo1 = (size_t)nb * 2048 * 512;
    gemm_kernel<0><<<68 * 24, 256, 0, stream>>>(Xb, Wqkvb + woqkv, biascat + nb * 1536, Qb,
                                                Kb2, Vt, 24, 512);
    attn_kernel<<<576, 256, 0, stream>>>(Qb, Kb2, Vt, Ob);
    gemm_kernel<2><<<68 * 8, 256, 0, stream>>>(Ob, Wob + wo512, bo + nb * 512, Y, nullptr,
                                               nullptr, 8, 512);
    ln_add_kernel<<<MPAD, 256, 0, stream>>>(Xb, Y, g1 + nb * 512, be1 + nb * 512);
    gemm_kernel<3><<<68 * 32, 256, 0, stream>>>(Xb, W1b + wo1, b1 + nb * 2048, Hm, nullptr,
                                                nullptr, 32, 512);
    gemm_kernel<2><<<68 * 8, 256, 0, stream>>>(Hm, W2b + wo1, b2 + nb * 512, Y, nullptr,
                                               nullptr, 8, 2048);
    ln_add_kernel<<<MPAD, 256, 0, stream>>>(Xb, Y, g2 + nb * 512, be2 + nb * 512);
  }

  logits_kernel<<<B_ * T_, 64, 0, stream>>>(Xb, Wp, bp, (float*)d_out);
  memout_kernel<<<256, 256, 0, stream>>>(Xb, (float*)d_out + (size_t)B_ * T_ * 4);
}

// Round 11
// 701.932 us; speedup vs baseline: 1.1458x; 1.1458x over previous
//
#include <hip/hip_runtime.h>
#include <hip/hip_bf16.h>

typedef unsigned short ushort_t;
typedef __attribute__((ext_vector_type(8))) __bf16 bf16x8;
typedef __attribute__((ext_vector_type(4))) float f32x4;
typedef __attribute__((ext_vector_type(16))) float f32x16;
typedef __attribute__((ext_vector_type(2))) unsigned u32x2;
typedef __attribute__((ext_vector_type(4))) unsigned u32x4;

#define B_ 8
#define T_ 340
#define M_ 32
#define H_ 512
#define NH_ 8
#define DH_ 64
#define INFO_ 1020
#define L_ 1084
#define LP_ 1088
#define MROWS 8672
#define MPAD 8704
#define HMLP 2048

__device__ __forceinline__ ushort_t f2bf(float f) {
  unsigned u = __builtin_bit_cast(unsigned, f);
  unsigned r = (u + 0x7fffu + ((u >> 16) & 1u)) >> 16;
  return (ushort_t)r;
}

__device__ __forceinline__ float bflo(unsigned u) {
  return __builtin_bit_cast(float, u << 16);
}
__device__ __forceinline__ float bfhi(unsigned u) {
  return __builtin_bit_cast(float, u & 0xffff0000u);
}

__device__ __forceinline__ unsigned cvtpk_bf16(float lo, float hi) {
  unsigned r;
  asm volatile("v_cvt_pk_bf16_f32 %0, %1, %2" : "=v"(r) : "v"(lo), "v"(hi));
  return r;
}

__device__ __forceinline__ void gload16(const ushort_t* g, ushort_t* l) {
  __builtin_amdgcn_global_load_lds((const __attribute__((address_space(1))) unsigned*)g,
                                   (__attribute__((address_space(3))) unsigned*)l, 16, 0, 0);
}

// ---------------- zero pads (Q/K l-pads, Vt l-pads, Ob row-pads) ----------------
__global__ __launch_bounds__(256) void zero_pads_kernel(ushort_t* Qb, ushort_t* Kb,
                                                        ushort_t* Vt, ushort_t* Ob) {
  int idx = blockIdx.x * 256 + threadIdx.x;
  if (idx < 16384) {
    int bh = idx >> 8;
    int rest = idx & 255;
    int l = L_ + (rest >> 6);
    int d = rest & 63;
    size_t o = ((size_t)bh * LP_ + l) * DH_ + d;
    Qb[o] = 0;
    Kb[o] = 0;
    Vt[((size_t)bh * DH_ + d) * LP_ + l] = 0;
  } else if (idx < 32768) {
    int j = idx - 16384;
    Ob[(size_t)MROWS * H_ + j] = 0;
  }
}

// ---------------- f32 -> bf16 convert, 8 elems/thread ----------------
__global__ __launch_bounds__(256) void cvt8_kernel(const float* __restrict__ src,
                                                   ushort_t* __restrict__ dst, int n8) {
  int i = blockIdx.x * 256 + threadIdx.x;
  if (i >= n8) return;
  f32x4 a = ((const f32x4*)src)[2 * i];
  f32x4 b = ((const f32x4*)src)[2 * i + 1];
  u32x4 o;
  o.x = cvtpk_bf16(a[0], a[1]);
  o.y = cvtpk_bf16(a[2], a[3]);
  o.z = cvtpk_bf16(b[0], b[1]);
  o.w = cvtpk_bf16(b[2], b[3]);
  ((u32x4*)dst)[i] = o;
}

// ---------------- Wq/Wk/Wv -> concatenated bf16 [nb][1536][512], 8/thread ----------
__global__ __launch_bounds__(256) void cvtqkv_kernel(const float* __restrict__ q,
                                                     const float* __restrict__ k,
                                                     const float* __restrict__ v,
                                                     ushort_t* __restrict__ dst) {
  int i8 = blockIdx.x * 256 + threadIdx.x;
  if (i8 >= 131072) return;  // 4*512*512/8
  int i = i8 * 8;
  int nb = i >> 18;
  int rem = i & 262143;
  size_t base8 = ((size_t)nb * 786432 + rem) >> 3;
  const float* srcs[3] = {q, k, v};
#pragma unroll
  for (int w = 0; w < 3; w++) {
    f32x4 a = ((const f32x4*)srcs[w])[2 * i8];
    f32x4 b = ((const f32x4*)srcs[w])[2 * i8 + 1];
    u32x4 o;
    o.x = cvtpk_bf16(a[0], a[1]);
    o.y = cvtpk_bf16(a[2], a[3]);
    o.z = cvtpk_bf16(b[0], b[1]);
    o.w = cvtpk_bf16(b[2], b[3]);
    ((u32x4*)dst)[base8 + (size_t)w * 32768] = o;  // 262144/8
  }
}

__global__ __launch_bounds__(256) void biascat_kernel(const float* __restrict__ bq,
                                                      const float* __restrict__ bk,
                                                      const float* __restrict__ bv,
                                                      float* __restrict__ dst) {
  int i = blockIdx.x * 256 + threadIdx.x;
  if (i < 2048) {
    int nb = i >> 9, r = i & 511;
    float* d = dst + nb * 1536;
    d[r] = bq[i];
    d[512 + r] = bk[i];
    d[1024 + r] = bv[i];
  }
}

// ---------------- embedding + initial LN (bf16 residual out) ----------------
__global__ __launch_bounds__(256) void embed_ln_kernel(
    const float* __restrict__ returns, const float* __restrict__ actions,
    const float* __restrict__ t_table, const float* __restrict__ s_table,
    const float* __restrict__ Wr, const float* __restrict__ br,
    const float* __restrict__ Wa, const float* __restrict__ ba,
    const float* __restrict__ g, const float* __restrict__ be,
    const float* __restrict__ read_mem, const float* __restrict__ mem_tok,
    const int* __restrict__ states, const int* __restrict__ timestep,
    ushort_t* __restrict__ Xb) {
  const int row = blockIdx.x;
  const int tid = threadIdx.x;
  if (row >= MROWS) {
    Xb[(size_t)row * H_ + tid] = 0;
    Xb[(size_t)row * H_ + tid + 256] = 0;
    return;
  }
  const int b = row / L_, l = row - b * L_;
  float v[2];
#pragma unroll
  for (int s2 = 0; s2 < 2; s2++) {
    int hh = tid + s2 * 256;
    float val;
    if (l < M_) {
      val = read_mem[(size_t)l * H_ + hh];
    } else if (l >= M_ + INFO_) {
      val = mem_tok[(size_t)(l - M_ - INFO_) * H_ + hh];
    } else {
      int ii = l - M_;
      int t = ii / 3, c = ii - t * 3;
      int bt = b * T_ + t;
      if (c == 1) {
        val = s_table[(size_t)states[bt] * H_ + hh];
      } else {
        float te = t_table[(size_t)timestep[bt] * H_ + hh];
        val = (c == 0 ? returns[bt] * Wr[hh] + br[hh] : actions[bt] * Wa[hh] + ba[hh]) + te;
      }
    }
    v[s2] = val;
  }
  float sum = v[0] + v[1], sq = v[0] * v[0] + v[1] * v[1];
  __shared__ float sa[4], sb[4];
#pragma unroll
  for (int o = 1; o < 64; o <<= 1) {
    sum += __shfl_xor(sum, o);
    sq += __shfl_xor(sq, o);
  }
  int wv = tid >> 6, lane = tid & 63;
  if (lane == 0) { sa[wv] = sum; sb[wv] = sq; }
  __syncthreads();
  sum = sa[0] + sa[1] + sa[2] + sa[3];
  sq = sb[0] + sb[1] + sb[2] + sb[3];
  float mu = sum * (1.0f / H_);
  float var = sq * (1.0f / H_) - mu * mu;
  float rstd = rsqrtf(var + 1e-5f);
#pragma unroll
  for (int s2 = 0; s2 < 2; s2++) {
    int hh = tid + s2 * 256;
    float y = (v[s2] - mu) * rstd * g[hh] + be[hh];
    Xb[(size_t)row * H_ + hh] = f2bf(y);
  }
}

// ---------------- fused residual-add + LN, bf16 in-place ----------------
__global__ __launch_bounds__(256) void ln_add_kernel(ushort_t* __restrict__ Xb,
                                                     const ushort_t* __restrict__ Y,
                                                     const float* __restrict__ g,
                                                     const float* __restrict__ be) {
  const int row = blockIdx.x;
  const int tid = threadIdx.x;
  unsigned* xr = (unsigned*)(Xb + (size_t)row * H_);
  if (row >= MROWS) {
    xr[tid] = 0;
    return;
  }
  const unsigned* yr = (const unsigned*)(Y + (size_t)row * H_);
  unsigned xu = xr[tid], yu = yr[tid];
  float v0 = bflo(xu) + bflo(yu);
  float v1 = bfhi(xu) + bfhi(yu);
  float sum = v0 + v1, sq = v0 * v0 + v1 * v1;
  __shared__ float sa[4], sb[4];
#pragma unroll
  for (int o = 1; o < 64; o <<= 1) {
    sum += __shfl_xor(sum, o);
    sq += __shfl_xor(sq, o);
  }
  int wv = tid >> 6, lane = tid & 63;
  if (lane == 0) { sa[wv] = sum; sb[wv] = sq; }
  __syncthreads();
  sum = sa[0] + sa[1] + sa[2] + sa[3];
  sq = sb[0] + sb[1] + sb[2] + sb[3];
  float mu = sum * (1.0f / H_);
  float var = sq * (1.0f / H_) - mu * mu;
  float rstd = rsqrtf(var + 1e-5f);
  float g0 = g[2 * tid], g1v = g[2 * tid + 1];
  float b0 = be[2 * tid], b1v = be[2 * tid + 1];
  float n0 = (v0 - mu) * rstd * g0 + b0;
  float n1 = (v1 - mu) * rstd * g1v + b1v;
  xr[tid] = cvtpk_bf16(n0, n1);
}

// ---------------- GEMM: 128x64 tile, BK=32, QUAD-buffered LDS (depth-3 prefetch),
// 48KB LDS -> 3 blocks/CU, counted vmcnt(9), XOR swizzle, chunked XCD mapping.
// MODE 0: fused QKV, N=1536 -> Q(scaled)->(b,h,l,d), K->(b,h,l,d), V packed->(b,h,d,l)
// MODE 2: bf16 o0[m,n] = acc + bias          (Y for fused resid+LN)
// MODE 3: bf16 o0[m,n] = gelu(acc + bias), N=2048
template <int MODE>
__global__ __launch_bounds__(256, 3) void gemm_kernel(const ushort_t* __restrict__ A,
                                                      const ushort_t* __restrict__ W,
                                                      const float* __restrict__ bias,
                                                      void* __restrict__ o0,
                                                      void* __restrict__ o1,
                                                      void* __restrict__ o2, int Ntiles,
                                                      int K) {
  __shared__ ushort_t As[4][4096];  // 128 rows x 32 cols
  __shared__ ushort_t Bs[4][2048];  // 64 rows x 32 cols
  const int tid = threadIdx.x;
  const int job = (blockIdx.x & 7) * (gridDim.x >> 3) + (blockIdx.x >> 3);
  const int bx = job % Ntiles, by = job / Ntiles;
  const int m0 = by * 128, n0 = bx * 64;
  const int lane = tid & 63, wv = tid >> 6;
  const int wr = wv >> 1, wc = wv & 1;
  f32x4 acc[4][2] = {};

  // staging: rows of 32 cols = 4 x 16B slots; lane l covers row rr=l>>2 of a
  // 16-row group, LDS slot l&3; global k-chunk pre-swizzled = (l&3)^((l>>3)&3)
  const int rr = lane >> 2;
  const int kgs = (lane & 3) ^ ((lane >> 3) & 3);
  const ushort_t* Asrc0 = A + (size_t)(m0 + wv * 32 + rr) * K + kgs * 8;
  const ushort_t* Asrc1 = A + (size_t)(m0 + wv * 32 + 16 + rr) * K + kgs * 8;
  const ushort_t* Bsrc0 = W + (size_t)(n0 + wv * 16 + rr) * K + kgs * 8;

  const int NT = K >> 5;

  auto stage = [&](int kt, int buf) {
    const int k0 = kt << 5;
    gload16(Asrc0 + k0, &As[buf][(wv * 32) * 32]);
    gload16(Asrc1 + k0, &As[buf][(wv * 32 + 16) * 32]);
    gload16(Bsrc0 + k0, &Bs[buf][(wv * 16) * 32]);
  };

  stage(0, 0);
  stage(1, 1);
  stage(2, 2);

  // read-side: frag slot s = q ^ ((lr>>1)&3), uniform across mi/ni
  const int q = lane >> 4, lr = lane & 15;
  const int s = q ^ ((lr >> 1) & 3);

  auto compute_tile = [&](int cur) {
    bf16x8 af[4], bfr[2];
#pragma unroll
    for (int mi = 0; mi < 4; mi++)
      af[mi] = *(const bf16x8*)&As[cur][(wr * 64 + mi * 16 + lr) * 32 + s * 8];
#pragma unroll
    for (int ni = 0; ni < 2; ni++)
      bfr[ni] = *(const bf16x8*)&Bs[cur][(wc * 32 + ni * 16 + lr) * 32 + s * 8];
#pragma unroll
    for (int mi = 0; mi < 4; mi++)
#pragma unroll
      for (int ni = 0; ni < 2; ni++)
        acc[mi][ni] =
            __builtin_amdgcn_mfma_f32_16x16x32_bf16(af[mi], bfr[ni], acc[mi][ni], 0, 0, 0);
  };

  for (int kt = 0; kt < NT; kt++) {
    const int n3 = kt + 3;
    if (n3 < NT) {
      stage(n3, n3 & 3);
      asm volatile("s_waitcnt vmcnt(9)" ::: "memory");
    } else if (kt + 2 < NT) {
      asm volatile("s_waitcnt vmcnt(6)" ::: "memory");
    } else if (kt + 1 < NT) {
      asm volatile("s_waitcnt vmcnt(3)" ::: "memory");
    } else {
      asm volatile("s_waitcnt vmcnt(0)" ::: "memory");
    }
    __builtin_amdgcn_s_barrier();
    asm volatile("" ::: "memory");
    compute_tile(kt & 3);
    asm volatile("" ::: "memory");
    __builtin_amdgcn_s_barrier();
  }

  // epilogue: 4-row groups are 4-aligned; L_=1084 and MROWS are multiples of 4,
  // so a group never crosses a batch boundary or the MROWS edge.
#pragma unroll
  for (int mi = 0; mi < 4; mi++) {
    const int mbase = m0 + wr * 64 + mi * 16 + ((lane >> 4) << 2);
    const bool mok = mbase < MROWS;
    int bb = 0, lbase = 0;
    if (MODE == 0) {
      bb = mbase / L_;
      lbase = mbase - bb * L_;
    }
#pragma unroll
    for (int ni = 0; ni < 2; ni++) {
      const int n = n0 + wc * 32 + ni * 16 + (lane & 15);
      float v[4];
#pragma unroll
      for (int r = 0; r < 4; r++) v[r] = acc[mi][ni][r] + bias[n];
      if (MODE == 0) {
        if (mok) {
          const int which = n >> 9, nn = n & 511;
          const int hh = nn >> 6, d = nn & 63;
          if (which == 0) {
            ushort_t* o = (ushort_t*)o0 + (((size_t)(bb * NH_ + hh)) * LP_ + lbase) * DH_ + d;
#pragma unroll
            for (int r = 0; r < 4; r++)
              o[(size_t)r * DH_] = f2bf(v[r] * 0.18033688011112043f);
          } else if (which == 1) {
            ushort_t* o = (ushort_t*)o1 + (((size_t)(bb * NH_ + hh)) * LP_ + lbase) * DH_ + d;
#pragma unroll
            for (int r = 0; r < 4; r++) o[(size_t)r * DH_] = f2bf(v[r]);
          } else {
            u32x2 w2;
            w2.x = cvtpk_bf16(v[0], v[1]);
            w2.y = cvtpk_bf16(v[2], v[3]);
            *(u32x2*)((ushort_t*)o2 + (((size_t)(bb * NH_ + hh)) * DH_ + d) * LP_ + lbase) = w2;
          }
        }
      } else if (MODE == 2) {
        if (mok) {
#pragma unroll
          for (int r = 0; r < 4; r++)
            ((ushort_t*)o0)[(size_t)(mbase + r) * H_ + n] = f2bf(v[r]);
        }
      } else {
#pragma unroll
        for (int r = 0; r < 4; r++) {
          float ge = 0.5f * v[r] * (1.0f + erff(v[r] * 0.70710678f));
          ((ushort_t*)o0)[(size_t)(mbase + r) * HMLP + n] = f2bf(ge);
        }
      }
    }
  }
}

// ---------------- flash attention v5: LDS-staged K/V, TRIPLE buffer depth-2 ----------
__global__ __launch_bounds__(256, 3) void attn_kernel(const ushort_t* __restrict__ Qb,
                                                      const ushort_t* __restrict__ Kb,
                                                      const ushort_t* __restrict__ Vt,
                                                      ushort_t* __restrict__ Ob) {
  __shared__ ushort_t Klds[3][2048];
  __shared__ ushort_t Vlds[3][2048];
  const int tid = threadIdx.x;
  const int lane = tid & 63, wv = tid >> 6;
  const int xcd = blockIdx.x & 7, slot = blockIdx.x >> 3;
  const int g = slot >> 3, bhi = slot & 7;
  const int bh = (bhi << 3) | xcd;
  const int t = 33 - 4 * g - wv;
  const bool active = (t >= 0);
  const int b = bh >> 3, h = bh & 7;
  const int qb = t * 32;
  const int lq = lane & 31, hi = lane >> 5;
  const int nk_own = active ? ((t == 33) ? 34 : (t + 1)) : 0;
  const int nkmax = (g == 0) ? 34 : (34 - 4 * g);
  const int cmask = (t == 0) ? -1 : (nk_own - 1);
  const int i = qb + lq;

  const ushort_t* Qp = Qb + (size_t)bh * LP_ * DH_;
  const ushort_t* Kp = Kb + (size_t)bh * LP_ * DH_;
  const ushort_t* Vp = Vt + (size_t)bh * DH_ * LP_;

  const ushort_t* KsrcB =
      Kp + (size_t)(8 * wv + (lane >> 3)) * DH_ + (((lane & 7) ^ ((lane >> 3) & 7)) * 8);
  const ushort_t* VsrcB =
      Vp + (size_t)(16 * wv + (lane >> 2)) * LP_ + (((lane & 3) ^ ((lane >> 3) & 3)) * 8);

  auto stageKV = [&](int c, int buf) {
    gload16(KsrcB + (size_t)c * 2048, &Klds[buf][wv * 512]);
    gload16(VsrcB + c * 32, &Vlds[buf][wv * 512]);
  };

  stageKV(0, 0);
  if (nkmax > 1) stageKV(1, 1);

  bf16x8 qf[4];
  if (active) {
#pragma unroll
    for (int dc = 0; dc < 4; dc++)
      qf[dc] = *(const bf16x8*)(Qp + (size_t)(qb + lq) * DH_ + dc * 16 + hi * 8);
  }

  f32x16 o0 = {}, o1 = {};
  float lsum = 0.f;

  int koff[4], voff[4];
#pragma unroll
  for (int dc = 0; dc < 4; dc++) koff[dc] = lq * 64 + (((dc * 2 + hi) ^ (lq & 7)) * 8);
#pragma unroll
  for (int f = 0; f < 4; f++) {
    int dt = f >> 1, cc = f & 1;
    voff[f] = (dt * 32 + lq) * 32 + ((((cc * 2 + hi) ^ ((lq >> 1) & 3))) * 8);
  }

  for (int c = 0; c < nkmax; c++) {
    const int cur = c % 3;
    const int n2 = c + 2;
    if (n2 < nkmax) stageKV(n2, n2 % 3);
    if (n2 < nkmax) {
      asm volatile("s_waitcnt vmcnt(4)" ::: "memory");
    } else if (c + 1 < nkmax) {
      asm volatile("s_waitcnt vmcnt(2)" ::: "memory");
    } else {
      asm volatile("s_waitcnt vmcnt(0)" ::: "memory");
    }
    __builtin_amdgcn_s_barrier();
    asm volatile("" ::: "memory");

    if (c < nk_own) {
      bf16x8 kf[4], vf[4];
#pragma unroll
      for (int dc = 0; dc < 4; dc++) kf[dc] = *(const bf16x8*)&Klds[cur][koff[dc]];
#pragma unroll
      for (int f = 0; f < 4; f++) vf[f] = *(const bf16x8*)&Vlds[cur][voff[f]];

      f32x16 s = {};
#pragma unroll
      for (int dc = 0; dc < 4; dc++)
        s = __builtin_amdgcn_mfma_f32_32x32x16_bf16(kf[dc], qf[dc], s, 0, 0, 0);
      float p[16];
      if (c == cmask) {
#pragma unroll
        for (int r = 0; r < 16; r++) {
          int jcol = c * 32 + (r & 3) + 8 * (r >> 2) + 4 * hi;
          bool ok = (jcol < L_) && ((jcol < M_) || (i >= M_ + INFO_) || (jcol <= i));
          p[r] = ok ? __builtin_amdgcn_exp2f(s[r]) : 0.f;
        }
      } else {
#pragma unroll
        for (int r = 0; r < 16; r++) p[r] = __builtin_amdgcn_exp2f(s[r]);
      }
      float u0 = (p[0] + p[1]) + (p[2] + p[3]);
      float u1 = (p[4] + p[5]) + (p[6] + p[7]);
      float u2 = (p[8] + p[9]) + (p[10] + p[11]);
      float u3 = (p[12] + p[13]) + (p[14] + p[15]);
      lsum += (u0 + u1) + (u2 + u3);
      bf16x8 pf[2];
#pragma unroll
      for (int cc = 0; cc < 2; cc++) {
        unsigned A01 = cvtpk_bf16(p[8 * cc + 0], p[8 * cc + 1]);
        unsigned A23 = cvtpk_bf16(p[8 * cc + 2], p[8 * cc + 3]);
        unsigned B45 = cvtpk_bf16(p[8 * cc + 4], p[8 * cc + 5]);
        unsigned B67 = cvtpk_bf16(p[8 * cc + 6], p[8 * cc + 7]);
        u32x2 r0 = __builtin_amdgcn_permlane32_swap(A01, B45, false, false);
        u32x2 r1 = __builtin_amdgcn_permlane32_swap(A23, B67, false, false);
        u32x4 w = {r0.x, r1.x, r0.y, r1.y};
        pf[cc] = __builtin_bit_cast(bf16x8, w);
      }
      o0 = __builtin_amdgcn_mfma_f32_32x32x16_bf16(vf[0], pf[0], o0, 0, 0, 0);
      o0 = __builtin_amdgcn_mfma_f32_32x32x16_bf16(vf[1], pf[1], o0, 0, 0, 0);
      o1 = __builtin_amdgcn_mfma_f32_32x32x16_bf16(vf[2], pf[0], o1, 0, 0, 0);
      o1 = __builtin_amdgcn_mfma_f32_32x32x16_bf16(vf[3], pf[1], o1, 0, 0, 0);
    }
    asm volatile("" ::: "memory");
    __builtin_amdgcn_s_barrier();
  }

  if (active) {
    u32x2 tt = __builtin_amdgcn_permlane32_swap(__builtin_bit_cast(unsigned, lsum),
                                                __builtin_bit_cast(unsigned, lsum), false, false);
    lsum = __builtin_bit_cast(float, tt.x) + __builtin_bit_cast(float, tt.y);
    if (i < L_) {
      const float inv = 1.0f / lsum;
      ushort_t* orow = Ob + ((size_t)(b * L_ + i)) * H_ + h * DH_;
#pragma unroll
      for (int dt = 0; dt < 2; dt++) {
#pragma unroll
        for (int q2 = 0; q2 < 4; q2++) {
          float v0 = (dt ? o1[4 * q2 + 0] : o0[4 * q2 + 0]) * inv;
          float v1 = (dt ? o1[4 * q2 + 1] : o0[4 * q2 + 1]) * inv;
          float v2 = (dt ? o1[4 * q2 + 2] : o0[4 * q2 + 2]) * inv;
          float v3 = (dt ? o1[4 * q2 + 3] : o0[4 * q2 + 3]) * inv;
          int dbase = dt * 32 + 8 * q2 + 4 * hi;
          *(unsigned*)(orow + dbase) = cvtpk_bf16(v0, v1);
          *(unsigned*)(orow + dbase + 2) = cvtpk_bf16(v2, v3);
        }
      }
    }
  }
}

// ---------------- heads (bf16 residual input) ----------------
__global__ __launch_bounds__(64) void logits_kernel(const ushort_t* __restrict__ Xb,
                                                    const float* __restrict__ Wp,
                                                    const float* __restrict__ bp,
                                                    float* __restrict__ out) {
  const int bt = blockIdx.x;
  const int b = bt / T_, t = bt - b * T_;
  const int lane = threadIdx.x;
  const ushort_t* xr = Xb + ((size_t)(b * L_ + M_ + 3 * t + 1)) * H_ + lane * 8;
  u32x4 xv = *(const u32x4*)xr;
  float x0[8];
#pragma unroll
  for (int ii = 0; ii < 4; ii++) {
    unsigned u = xv[ii];
    x0[2 * ii] = bflo(u);
    x0[2 * ii + 1] = bfhi(u);
  }
#pragma unroll
  for (int a = 0; a < 4; a++) {
    const float* wr2 = Wp + (size_t)a * H_ + lane * 8;
    float p = 0.f;
#pragma unroll
    for (int ii = 0; ii < 8; ii++) p += x0[ii] * wr2[ii];
#pragma unroll
    for (int o = 1; o < 64; o <<= 1) p += __shfl_xor(p, o);
    if (lane == 0) out[(size_t)bt * 4 + a] = p + bp[a];
  }
}

__global__ __launch_bounds__(256) void memout_kernel(const ushort_t* __restrict__ Xb,
                                                     float* __restrict__ out) {
  int idx = blockIdx.x * 256 + threadIdx.x;
  if (idx < B_ * M_ * H_ / 2) {
    int e = idx * 2;
    int b = e >> 14;
    int rest = e & 16383;
    int r = rest >> 9;
    int hh = rest & 511;
    unsigned u = *(const unsigned*)&Xb[((size_t)(b * L_ + M_ + INFO_ + r)) * H_ + hh];
    out[e] = bflo(u);
    out[e + 1] = bfhi(u);
  }
}

// ---------------- launcher ----------------
extern "C" void kernel_launch(void* const* d_in, const int* in_sizes, int n_in, void* d_out,
                              int out_size, void* d_ws, size_t ws_size, hipStream_t stream) {
  const float* returns = (const float*)d_in[0];
  const float* actions = (const float*)d_in[1];
  const float* t_table = (const float*)d_in[2];
  const float* s_table = (const float*)d_in[3];
  const float* Wr = (const float*)d_in[4];
  const float* br = (const float*)d_in[5];
  const float* Wa = (const float*)d_in[6];
  const float* ba = (const float*)d_in[7];
  const float* ln_e_g = (const float*)d_in[8];
  const float* ln_e_b = (const float*)d_in[9];
  const float* read_mem = (const float*)d_in[10];
  const float* mem_tok = (const float*)d_in[11];
  const float* Wq = (const float*)d_in[12];
  const float* bq = (const float*)d_in[13];
  const float* Wk = (const float*)d_in[14];
  const float* bk = (const float*)d_in[15];
  const float* Wv = (const float*)d_in[16];
  const float* bv = (const float*)d_in[17];
  const float* Wo = (const float*)d_in[18];
  const float* bo = (const float*)d_in[19];
  const float* W1 = (const float*)d_in[20];
  const float* b1 = (const float*)d_in[21];
  const float* W2 = (const float*)d_in[22];
  const float* b2 = (const float*)d_in[23];
  const float* g1 = (const float*)d_in[24];
  const float* be1 = (const float*)d_in[25];
  const float* g2 = (const float*)d_in[26];
  const float* be2 = (const float*)d_in[27];
  const float* Wp = (const float*)d_in[28];
  const float* bp = (const float*)d_in[29];
  const int* states = (const int*)d_in[30];
  const int* timestep = (const int*)d_in[31];

  char* ws = (char*)d_ws;
  size_t off = 0;
  auto alloc = [&](size_t bytes) -> char* {
    char* p = ws + off;
    off += (bytes + 255) & ~(size_t)255;
    return p;
  };
  ushort_t* Xb = (ushort_t*)alloc((size_t)MPAD * H_ * 2);
  ushort_t* Y = (ushort_t*)alloc((size_t)MPAD * H_ * 2);
  ushort_t* Qb = (ushort_t*)alloc((size_t)B_ * NH_ * LP_ * DH_ * 2);
  ushort_t* Kb2 = (ushort_t*)alloc((size_t)B_ * NH_ * LP_ * DH_ * 2);
  ushort_t* Vt = (ushort_t*)alloc((size_t)B_ * NH_ * DH_ * LP_ * 2);
  ushort_t* Ob = (ushort_t*)alloc((size_t)MPAD * H_ * 2);
  ushort_t* Hm = (ushort_t*)alloc((size_t)MPAD * HMLP * 2);
  ushort_t* Wqkvb = (ushort_t*)alloc((size_t)4 * 1536 * 512 * 2);
  ushort_t* Wob = (ushort_t*)alloc((size_t)4 * 512 * 512 * 2);
  ushort_t* W1b = (ushort_t*)alloc((size_t)4 * 2048 * 512 * 2);
  ushort_t* W2b = (ushort_t*)alloc((size_t)4 * 512 * 2048 * 2);
  float* biascat = (float*)alloc((size_t)4 * 1536 * 4);

  zero_pads_kernel<<<128, 256, 0, stream>>>(Qb, Kb2, Vt, Ob);
  cvtqkv_kernel<<<512, 256, 0, stream>>>(Wq, Wk, Wv, Wqkvb);
  biascat_kernel<<<8, 256, 0, stream>>>(bq, bk, bv, biascat);
  cvt8_kernel<<<512, 256, 0, stream>>>(Wo, Wob, 4 * 512 * 512 / 8);
  cvt8_kernel<<<2048, 256, 0, stream>>>(W1, W1b, 4 * 2048 * 512 / 8);
  cvt8_kernel<<<2048, 256, 0, stream>>>(W2, W2b, 4 * 512 * 2048 / 8);

  embed_ln_kernel<<<MPAD, 256, 0, stream>>>(returns, actions, t_table, s_table, Wr, br, Wa,
                                            ba, ln_e_g, ln_e_b, read_mem, mem_tok, states,
                                            timestep, Xb);

  for (int nb = 0; nb < 4; ++nb) {
    const size_t wo512 = (size_t)nb * 512 * 512;
    const size_t woqkv = (size_t)nb * 1536 * 512;
    const size_t wo1 = (size_t)nb * 2048 * 512;
    gemm_kernel<0><<<68 * 24, 256, 0, stream>>>(Xb, Wqkvb + woqkv, biascat + nb * 1536, Qb,
                                                Kb2, Vt, 24, 512);
    attn_kernel<<<576, 256, 0, stream>>>(Qb, Kb2, Vt, Ob);
    gemm_kernel<2><<<68 * 8, 256, 0, stream>>>(Ob, Wob + wo512, bo + nb * 512, Y, nullptr,
                                               nullptr, 8, 512);
    ln_add_kernel<<<MPAD, 256, 0, stream>>>(Xb, Y, g1 + nb * 512, be1 + nb * 512);
    gemm_kernel<3><<<68 * 32, 256, 0, stream>>>(Xb, W1b + wo1, b1 + nb * 2048, Hm, nullptr,
                                                nullptr, 32, 512);
    gemm_kernel<2><<<68 * 8, 256, 0, stream>>>(Hm, W2b + wo1, b2 + nb * 512, Y, nullptr,
                                               nullptr, 8, 2048);
    ln_add_kernel<<<MPAD, 256, 0, stream>>>(Xb, Y, g2 + nb * 512, be2 + nb * 512);
  }

  logits_kernel<<<B_ * T_, 64, 0, stream>>>(Xb, Wp, bp, (float*)d_out);
  memout_kernel<<<256, 256, 0, stream>>>(Xb, (float*)d_out + (size_t)B_ * T_ * 4);
}

// Round 12
// 700.099 us; speedup vs baseline: 1.1488x; 1.0026x over previous
//
#include <hip/hip_runtime.h>
#include <hip/hip_bf16.h>

typedef unsigned short ushort_t;
typedef __attribute__((ext_vector_type(8))) __bf16 bf16x8;
typedef __attribute__((ext_vector_type(4))) float f32x4;
typedef __attribute__((ext_vector_type(16))) float f32x16;
typedef __attribute__((ext_vector_type(2))) unsigned u32x2;
typedef __attribute__((ext_vector_type(4))) unsigned u32x4;

#define B_ 8
#define T_ 340
#define M_ 32
#define H_ 512
#define NH_ 8
#define DH_ 64
#define INFO_ 1020
#define L_ 1084
#define LP_ 1088
#define MROWS 8672
#define MPAD 8704
#define HMLP 2048

__device__ __forceinline__ ushort_t f2bf(float f) {
  unsigned u = __builtin_bit_cast(unsigned, f);
  unsigned r = (u + 0x7fffu + ((u >> 16) & 1u)) >> 16;
  return (ushort_t)r;
}

__device__ __forceinline__ float bflo(unsigned u) {
  return __builtin_bit_cast(float, u << 16);
}
__device__ __forceinline__ float bfhi(unsigned u) {
  return __builtin_bit_cast(float, u & 0xffff0000u);
}

__device__ __forceinline__ unsigned cvtpk_bf16(float lo, float hi) {
  unsigned r;
  asm volatile("v_cvt_pk_bf16_f32 %0, %1, %2" : "=v"(r) : "v"(lo), "v"(hi));
  return r;
}

__device__ __forceinline__ void gload16(const ushort_t* g, ushort_t* l) {
  __builtin_amdgcn_global_load_lds((const __attribute__((address_space(1))) unsigned*)g,
                                   (__attribute__((address_space(3))) unsigned*)l, 16, 0, 0);
}

// ---------------- zero pads (Q/K l-pads, Vt l-pads, Ob row-pads) ----------------
__global__ __launch_bounds__(256) void zero_pads_kernel(ushort_t* Qb, ushort_t* Kb,
                                                        ushort_t* Vt, ushort_t* Ob) {
  int idx = blockIdx.x * 256 + threadIdx.x;
  if (idx < 16384) {
    int bh = idx >> 8;
    int rest = idx & 255;
    int l = L_ + (rest >> 6);
    int d = rest & 63;
    size_t o = ((size_t)bh * LP_ + l) * DH_ + d;
    Qb[o] = 0;
    Kb[o] = 0;
    Vt[((size_t)bh * DH_ + d) * LP_ + l] = 0;
  } else if (idx < 32768) {
    int j = idx - 16384;
    Ob[(size_t)MROWS * H_ + j] = 0;
  }
}

// ---------------- f32 -> bf16 convert, 8 elems/thread ----------------
__global__ __launch_bounds__(256) void cvt8_kernel(const float* __restrict__ src,
                                                   ushort_t* __restrict__ dst, int n8) {
  int i = blockIdx.x * 256 + threadIdx.x;
  if (i >= n8) return;
  f32x4 a = ((const f32x4*)src)[2 * i];
  f32x4 b = ((const f32x4*)src)[2 * i + 1];
  u32x4 o;
  o.x = cvtpk_bf16(a[0], a[1]);
  o.y = cvtpk_bf16(a[2], a[3]);
  o.z = cvtpk_bf16(b[0], b[1]);
  o.w = cvtpk_bf16(b[2], b[3]);
  ((u32x4*)dst)[i] = o;
}

// ---------------- Wq/Wk/Wv -> concatenated bf16 [nb][1536][512], 8/thread ----------
__global__ __launch_bounds__(256) void cvtqkv_kernel(const float* __restrict__ q,
                                                     const float* __restrict__ k,
                                                     const float* __restrict__ v,
                                                     ushort_t* __restrict__ dst) {
  int i8 = blockIdx.x * 256 + threadIdx.x;
  if (i8 >= 131072) return;  // 4*512*512/8
  int i = i8 * 8;
  int nb = i >> 18;
  int rem = i & 262143;
  size_t base8 = ((size_t)nb * 786432 + rem) >> 3;
  const float* srcs[3] = {q, k, v};
#pragma unroll
  for (int w = 0; w < 3; w++) {
    f32x4 a = ((const f32x4*)srcs[w])[2 * i8];
    f32x4 b = ((const f32x4*)srcs[w])[2 * i8 + 1];
    u32x4 o;
    o.x = cvtpk_bf16(a[0], a[1]);
    o.y = cvtpk_bf16(a[2], a[3]);
    o.z = cvtpk_bf16(b[0], b[1]);
    o.w = cvtpk_bf16(b[2], b[3]);
    ((u32x4*)dst)[base8 + (size_t)w * 32768] = o;  // 262144/8
  }
}

__global__ __launch_bounds__(256) void biascat_kernel(const float* __restrict__ bq,
                                                      const float* __restrict__ bk,
                                                      const float* __restrict__ bv,
                                                      float* __restrict__ dst) {
  int i = blockIdx.x * 256 + threadIdx.x;
  if (i < 2048) {
    int nb = i >> 9, r = i & 511;
    float* d = dst + nb * 1536;
    d[r] = bq[i];
    d[512 + r] = bk[i];
    d[1024 + r] = bv[i];
  }
}

// ---------------- embedding + initial LN (bf16 residual out) ----------------
__global__ __launch_bounds__(256) void embed_ln_kernel(
    const float* __restrict__ returns, const float* __restrict__ actions,
    const float* __restrict__ t_table, const float* __restrict__ s_table,
    const float* __restrict__ Wr, const float* __restrict__ br,
    const float* __restrict__ Wa, const float* __restrict__ ba,
    const float* __restrict__ g, const float* __restrict__ be,
    const float* __restrict__ read_mem, const float* __restrict__ mem_tok,
    const int* __restrict__ states, const int* __restrict__ timestep,
    ushort_t* __restrict__ Xb) {
  const int row = blockIdx.x;
  const int tid = threadIdx.x;
  if (row >= MROWS) {
    Xb[(size_t)row * H_ + tid] = 0;
    Xb[(size_t)row * H_ + tid + 256] = 0;
    return;
  }
  const int b = row / L_, l = row - b * L_;
  float v[2];
#pragma unroll
  for (int s2 = 0; s2 < 2; s2++) {
    int hh = tid + s2 * 256;
    float val;
    if (l < M_) {
      val = read_mem[(size_t)l * H_ + hh];
    } else if (l >= M_ + INFO_) {
      val = mem_tok[(size_t)(l - M_ - INFO_) * H_ + hh];
    } else {
      int ii = l - M_;
      int t = ii / 3, c = ii - t * 3;
      int bt = b * T_ + t;
      if (c == 1) {
        val = s_table[(size_t)states[bt] * H_ + hh];
      } else {
        float te = t_table[(size_t)timestep[bt] * H_ + hh];
        val = (c == 0 ? returns[bt] * Wr[hh] + br[hh] : actions[bt] * Wa[hh] + ba[hh]) + te;
      }
    }
    v[s2] = val;
  }
  float sum = v[0] + v[1], sq = v[0] * v[0] + v[1] * v[1];
  __shared__ float sa[4], sb[4];
#pragma unroll
  for (int o = 1; o < 64; o <<= 1) {
    sum += __shfl_xor(sum, o);
    sq += __shfl_xor(sq, o);
  }
  int wv = tid >> 6, lane = tid & 63;
  if (lane == 0) { sa[wv] = sum; sb[wv] = sq; }
  __syncthreads();
  sum = sa[0] + sa[1] + sa[2] + sa[3];
  sq = sb[0] + sb[1] + sb[2] + sb[3];
  float mu = sum * (1.0f / H_);
  float var = sq * (1.0f / H_) - mu * mu;
  float rstd = rsqrtf(var + 1e-5f);
#pragma unroll
  for (int s2 = 0; s2 < 2; s2++) {
    int hh = tid + s2 * 256;
    float y = (v[s2] - mu) * rstd * g[hh] + be[hh];
    Xb[(size_t)row * H_ + hh] = f2bf(y);
  }
}

// ---------------- fused residual-add + LN, bf16 in-place ----------------
__global__ __launch_bounds__(256) void ln_add_kernel(ushort_t* __restrict__ Xb,
                                                     const ushort_t* __restrict__ Y,
                                                     const float* __restrict__ g,
                                                     const float* __restrict__ be) {
  const int row = blockIdx.x;
  const int tid = threadIdx.x;
  unsigned* xr = (unsigned*)(Xb + (size_t)row * H_);
  if (row >= MROWS) {
    xr[tid] = 0;
    return;
  }
  const unsigned* yr = (const unsigned*)(Y + (size_t)row * H_);
  unsigned xu = xr[tid], yu = yr[tid];
  float v0 = bflo(xu) + bflo(yu);
  float v1 = bfhi(xu) + bfhi(yu);
  float sum = v0 + v1, sq = v0 * v0 + v1 * v1;
  __shared__ float sa[4], sb[4];
#pragma unroll
  for (int o = 1; o < 64; o <<= 1) {
    sum += __shfl_xor(sum, o);
    sq += __shfl_xor(sq, o);
  }
  int wv = tid >> 6, lane = tid & 63;
  if (lane == 0) { sa[wv] = sum; sb[wv] = sq; }
  __syncthreads();
  sum = sa[0] + sa[1] + sa[2] + sa[3];
  sq = sb[0] + sb[1] + sb[2] + sb[3];
  float mu = sum * (1.0f / H_);
  float var = sq * (1.0f / H_) - mu * mu;
  float rstd = rsqrtf(var + 1e-5f);
  float g0 = g[2 * tid], g1v = g[2 * tid + 1];
  float b0 = be[2 * tid], b1v = be[2 * tid + 1];
  float n0 = (v0 - mu) * rstd * g0 + b0;
  float n1 = (v1 - mu) * rstd * g1v + b1v;
  xr[tid] = cvtpk_bf16(n0, n1);
}

// ---------------- GEMM: 128x64 tile, BK=32, NB=3 (36KB -> 4 blocks/CU),
// SINGLE barrier per K-step (stage issued after barrier), counted vmcnt(3) depth-2,
// XOR swizzle, chunked XCD mapping.
// MODE 0: fused QKV, N=1536 -> Q(scaled)->(b,h,l,d), K->(b,h,l,d), V packed->(b,h,d,l)
// MODE 2: bf16 o0[m,n] = acc + bias          (Y for fused resid+LN)
// MODE 3: bf16 o0[m,n] = gelu(acc + bias), N=2048
template <int MODE>
__global__ __launch_bounds__(256, 4) void gemm_kernel(const ushort_t* __restrict__ A,
                                                      const ushort_t* __restrict__ W,
                                                      const float* __restrict__ bias,
                                                      void* __restrict__ o0,
                                                      void* __restrict__ o1,
                                                      void* __restrict__ o2, int Ntiles,
                                                      int K) {
  __shared__ ushort_t As[3][4096];  // 128 rows x 32 cols
  __shared__ ushort_t Bs[3][2048];  // 64 rows x 32 cols
  const int tid = threadIdx.x;
  const int job = (blockIdx.x & 7) * (gridDim.x >> 3) + (blockIdx.x >> 3);
  const int bx = job % Ntiles, by = job / Ntiles;
  const int m0 = by * 128, n0 = bx * 64;
  const int lane = tid & 63, wv = tid >> 6;
  const int wr = wv >> 1, wc = wv & 1;
  f32x4 acc[4][2] = {};

  // staging: rows of 32 cols = 4 x 16B slots; lane l covers row rr=l>>2 of a
  // 16-row group, LDS slot l&3; global k-chunk pre-swizzled = (l&3)^((l>>3)&3)
  const int rr = lane >> 2;
  const int kgs = (lane & 3) ^ ((lane >> 3) & 3);
  const ushort_t* Asrc0 = A + (size_t)(m0 + wv * 32 + rr) * K + kgs * 8;
  const ushort_t* Asrc1 = A + (size_t)(m0 + wv * 32 + 16 + rr) * K + kgs * 8;
  const ushort_t* Bsrc0 = W + (size_t)(n0 + wv * 16 + rr) * K + kgs * 8;

  const int NT = K >> 5;

  auto stage = [&](int kt, int buf) {
    const int k0 = kt << 5;
    gload16(Asrc0 + k0, &As[buf][(wv * 32) * 32]);
    gload16(Asrc1 + k0, &As[buf][(wv * 32 + 16) * 32]);
    gload16(Bsrc0 + k0, &Bs[buf][(wv * 16) * 32]);
  };

  stage(0, 0);
  stage(1, 1);

  // read-side: frag slot s = q ^ ((lr>>1)&3), uniform across mi/ni
  const int q = lane >> 4, lr = lane & 15;
  const int s = q ^ ((lr >> 1) & 3);

  auto compute_tile = [&](int cur) {
    bf16x8 af[4], bfr[2];
#pragma unroll
    for (int mi = 0; mi < 4; mi++)
      af[mi] = *(const bf16x8*)&As[cur][(wr * 64 + mi * 16 + lr) * 32 + s * 8];
#pragma unroll
    for (int ni = 0; ni < 2; ni++)
      bfr[ni] = *(const bf16x8*)&Bs[cur][(wc * 32 + ni * 16 + lr) * 32 + s * 8];
#pragma unroll
    for (int mi = 0; mi < 4; mi++)
#pragma unroll
      for (int ni = 0; ni < 2; ni++)
        acc[mi][ni] =
            __builtin_amdgcn_mfma_f32_16x16x32_bf16(af[mi], bfr[ni], acc[mi][ni], 0, 0, 0);
  };

  int rd = 0, wr2 = 2;
  for (int kt = 0; kt < NT; kt++) {
    // per-wave vmcnt BEFORE barrier guarantees this wave's stage(kt) landed;
    // barrier then publishes all waves' stores before any ds_read.
    if (kt < NT - 1) {
      asm volatile("s_waitcnt vmcnt(3)" ::: "memory");
    } else {
      asm volatile("s_waitcnt vmcnt(0)" ::: "memory");
    }
    __builtin_amdgcn_s_barrier();
    asm volatile("" ::: "memory");
    // stage AFTER barrier: buf[wr2] was last read in window kt-1, whose reads
    // retired (lgkmcnt before MFMA) before every wave reached this barrier.
    if (kt + 2 < NT) stage(kt + 2, wr2);
    compute_tile(rd);
    rd = (rd == 2) ? 0 : rd + 1;
    wr2 = (wr2 == 2) ? 0 : wr2 + 1;
  }

  // epilogue: 4-row groups are 4-aligned; L_=1084 and MROWS are multiples of 4,
  // so a group never crosses a batch boundary or the MROWS edge.
#pragma unroll
  for (int mi = 0; mi < 4; mi++) {
    const int mbase = m0 + wr * 64 + mi * 16 + ((lane >> 4) << 2);
    const bool mok = mbase < MROWS;
    int bb = 0, lbase = 0;
    if (MODE == 0) {
      bb = mbase / L_;
      lbase = mbase - bb * L_;
    }
#pragma unroll
    for (int ni = 0; ni < 2; ni++) {
      const int n = n0 + wc * 32 + ni * 16 + (lane & 15);
      float v[4];
#pragma unroll
      for (int r = 0; r < 4; r++) v[r] = acc[mi][ni][r] + bias[n];
      if (MODE == 0) {
        if (mok) {
          const int which = n >> 9, nn = n & 511;
          const int hh = nn >> 6, d = nn & 63;
          if (which == 0) {
            ushort_t* o = (ushort_t*)o0 + (((size_t)(bb * NH_ + hh)) * LP_ + lbase) * DH_ + d;
#pragma unroll
            for (int r = 0; r < 4; r++)
              o[(size_t)r * DH_] = f2bf(v[r] * 0.18033688011112043f);
          } else if (which == 1) {
            ushort_t* o = (ushort_t*)o1 + (((size_t)(bb * NH_ + hh)) * LP_ + lbase) * DH_ + d;
#pragma unroll
            for (int r = 0; r < 4; r++) o[(size_t)r * DH_] = f2bf(v[r]);
          } else {
            u32x2 w2;
            w2.x = cvtpk_bf16(v[0], v[1]);
            w2.y = cvtpk_bf16(v[2], v[3]);
            *(u32x2*)((ushort_t*)o2 + (((size_t)(bb * NH_ + hh)) * DH_ + d) * LP_ + lbase) = w2;
          }
        }
      } else if (MODE == 2) {
        if (mok) {
#pragma unroll
          for (int r = 0; r < 4; r++)
            ((ushort_t*)o0)[(size_t)(mbase + r) * H_ + n] = f2bf(v[r]);
        }
      } else {
#pragma unroll
        for (int r = 0; r < 4; r++) {
          float ge = 0.5f * v[r] * (1.0f + erff(v[r] * 0.70710678f));
          ((ushort_t*)o0)[(size_t)(mbase + r) * HMLP + n] = f2bf(ge);
        }
      }
    }
  }
}

// ---------------- flash attention v6: LDS K/V NB=3, single barrier per chunk ---------
__global__ __launch_bounds__(256, 4) void attn_kernel(const ushort_t* __restrict__ Qb,
                                                      const ushort_t* __restrict__ Kb,
                                                      const ushort_t* __restrict__ Vt,
                                                      ushort_t* __restrict__ Ob) {
  __shared__ ushort_t Klds[3][2048];
  __shared__ ushort_t Vlds[3][2048];
  const int tid = threadIdx.x;
  const int lane = tid & 63, wv = tid >> 6;
  const int xcd = blockIdx.x & 7, slot = blockIdx.x >> 3;
  const int g = slot >> 3, bhi = slot & 7;
  const int bh = (bhi << 3) | xcd;
  const int t = 33 - 4 * g - wv;
  const bool active = (t >= 0);
  const int b = bh >> 3, h = bh & 7;
  const int qb = t * 32;
  const int lq = lane & 31, hi = lane >> 5;
  const int nk_own = active ? ((t == 33) ? 34 : (t + 1)) : 0;
  const int nkmax = (g == 0) ? 34 : (34 - 4 * g);
  const int cmask = (t == 0) ? -1 : (nk_own - 1);
  const int i = qb + lq;

  const ushort_t* Qp = Qb + (size_t)bh * LP_ * DH_;
  const ushort_t* Kp = Kb + (size_t)bh * LP_ * DH_;
  const ushort_t* Vp = Vt + (size_t)bh * DH_ * LP_;

  // Q first so its vmem retires before the staged K/V in counter order
  bf16x8 qf[4];
  if (active) {
#pragma unroll
    for (int dc = 0; dc < 4; dc++)
      qf[dc] = *(const bf16x8*)(Qp + (size_t)(qb + lq) * DH_ + dc * 16 + hi * 8);
  }

  const ushort_t* KsrcB =
      Kp + (size_t)(8 * wv + (lane >> 3)) * DH_ + (((lane & 7) ^ ((lane >> 3) & 7)) * 8);
  const ushort_t* VsrcB =
      Vp + (size_t)(16 * wv + (lane >> 2)) * LP_ + (((lane & 3) ^ ((lane >> 3) & 3)) * 8);

  auto stageKV = [&](int c, int buf) {
    gload16(KsrcB + (size_t)c * 2048, &Klds[buf][wv * 512]);
    gload16(VsrcB + c * 32, &Vlds[buf][wv * 512]);
  };

  stageKV(0, 0);
  if (nkmax > 1) stageKV(1, 1);

  f32x16 o0 = {}, o1 = {};
  float lsum = 0.f;

  int koff[4], voff[4];
#pragma unroll
  for (int dc = 0; dc < 4; dc++) koff[dc] = lq * 64 + (((dc * 2 + hi) ^ (lq & 7)) * 8);
#pragma unroll
  for (int f = 0; f < 4; f++) {
    int dt = f >> 1, cc = f & 1;
    voff[f] = (dt * 32 + lq) * 32 + ((((cc * 2 + hi) ^ ((lq >> 1) & 3))) * 8);
  }

  int rd = 0, wr2 = 2;
  for (int c = 0; c < nkmax; c++) {
    if (c < nkmax - 1) {
      asm volatile("s_waitcnt vmcnt(2)" ::: "memory");
    } else {
      asm volatile("s_waitcnt vmcnt(0)" ::: "memory");
    }
    __builtin_amdgcn_s_barrier();
    asm volatile("" ::: "memory");
    if (c + 2 < nkmax) stageKV(c + 2, wr2);

    if (c < nk_own) {
      bf16x8 kf[4], vf[4];
#pragma unroll
      for (int dc = 0; dc < 4; dc++) kf[dc] = *(const bf16x8*)&Klds[rd][koff[dc]];
#pragma unroll
      for (int f = 0; f < 4; f++) vf[f] = *(const bf16x8*)&Vlds[rd][voff[f]];

      f32x16 s = {};
#pragma unroll
      for (int dc = 0; dc < 4; dc++)
        s = __builtin_amdgcn_mfma_f32_32x32x16_bf16(kf[dc], qf[dc], s, 0, 0, 0);
      float p[16];
      if (c == cmask) {
#pragma unroll
        for (int r = 0; r < 16; r++) {
          int jcol = c * 32 + (r & 3) + 8 * (r >> 2) + 4 * hi;
          bool ok = (jcol < L_) && ((jcol < M_) || (i >= M_ + INFO_) || (jcol <= i));
          p[r] = ok ? __builtin_amdgcn_exp2f(s[r]) : 0.f;
        }
      } else {
#pragma unroll
        for (int r = 0; r < 16; r++) p[r] = __builtin_amdgcn_exp2f(s[r]);
      }
      float u0 = (p[0] + p[1]) + (p[2] + p[3]);
      float u1 = (p[4] + p[5]) + (p[6] + p[7]);
      float u2 = (p[8] + p[9]) + (p[10] + p[11]);
      float u3 = (p[12] + p[13]) + (p[14] + p[15]);
      lsum += (u0 + u1) + (u2 + u3);
      bf16x8 pf[2];
#pragma unroll
      for (int cc = 0; cc < 2; cc++) {
        unsigned A01 = cvtpk_bf16(p[8 * cc + 0], p[8 * cc + 1]);
        unsigned A23 = cvtpk_bf16(p[8 * cc + 2], p[8 * cc + 3]);
        unsigned B45 = cvtpk_bf16(p[8 * cc + 4], p[8 * cc + 5]);
        unsigned B67 = cvtpk_bf16(p[8 * cc + 6], p[8 * cc + 7]);
        u32x2 r0 = __builtin_amdgcn_permlane32_swap(A01, B45, false, false);
        u32x2 r1 = __builtin_amdgcn_permlane32_swap(A23, B67, false, false);
        u32x4 w = {r0.x, r1.x, r0.y, r1.y};
        pf[cc] = __builtin_bit_cast(bf16x8, w);
      }
      o0 = __builtin_amdgcn_mfma_f32_32x32x16_bf16(vf[0], pf[0], o0, 0, 0, 0);
      o0 = __builtin_amdgcn_mfma_f32_32x32x16_bf16(vf[1], pf[1], o0, 0, 0, 0);
      o1 = __builtin_amdgcn_mfma_f32_32x32x16_bf16(vf[2], pf[0], o1, 0, 0, 0);
      o1 = __builtin_amdgcn_mfma_f32_32x32x16_bf16(vf[3], pf[1], o1, 0, 0, 0);
    }
    rd = (rd == 2) ? 0 : rd + 1;
    wr2 = (wr2 == 2) ? 0 : wr2 + 1;
  }

  if (active) {
    u32x2 tt = __builtin_amdgcn_permlane32_swap(__builtin_bit_cast(unsigned, lsum),
                                                __builtin_bit_cast(unsigned, lsum), false, false);
    lsum = __builtin_bit_cast(float, tt.x) + __builtin_bit_cast(float, tt.y);
    if (i < L_) {
      const float inv = 1.0f / lsum;
      ushort_t* orow = Ob + ((size_t)(b * L_ + i)) * H_ + h * DH_;
#pragma unroll
      for (int dt = 0; dt < 2; dt++) {
#pragma unroll
        for (int q2 = 0; q2 < 4; q2++) {
          float v0 = (dt ? o1[4 * q2 + 0] : o0[4 * q2 + 0]) * inv;
          float v1 = (dt ? o1[4 * q2 + 1] : o0[4 * q2 + 1]) * inv;
          float v2 = (dt ? o1[4 * q2 + 2] : o0[4 * q2 + 2]) * inv;
          float v3 = (dt ? o1[4 * q2 + 3] : o0[4 * q2 + 3]) * inv;
          int dbase = dt * 32 + 8 * q2 + 4 * hi;
          *(unsigned*)(orow + dbase) = cvtpk_bf16(v0, v1);
          *(unsigned*)(orow + dbase + 2) = cvtpk_bf16(v2, v3);
        }
      }
    }
  }
}

// ---------------- heads (bf16 residual input) ----------------
__global__ __launch_bounds__(64) void logits_kernel(const ushort_t* __restrict__ Xb,
                                                    const float* __restrict__ Wp,
                                                    const float* __restrict__ bp,
                                                    float* __restrict__ out) {
  const int bt = blockIdx.x;
  const int b = bt / T_, t = bt - b * T_;
  const int lane = threadIdx.x;
  const ushort_t* xr = Xb + ((size_t)(b * L_ + M_ + 3 * t + 1)) * H_ + lane * 8;
  u32x4 xv = *(const u32x4*)xr;
  float x0[8];
#pragma unroll
  for (int ii = 0; ii < 4; ii++) {
    unsigned u = xv[ii];
    x0[2 * ii] = bflo(u);
    x0[2 * ii + 1] = bfhi(u);
  }
#pragma unroll
  for (int a = 0; a < 4; a++) {
    const float* wr2 = Wp + (size_t)a * H_ + lane * 8;
    float p = 0.f;
#pragma unroll
    for (int ii = 0; ii < 8; ii++) p += x0[ii] * wr2[ii];
#pragma unroll
    for (int o = 1; o < 64; o <<= 1) p += __shfl_xor(p, o);
    if (lane == 0) out[(size_t)bt * 4 + a] = p + bp[a];
  }
}

__global__ __launch_bounds__(256) void memout_kernel(const ushort_t* __restrict__ Xb,
                                                     float* __restrict__ out) {
  int idx = blockIdx.x * 256 + threadIdx.x;
  if (idx < B_ * M_ * H_ / 2) {
    int e = idx * 2;
    int b = e >> 14;
    int rest = e & 16383;
    int r = rest >> 9;
    int hh = rest & 511;
    unsigned u = *(const unsigned*)&Xb[((size_t)(b * L_ + M_ + INFO_ + r)) * H_ + hh];
    out[e] = bflo(u);
    out[e + 1] = bfhi(u);
  }
}

// ---------------- launcher ----------------
extern "C" void kernel_launch(void* const* d_in, const int* in_sizes, int n_in, void* d_out,
                              int out_size, void* d_ws, size_t ws_size, hipStream_t stream) {
  const float* returns = (const float*)d_in[0];
  const float* actions = (const float*)d_in[1];
  const float* t_table = (const float*)d_in[2];
  const float* s_table = (const float*)d_in[3];
  const float* Wr = (const float*)d_in[4];
  const float* br = (const float*)d_in[5];
  const float* Wa = (const float*)d_in[6];
  const float* ba = (const float*)d_in[7];
  const float* ln_e_g = (const float*)d_in[8];
  const float* ln_e_b = (const float*)d_in[9];
  const float* read_mem = (const float*)d_in[10];
  const float* mem_tok = (const float*)d_in[11];
  const float* Wq = (const float*)d_in[12];
  const float* bq = (const float*)d_in[13];
  const float* Wk = (const float*)d_in[14];
  const float* bk = (const float*)d_in[15];
  const float* Wv = (const float*)d_in[16];
  const float* bv = (const float*)d_in[17];
  const float* Wo = (const float*)d_in[18];
  const float* bo = (const float*)d_in[19];
  const float* W1 = (const float*)d_in[20];
  const float* b1 = (const float*)d_in[21];
  const float* W2 = (const float*)d_in[22];
  const float* b2 = (const float*)d_in[23];
  const float* g1 = (const float*)d_in[24];
  const float* be1 = (const float*)d_in[25];
  const float* g2 = (const float*)d_in[26];
  const float* be2 = (const float*)d_in[27];
  const float* Wp = (const float*)d_in[28];
  const float* bp = (const float*)d_in[29];
  const int* states = (const int*)d_in[30];
  const int* timestep = (const int*)d_in[31];

  char* ws = (char*)d_ws;
  size_t off = 0;
  auto alloc = [&](size_t bytes) -> char* {
    char* p = ws + off;
    off += (bytes + 255) & ~(size_t)255;
    return p;
  };
  ushort_t* Xb = (ushort_t*)alloc((size_t)MPAD * H_ * 2);
  ushort_t* Y = (ushort_t*)alloc((size_t)MPAD * H_ * 2);
  ushort_t* Qb = (ushort_t*)alloc((size_t)B_ * NH_ * LP_ * DH_ * 2);
  ushort_t* Kb2 = (ushort_t*)alloc((size_t)B_ * NH_ * LP_ * DH_ * 2);
  ushort_t* Vt = (ushort_t*)alloc((size_t)B_ * NH_ * DH_ * LP_ * 2);
  ushort_t* Ob = (ushort_t*)alloc((size_t)MPAD * H_ * 2);
  ushort_t* Hm = (ushort_t*)alloc((size_t)MPAD * HMLP * 2);
  ushort_t* Wqkvb = (ushort_t*)alloc((size_t)4 * 1536 * 512 * 2);
  ushort_t* Wob = (ushort_t*)alloc((size_t)4 * 512 * 512 * 2);
  ushort_t* W1b = (ushort_t*)alloc((size_t)4 * 2048 * 512 * 2);
  ushort_t* W2b = (ushort_t*)alloc((size_t)4 * 512 * 2048 * 2);
  float* biascat = (float*)alloc((size_t)4 * 1536 * 4);

  zero_pads_kernel<<<128, 256, 0, stream>>>(Qb, Kb2, Vt, Ob);
  cvtqkv_kernel<<<512, 256, 0, stream>>>(Wq, Wk, Wv, Wqkvb);
  biascat_kernel<<<8, 256, 0, stream>>>(bq, bk, bv, biascat);
  cvt8_kernel<<<512, 256, 0, stream>>>(Wo, Wob, 4 * 512 * 512 / 8);
  cvt8_kernel<<<2048, 256, 0, stream>>>(W1, W1b, 4 * 2048 * 512 / 8);
  cvt8_kernel<<<2048, 256, 0, stream>>>(W2, W2b, 4 * 512 * 2048 / 8);

  embed_ln_kernel<<<MPAD, 256, 0, stream>>>(returns, actions, t_table, s_table, Wr, br, Wa,
                                            ba, ln_e_g, ln_e_b, read_mem, mem_tok, states,
                                            timestep, Xb);

  for (int nb = 0; nb < 4; ++nb) {
    const size_t wo512 = (size_t)nb * 512 * 512;
    const size_t woqkv = (size_t)nb * 1536 * 512;
    const size_t wo1 = (size_t)nb * 2048 * 512;
    gemm_kernel<0><<<68 * 24, 256, 0, stream>>>(Xb, Wqkvb + woqkv, biascat + nb * 1536, Qb,
                                                Kb2, Vt, 24, 512);
    attn_kernel<<<576, 256, 0, stream>>>(Qb, Kb2, Vt, Ob);
    gemm_kernel<2><<<68 * 8, 256, 0, stream>>>(Ob, Wob + wo512, bo + nb * 512, Y, nullptr,
                                               nullptr, 8, 512);
    ln_add_kernel<<<MPAD, 256, 0, stream>>>(Xb, Y, g1 + nb * 512, be1 + nb * 512);
    gemm_kernel<3><<<68 * 32, 256, 0, stream>>>(Xb, W1b + wo1, b1 + nb * 2048, Hm, nullptr,
                                                nullptr, 32, 512);
    gemm_kernel<2><<<68 * 8, 256, 0, stream>>>(Hm, W2b + wo1, b2 + nb * 512, Y, nullptr,
                                               nullptr, 8, 2048);
    ln_add_kernel<<<MPAD, 256, 0, stream>>>(Xb, Y, g2 + nb * 512, be2 + nb * 512);
  }

  logits_kernel<<<B_ * T_, 64, 0, stream>>>(Xb, Wp, bp, (float*)d_out);
  memout_kernel<<<256, 256, 0, stream>>>(Xb, (float*)d_out + (size_t)B_ * T_ * 4);
}

// Round 13
// 608.854 us; speedup vs baseline: 1.3210x; 1.1499x over previous
//
#include <hip/hip_runtime.h>
#include <hip/hip_bf16.h>

typedef unsigned short ushort_t;
typedef __attribute__((ext_vector_type(8))) __bf16 bf16x8;
typedef __attribute__((ext_vector_type(4))) float f32x4;
typedef __attribute__((ext_vector_type(16))) float f32x16;
typedef __attribute__((ext_vector_type(2))) unsigned u32x2;
typedef __attribute__((ext_vector_type(4))) unsigned u32x4;

#define B_ 8
#define T_ 340
#define M_ 32
#define H_ 512
#define NH_ 8
#define DH_ 64
#define INFO_ 1020
#define L_ 1084
#define LP_ 1088
#define MROWS 8672
#define MPAD 8704
#define HMLP 2048

__device__ __forceinline__ ushort_t f2bf(float f) {
  unsigned u = __builtin_bit_cast(unsigned, f);
  unsigned r = (u + 0x7fffu + ((u >> 16) & 1u)) >> 16;
  return (ushort_t)r;
}

__device__ __forceinline__ float bflo(unsigned u) {
  return __builtin_bit_cast(float, u << 16);
}
__device__ __forceinline__ float bfhi(unsigned u) {
  return __builtin_bit_cast(float, u & 0xffff0000u);
}

__device__ __forceinline__ unsigned cvtpk_bf16(float lo, float hi) {
  unsigned r;
  asm volatile("v_cvt_pk_bf16_f32 %0, %1, %2" : "=v"(r) : "v"(lo), "v"(hi));
  return r;
}

__device__ __forceinline__ void gload16(const ushort_t* g, ushort_t* l) {
  __builtin_amdgcn_global_load_lds((const __attribute__((address_space(1))) unsigned*)g,
                                   (__attribute__((address_space(3))) unsigned*)l, 16, 0, 0);
}

// ---------------- zero pads (Q/K l-pads, Vt l-pads, Ob row-pads) ----------------
__global__ __launch_bounds__(256) void zero_pads_kernel(ushort_t* Qb, ushort_t* Kb,
                                                        ushort_t* Vt, ushort_t* Ob) {
  int idx = blockIdx.x * 256 + threadIdx.x;
  if (idx < 16384) {
    int bh = idx >> 8;
    int rest = idx & 255;
    int l = L_ + (rest >> 6);
    int d = rest & 63;
    size_t o = ((size_t)bh * LP_ + l) * DH_ + d;
    Qb[o] = 0;
    Kb[o] = 0;
    Vt[((size_t)bh * DH_ + d) * LP_ + l] = 0;
  } else if (idx < 32768) {
    int j = idx - 16384;
    Ob[(size_t)MROWS * H_ + j] = 0;
  }
}

// ---------------- f32 -> bf16 convert, 8 elems/thread ----------------
__global__ __launch_bounds__(256) void cvt8_kernel(const float* __restrict__ src,
                                                   ushort_t* __restrict__ dst, int n8) {
  int i = blockIdx.x * 256 + threadIdx.x;
  if (i >= n8) return;
  f32x4 a = ((const f32x4*)src)[2 * i];
  f32x4 b = ((const f32x4*)src)[2 * i + 1];
  u32x4 o;
  o.x = cvtpk_bf16(a[0], a[1]);
  o.y = cvtpk_bf16(a[2], a[3]);
  o.z = cvtpk_bf16(b[0], b[1]);
  o.w = cvtpk_bf16(b[2], b[3]);
  ((u32x4*)dst)[i] = o;
}

// ---------------- Wq/Wk/Wv -> concatenated bf16 [nb][1536][512], 8/thread ----------
__global__ __launch_bounds__(256) void cvtqkv_kernel(const float* __restrict__ q,
                                                     const float* __restrict__ k,
                                                     const float* __restrict__ v,
                                                     ushort_t* __restrict__ dst) {
  int i8 = blockIdx.x * 256 + threadIdx.x;
  if (i8 >= 131072) return;  // 4*512*512/8
  int i = i8 * 8;
  int nb = i >> 18;
  int rem = i & 262143;
  size_t base8 = ((size_t)nb * 786432 + rem) >> 3;
  const float* srcs[3] = {q, k, v};
#pragma unroll
  for (int w = 0; w < 3; w++) {
    f32x4 a = ((const f32x4*)srcs[w])[2 * i8];
    f32x4 b = ((const f32x4*)srcs[w])[2 * i8 + 1];
    u32x4 o;
    o.x = cvtpk_bf16(a[0], a[1]);
    o.y = cvtpk_bf16(a[2], a[3]);
    o.z = cvtpk_bf16(b[0], b[1]);
    o.w = cvtpk_bf16(b[2], b[3]);
    ((u32x4*)dst)[base8 + (size_t)w * 32768] = o;  // 262144/8
  }
}

__global__ __launch_bounds__(256) void biascat_kernel(const float* __restrict__ bq,
                                                      const float* __restrict__ bk,
                                                      const float* __restrict__ bv,
                                                      float* __restrict__ dst) {
  int i = blockIdx.x * 256 + threadIdx.x;
  if (i < 2048) {
    int nb = i >> 9, r = i & 511;
    float* d = dst + nb * 1536;
    d[r] = bq[i];
    d[512 + r] = bk[i];
    d[1024 + r] = bv[i];
  }
}

// ---------------- embedding + initial LN (bf16 residual out) ----------------
__global__ __launch_bounds__(256) void embed_ln_kernel(
    const float* __restrict__ returns, const float* __restrict__ actions,
    const float* __restrict__ t_table, const float* __restrict__ s_table,
    const float* __restrict__ Wr, const float* __restrict__ br,
    const float* __restrict__ Wa, const float* __restrict__ ba,
    const float* __restrict__ g, const float* __restrict__ be,
    const float* __restrict__ read_mem, const float* __restrict__ mem_tok,
    const int* __restrict__ states, const int* __restrict__ timestep,
    ushort_t* __restrict__ Xb) {
  const int row = blockIdx.x;
  const int tid = threadIdx.x;
  if (row >= MROWS) {
    Xb[(size_t)row * H_ + tid] = 0;
    Xb[(size_t)row * H_ + tid + 256] = 0;
    return;
  }
  const int b = row / L_, l = row - b * L_;
  float v[2];
#pragma unroll
  for (int s2 = 0; s2 < 2; s2++) {
    int hh = tid + s2 * 256;
    float val;
    if (l < M_) {
      val = read_mem[(size_t)l * H_ + hh];
    } else if (l >= M_ + INFO_) {
      val = mem_tok[(size_t)(l - M_ - INFO_) * H_ + hh];
    } else {
      int ii = l - M_;
      int t = ii / 3, c = ii - t * 3;
      int bt = b * T_ + t;
      if (c == 1) {
        val = s_table[(size_t)states[bt] * H_ + hh];
      } else {
        float te = t_table[(size_t)timestep[bt] * H_ + hh];
        val = (c == 0 ? returns[bt] * Wr[hh] + br[hh] : actions[bt] * Wa[hh] + ba[hh]) + te;
      }
    }
    v[s2] = val;
  }
  float sum = v[0] + v[1], sq = v[0] * v[0] + v[1] * v[1];
  __shared__ float sa[4], sb[4];
#pragma unroll
  for (int o = 1; o < 64; o <<= 1) {
    sum += __shfl_xor(sum, o);
    sq += __shfl_xor(sq, o);
  }
  int wv = tid >> 6, lane = tid & 63;
  if (lane == 0) { sa[wv] = sum; sb[wv] = sq; }
  __syncthreads();
  sum = sa[0] + sa[1] + sa[2] + sa[3];
  sq = sb[0] + sb[1] + sb[2] + sb[3];
  float mu = sum * (1.0f / H_);
  float var = sq * (1.0f / H_) - mu * mu;
  float rstd = rsqrtf(var + 1e-5f);
#pragma unroll
  for (int s2 = 0; s2 < 2; s2++) {
    int hh = tid + s2 * 256;
    float y = (v[s2] - mu) * rstd * g[hh] + be[hh];
    Xb[(size_t)row * H_ + hh] = f2bf(y);
  }
}

// ---------------- fused residual-add + LN, bf16 in-place ----------------
__global__ __launch_bounds__(256) void ln_add_kernel(ushort_t* __restrict__ Xb,
                                                     const ushort_t* __restrict__ Y,
                                                     const float* __restrict__ g,
                                                     const float* __restrict__ be) {
  const int row = blockIdx.x;
  const int tid = threadIdx.x;
  unsigned* xr = (unsigned*)(Xb + (size_t)row * H_);
  if (row >= MROWS) {
    xr[tid] = 0;
    return;
  }
  const unsigned* yr = (const unsigned*)(Y + (size_t)row * H_);
  unsigned xu = xr[tid], yu = yr[tid];
  float v0 = bflo(xu) + bflo(yu);
  float v1 = bfhi(xu) + bfhi(yu);
  float sum = v0 + v1, sq = v0 * v0 + v1 * v1;
  __shared__ float sa[4], sb[4];
#pragma unroll
  for (int o = 1; o < 64; o <<= 1) {
    sum += __shfl_xor(sum, o);
    sq += __shfl_xor(sq, o);
  }
  int wv = tid >> 6, lane = tid & 63;
  if (lane == 0) { sa[wv] = sum; sb[wv] = sq; }
  __syncthreads();
  sum = sa[0] + sa[1] + sa[2] + sa[3];
  sq = sb[0] + sb[1] + sb[2] + sb[3];
  float mu = sum * (1.0f / H_);
  float var = sq * (1.0f / H_) - mu * mu;
  float rstd = rsqrtf(var + 1e-5f);
  float g0 = g[2 * tid], g1v = g[2 * tid + 1];
  float b0 = be[2 * tid], b1v = be[2 * tid + 1];
  float n0 = (v0 - mu) * rstd * g0 + b0;
  float n1 = (v1 - mu) * rstd * g1v + b1v;
  xr[tid] = cvtpk_bf16(n0, n1);
}

// ---------------- GEMM (round-9 config): 128x64 tile, BK=64, dbuf LDS, counted
// vmcnt(6), XOR swizzle, chunked XCD mapping, 48KB -> 3 blocks/CU.
// MODE 0: fused QKV, N=1536 -> Q(scaled)->(b,h,l,d), K->(b,h,l,d), V packed->(b,h,d,l)
// MODE 2: bf16 o0[m,n] = acc + bias          (Y for fused resid+LN)
// MODE 3: bf16 o0[m,n] = gelu(acc + bias), N=2048
template <int MODE>
__global__ __launch_bounds__(256, 3) void gemm_kernel(const ushort_t* __restrict__ A,
                                                      const ushort_t* __restrict__ W,
                                                      const float* __restrict__ bias,
                                                      void* __restrict__ o0,
                                                      void* __restrict__ o1,
                                                      void* __restrict__ o2, int Ntiles,
                                                      int K) {
  __shared__ ushort_t As[2][8192];
  __shared__ ushort_t Bs[2][4096];
  const int tid = threadIdx.x;
  const int job = (blockIdx.x & 7) * (gridDim.x >> 3) + (blockIdx.x >> 3);
  const int bx = job % Ntiles, by = job / Ntiles;
  const int m0 = by * 128, n0 = bx * 64;
  const int lane = tid & 63, wv = tid >> 6;
  const int wr = wv >> 1, wc = wv & 1;
  f32x4 acc[4][2] = {};

  const int srow = lane >> 3;
  const int kg = (lane & 7) ^ srow;
  const ushort_t* Asrc[4];
  const ushort_t* Bsrc[2];
#pragma unroll
  for (int g2 = 0; g2 < 4; g2++) {
    int row = wv * 32 + g2 * 8 + srow;
    Asrc[g2] = A + (size_t)(m0 + row) * K + kg * 8;
  }
#pragma unroll
  for (int g2 = 0; g2 < 2; g2++) {
    int row = wv * 16 + g2 * 8 + srow;
    Bsrc[g2] = W + (size_t)(n0 + row) * K + kg * 8;
  }
  ushort_t* ldsA[2] = {&As[0][wv * 2048], &As[1][wv * 2048]};
  ushort_t* ldsB[2] = {&Bs[0][wv * 1024], &Bs[1][wv * 1024]};

  const int NT = K >> 6;

#pragma unroll
  for (int g2 = 0; g2 < 4; g2++) gload16(Asrc[g2], ldsA[0] + g2 * 512);
#pragma unroll
  for (int g2 = 0; g2 < 2; g2++) gload16(Bsrc[g2], ldsB[0] + g2 * 512);

  const int q = lane >> 4, lr = lane & 15;
  const int s0 = q ^ (lr & 7);
  const int s1 = (4 + q) ^ (lr & 7);

  auto compute_tile = [&](int cur) {
    bf16x8 af[4][2], bfr[2][2];
#pragma unroll
    for (int mi = 0; mi < 4; mi++) {
      const ushort_t* rp = &As[cur][(wr * 64 + mi * 16 + lr) * 64];
      af[mi][0] = *(const bf16x8*)(rp + s0 * 8);
      af[mi][1] = *(const bf16x8*)(rp + s1 * 8);
    }
#pragma unroll
    for (int ni = 0; ni < 2; ni++) {
      const ushort_t* rp = &Bs[cur][(wc * 32 + ni * 16 + lr) * 64];
      bfr[ni][0] = *(const bf16x8*)(rp + s0 * 8);
      bfr[ni][1] = *(const bf16x8*)(rp + s1 * 8);
    }
#pragma unroll
    for (int kc = 0; kc < 2; kc++)
#pragma unroll
      for (int mi = 0; mi < 4; mi++)
#pragma unroll
        for (int ni = 0; ni < 2; ni++)
          acc[mi][ni] =
              __builtin_amdgcn_mfma_f32_16x16x32_bf16(af[mi][kc], bfr[ni][kc], acc[mi][ni], 0, 0, 0);
  };

  for (int kt = 0; kt < NT - 1; kt++) {
    const int cur = kt & 1, nxt = cur ^ 1;
    const int k0n = (kt + 1) << 6;
#pragma unroll
    for (int g2 = 0; g2 < 4; g2++) gload16(Asrc[g2] + k0n, ldsA[nxt] + g2 * 512);
#pragma unroll
    for (int g2 = 0; g2 < 2; g2++) gload16(Bsrc[g2] + k0n, ldsB[nxt] + g2 * 512);
    asm volatile("s_waitcnt vmcnt(6)" ::: "memory");
    __builtin_amdgcn_s_barrier();
    asm volatile("" ::: "memory");
    compute_tile(cur);
    asm volatile("" ::: "memory");
    __builtin_amdgcn_s_barrier();
  }
  {
    asm volatile("s_waitcnt vmcnt(0)" ::: "memory");
    __builtin_amdgcn_s_barrier();
    asm volatile("" ::: "memory");
    compute_tile((NT - 1) & 1);
  }

  // epilogue: 4-row groups are 4-aligned; L_=1084 and MROWS are multiples of 4,
  // so a group never crosses a batch boundary or the MROWS edge.
#pragma unroll
  for (int mi = 0; mi < 4; mi++) {
    const int mbase = m0 + wr * 64 + mi * 16 + ((lane >> 4) << 2);
    const bool mok = mbase < MROWS;
    int bb = 0, lbase = 0;
    if (MODE == 0) {
      bb = mbase / L_;
      lbase = mbase - bb * L_;
    }
#pragma unroll
    for (int ni = 0; ni < 2; ni++) {
      const int n = n0 + wc * 32 + ni * 16 + (lane & 15);
      float v[4];
#pragma unroll
      for (int r = 0; r < 4; r++) v[r] = acc[mi][ni][r] + bias[n];
      if (MODE == 0) {
        if (mok) {
          const int which = n >> 9, nn = n & 511;
          const int hh = nn >> 6, d = nn & 63;
          if (which == 0) {
            ushort_t* o = (ushort_t*)o0 + (((size_t)(bb * NH_ + hh)) * LP_ + lbase) * DH_ + d;
#pragma unroll
            for (int r = 0; r < 4; r++)
              o[(size_t)r * DH_] = f2bf(v[r] * 0.18033688011112043f);
          } else if (which == 1) {
            ushort_t* o = (ushort_t*)o1 + (((size_t)(bb * NH_ + hh)) * LP_ + lbase) * DH_ + d;
#pragma unroll
            for (int r = 0; r < 4; r++) o[(size_t)r * DH_] = f2bf(v[r]);
          } else {
            u32x2 w2;
            w2.x = cvtpk_bf16(v[0], v[1]);
            w2.y = cvtpk_bf16(v[2], v[3]);
            *(u32x2*)((ushort_t*)o2 + (((size_t)(bb * NH_ + hh)) * DH_ + d) * LP_ + lbase) = w2;
          }
        }
      } else if (MODE == 2) {
        if (mok) {
#pragma unroll
          for (int r = 0; r < 4; r++)
            ((ushort_t*)o0)[(size_t)(mbase + r) * H_ + n] = f2bf(v[r]);
        }
      } else {
#pragma unroll
        for (int r = 0; r < 4; r++) {
          float ge = 0.5f * v[r] * (1.0f + erff(v[r] * 0.70710678f));
          ((ushort_t*)o0)[(size_t)(mbase + r) * HMLP + n] = f2bf(ge);
        }
      }
    }
  }
}

// ---------------- flash attention v7: KVBLK=64 — chunk PAIRS per barrier window ----
// Block = 4 waves, ONE bh, 4 consecutive q-tiles. Each window stages 64 K-rows +
// 64 V-cols (4 gloads/wave), vmcnt(4) counted, then TWO tilesteps (16 MFMA).
// nkmax = 34-4g is always even -> every window is a full pair.
__global__ __launch_bounds__(256, 3) void attn_kernel(const ushort_t* __restrict__ Qb,
                                                      const ushort_t* __restrict__ Kb,
                                                      const ushort_t* __restrict__ Vt,
                                                      ushort_t* __restrict__ Ob) {
  __shared__ ushort_t Klds[2][4096];  // [buf][half 2048]: 32 rows x 64, swizzled
  __shared__ ushort_t Vlds[2][4096];  // [buf][half 2048]: 64 rows x 32, swizzled
  const int tid = threadIdx.x;
  const int lane = tid & 63, wv = tid >> 6;
  const int xcd = blockIdx.x & 7, slot = blockIdx.x >> 3;
  const int g = slot >> 3, bhi = slot & 7;
  const int bh = (bhi << 3) | xcd;
  const int t = 33 - 4 * g - wv;
  const bool active = (t >= 0);
  const int b = bh >> 3, h = bh & 7;
  const int qb = t * 32;
  const int lq = lane & 31, hi = lane >> 5;
  const int nk_own = active ? ((t == 33) ? 34 : (t + 1)) : 0;
  const int nkmax = (g == 0) ? 34 : (34 - 4 * g);  // always even
  const int nw = nkmax >> 1;
  const int cmask = (t == 0) ? -1 : (nk_own - 1);
  const int i = qb + lq;

  const ushort_t* Qp = Qb + (size_t)bh * LP_ * DH_;
  const ushort_t* Kp = Kb + (size_t)bh * LP_ * DH_;
  const ushort_t* Vp = Vt + (size_t)bh * DH_ * LP_;

  const ushort_t* KsrcB =
      Kp + (size_t)(8 * wv + (lane >> 3)) * DH_ + (((lane & 7) ^ ((lane >> 3) & 7)) * 8);
  const ushort_t* VsrcB =
      Vp + (size_t)(16 * wv + (lane >> 2)) * LP_ + (((lane & 3) ^ ((lane >> 3) & 3)) * 8);

  auto stageW = [&](int w, int buf) {
    const int c0 = 2 * w;
    gload16(KsrcB + (size_t)c0 * 2048, &Klds[buf][wv * 512]);
    gload16(KsrcB + (size_t)(c0 + 1) * 2048, &Klds[buf][2048 + wv * 512]);
    gload16(VsrcB + c0 * 32, &Vlds[buf][wv * 512]);
    gload16(VsrcB + (c0 + 1) * 32, &Vlds[buf][2048 + wv * 512]);
  };

  bf16x8 qf[4];
  if (active) {
#pragma unroll
    for (int dc = 0; dc < 4; dc++)
      qf[dc] = *(const bf16x8*)(Qp + (size_t)(qb + lq) * DH_ + dc * 16 + hi * 8);
  }

  stageW(0, 0);

  f32x16 o0 = {}, o1 = {};
  float lsum = 0.f;

  int koff[4], voff[4];
#pragma unroll
  for (int dc = 0; dc < 4; dc++) koff[dc] = lq * 64 + (((dc * 2 + hi) ^ (lq & 7)) * 8);
#pragma unroll
  for (int f = 0; f < 4; f++) {
    int dt = f >> 1, cc = f & 1;
    voff[f] = (dt * 32 + lq) * 32 + ((((cc * 2 + hi) ^ ((lq >> 1) & 3))) * 8);
  }

  auto tilestep = [&](int c, const ushort_t* Kbase, const ushort_t* Vbase) {
    bf16x8 kf[4], vf[4];
#pragma unroll
    for (int dc = 0; dc < 4; dc++) kf[dc] = *(const bf16x8*)&Kbase[koff[dc]];
#pragma unroll
    for (int f = 0; f < 4; f++) vf[f] = *(const bf16x8*)&Vbase[voff[f]];

    f32x16 s = {};
#pragma unroll
    for (int dc = 0; dc < 4; dc++)
      s = __builtin_amdgcn_mfma_f32_32x32x16_bf16(kf[dc], qf[dc], s, 0, 0, 0);
    float p[16];
    if (c == cmask) {
#pragma unroll
      for (int r = 0; r < 16; r++) {
        int jcol = c * 32 + (r & 3) + 8 * (r >> 2) + 4 * hi;
        bool ok = (jcol < L_) && ((jcol < M_) || (i >= M_ + INFO_) || (jcol <= i));
        p[r] = ok ? __builtin_amdgcn_exp2f(s[r]) : 0.f;
      }
    } else {
#pragma unroll
      for (int r = 0; r < 16; r++) p[r] = __builtin_amdgcn_exp2f(s[r]);
    }
    float u0 = (p[0] + p[1]) + (p[2] + p[3]);
    float u1 = (p[4] + p[5]) + (p[6] + p[7]);
    float u2 = (p[8] + p[9]) + (p[10] + p[11]);
    float u3 = (p[12] + p[13]) + (p[14] + p[15]);
    lsum += (u0 + u1) + (u2 + u3);
    bf16x8 pf[2];
#pragma unroll
    for (int cc = 0; cc < 2; cc++) {
      unsigned A01 = cvtpk_bf16(p[8 * cc + 0], p[8 * cc + 1]);
      unsigned A23 = cvtpk_bf16(p[8 * cc + 2], p[8 * cc + 3]);
      unsigned B45 = cvtpk_bf16(p[8 * cc + 4], p[8 * cc + 5]);
      unsigned B67 = cvtpk_bf16(p[8 * cc + 6], p[8 * cc + 7]);
      u32x2 r0 = __builtin_amdgcn_permlane32_swap(A01, B45, false, false);
      u32x2 r1 = __builtin_amdgcn_permlane32_swap(A23, B67, false, false);
      u32x4 w = {r0.x, r1.x, r0.y, r1.y};
      pf[cc] = __builtin_bit_cast(bf16x8, w);
    }
    o0 = __builtin_amdgcn_mfma_f32_32x32x16_bf16(vf[0], pf[0], o0, 0, 0, 0);
    o0 = __builtin_amdgcn_mfma_f32_32x32x16_bf16(vf[1], pf[1], o0, 0, 0, 0);
    o1 = __builtin_amdgcn_mfma_f32_32x32x16_bf16(vf[2], pf[0], o1, 0, 0, 0);
    o1 = __builtin_amdgcn_mfma_f32_32x32x16_bf16(vf[3], pf[1], o1, 0, 0, 0);
  };

  for (int w = 0; w < nw; w++) {
    const int cur = w & 1;
    if (w + 1 < nw) {
      stageW(w + 1, cur ^ 1);
      asm volatile("s_waitcnt vmcnt(4)" ::: "memory");
    } else {
      asm volatile("s_waitcnt vmcnt(0)" ::: "memory");
    }
    __builtin_amdgcn_s_barrier();
    asm volatile("" ::: "memory");

    const int c0 = 2 * w;
    if (c0 < nk_own) tilestep(c0, &Klds[cur][0], &Vlds[cur][0]);
    if (c0 + 1 < nk_own) tilestep(c0 + 1, &Klds[cur][2048], &Vlds[cur][2048]);

    asm volatile("" ::: "memory");
    __builtin_amdgcn_s_barrier();
  }

  if (active) {
    u32x2 tt = __builtin_amdgcn_permlane32_swap(__builtin_bit_cast(unsigned, lsum),
                                                __builtin_bit_cast(unsigned, lsum), false, false);
    lsum = __builtin_bit_cast(float, tt.x) + __builtin_bit_cast(float, tt.y);
    if (i < L_) {
      const float inv = 1.0f / lsum;
      ushort_t* orow = Ob + ((size_t)(b * L_ + i)) * H_ + h * DH_;
#pragma unroll
      for (int dt = 0; dt < 2; dt++) {
#pragma unroll
        for (int q2 = 0; q2 < 4; q2++) {
          float v0 = (dt ? o1[4 * q2 + 0] : o0[4 * q2 + 0]) * inv;
          float v1 = (dt ? o1[4 * q2 + 1] : o0[4 * q2 + 1]) * inv;
          float v2 = (dt ? o1[4 * q2 + 2] : o0[4 * q2 + 2]) * inv;
          float v3 = (dt ? o1[4 * q2 + 3] : o0[4 * q2 + 3]) * inv;
          int dbase = dt * 32 + 8 * q2 + 4 * hi;
          *(unsigned*)(orow + dbase) = cvtpk_bf16(v0, v1);
          *(unsigned*)(orow + dbase + 2) = cvtpk_bf16(v2, v3);
        }
      }
    }
  }
}

// ---------------- heads (bf16 residual input) ----------------
__global__ __launch_bounds__(64) void logits_kernel(const ushort_t* __restrict__ Xb,
                                                    const float* __restrict__ Wp,
                                                    const float* __restrict__ bp,
                                                    float* __restrict__ out) {
  const int bt = blockIdx.x;
  const int b = bt / T_, t = bt - b * T_;
  const int lane = threadIdx.x;
  const ushort_t* xr = Xb + ((size_t)(b * L_ + M_ + 3 * t + 1)) * H_ + lane * 8;
  u32x4 xv = *(const u32x4*)xr;
  float x0[8];
#pragma unroll
  for (int ii = 0; ii < 4; ii++) {
    unsigned u = xv[ii];
    x0[2 * ii] = bflo(u);
    x0[2 * ii + 1] = bfhi(u);
  }
#pragma unroll
  for (int a = 0; a < 4; a++) {
    const float* wr2 = Wp + (size_t)a * H_ + lane * 8;
    float p = 0.f;
#pragma unroll
    for (int ii = 0; ii < 8; ii++) p += x0[ii] * wr2[ii];
#pragma unroll
    for (int o = 1; o < 64; o <<= 1) p += __shfl_xor(p, o);
    if (lane == 0) out[(size_t)bt * 4 + a] = p + bp[a];
  }
}

__global__ __launch_bounds__(256) void memout_kernel(const ushort_t* __restrict__ Xb,
                                                     float* __restrict__ out) {
  int idx = blockIdx.x * 256 + threadIdx.x;
  if (idx < B_ * M_ * H_ / 2) {
    int e = idx * 2;
    int b = e >> 14;
    int rest = e & 16383;
    int r = rest >> 9;
    int hh = rest & 511;
    unsigned u = *(const unsigned*)&Xb[((size_t)(b * L_ + M_ + INFO_ + r)) * H_ + hh];
    out[e] = bflo(u);
    out[e + 1] = bfhi(u);
  }
}

// ---------------- launcher ----------------
extern "C" void kernel_launch(void* const* d_in, const int* in_sizes, int n_in, void* d_out,
                              int out_size, void* d_ws, size_t ws_size, hipStream_t stream) {
  const float* returns = (const float*)d_in[0];
  const float* actions = (const float*)d_in[1];
  const float* t_table = (const float*)d_in[2];
  const float* s_table = (const float*)d_in[3];
  const float* Wr = (const float*)d_in[4];
  const float* br = (const float*)d_in[5];
  const float* Wa = (const float*)d_in[6];
  const float* ba = (const float*)d_in[7];
  const float* ln_e_g = (const float*)d_in[8];
  const float* ln_e_b = (const float*)d_in[9];
  const float* read_mem = (const float*)d_in[10];
  const float* mem_tok = (const float*)d_in[11];
  const float* Wq = (const float*)d_in[12];
  const float* bq = (const float*)d_in[13];
  const float* Wk = (const float*)d_in[14];
  const float* bk = (const float*)d_in[15];
  const float* Wv = (const float*)d_in[16];
  const float* bv = (const float*)d_in[17];
  const float* Wo = (const float*)d_in[18];
  const float* bo = (const float*)d_in[19];
  const float* W1 = (const float*)d_in[20];
  const float* b1 = (const float*)d_in[21];
  const float* W2 = (const float*)d_in[22];
  const float* b2 = (const float*)d_in[23];
  const float* g1 = (const float*)d_in[24];
  const float* be1 = (const float*)d_in[25];
  const float* g2 = (const float*)d_in[26];
  const float* be2 = (const float*)d_in[27];
  const float* Wp = (const float*)d_in[28];
  const float* bp = (const float*)d_in[29];
  const int* states = (const int*)d_in[30];
  const int* timestep = (const int*)d_in[31];

  char* ws = (char*)d_ws;
  size_t off = 0;
  auto alloc = [&](size_t bytes) -> char* {
    char* p = ws + off;
    off += (bytes + 255) & ~(size_t)255;
    return p;
  };
  ushort_t* Xb = (ushort_t*)alloc((size_t)MPAD * H_ * 2);
  ushort_t* Y = (ushort_t*)alloc((size_t)MPAD * H_ * 2);
  ushort_t* Qb = (ushort_t*)alloc((size_t)B_ * NH_ * LP_ * DH_ * 2);
  ushort_t* Kb2 = (ushort_t*)alloc((size_t)B_ * NH_ * LP_ * DH_ * 2);
  ushort_t* Vt = (ushort_t*)alloc((size_t)B_ * NH_ * DH_ * LP_ * 2);
  ushort_t* Ob = (ushort_t*)alloc((size_t)MPAD * H_ * 2);
  ushort_t* Hm = (ushort_t*)alloc((size_t)MPAD * HMLP * 2);
  ushort_t* Wqkvb = (ushort_t*)alloc((size_t)4 * 1536 * 512 * 2);
  ushort_t* Wob = (ushort_t*)alloc((size_t)4 * 512 * 512 * 2);
  ushort_t* W1b = (ushort_t*)alloc((size_t)4 * 2048 * 512 * 2);
  ushort_t* W2b = (ushort_t*)alloc((size_t)4 * 512 * 2048 * 2);
  float* biascat = (float*)alloc((size_t)4 * 1536 * 4);

  zero_pads_kernel<<<128, 256, 0, stream>>>(Qb, Kb2, Vt, Ob);
  cvtqkv_kernel<<<512, 256, 0, stream>>>(Wq, Wk, Wv, Wqkvb);
  biascat_kernel<<<8, 256, 0, stream>>>(bq, bk, bv, biascat);
  cvt8_kernel<<<512, 256, 0, stream>>>(Wo, Wob, 4 * 512 * 512 / 8);
  cvt8_kernel<<<2048, 256, 0, stream>>>(W1, W1b, 4 * 2048 * 512 / 8);
  cvt8_kernel<<<2048, 256, 0, stream>>>(W2, W2b, 4 * 512 * 2048 / 8);

  embed_ln_kernel<<<MPAD, 256, 0, stream>>>(returns, actions, t_table, s_table, Wr, br, Wa,
                                            ba, ln_e_g, ln_e_b, read_mem, mem_tok, states,
                                            timestep, Xb);

  for (int nb = 0; nb < 4; ++nb) {
    const size_t wo512 = (size_t)nb * 512 * 512;
    const size_t woqkv = (size_t)nb * 1536 * 512;
    const size_t wo1 = (size_t)nb * 2048 * 512;
    gemm_kernel<0><<<68 * 24, 256, 0, stream>>>(Xb, Wqkvb + woqkv, biascat + nb * 1536, Qb,
                                                Kb2, Vt, 24, 512);
    attn_kernel<<<576, 256, 0, stream>>>(Qb, Kb2, Vt, Ob);
    gemm_kernel<2><<<68 * 8, 256, 0, stream>>>(Ob, Wob + wo512, bo + nb * 512, Y, nullptr,
                                               nullptr, 8, 512);
    ln_add_kernel<<<MPAD, 256, 0, stream>>>(Xb, Y, g1 + nb * 512, be1 + nb * 512);
    gemm_kernel<3><<<68 * 32, 256, 0, stream>>>(Xb, W1b + wo1, b1 + nb * 2048, Hm, nullptr,
                                                nullptr, 32, 512);
    gemm_kernel<2><<<68 * 8, 256, 0, stream>>>(Hm, W2b + wo1, b2 + nb * 512, Y, nullptr,
                                               nullptr, 8, 2048);
    ln_add_kernel<<<MPAD, 256, 0, stream>>>(Xb, Y, g2 + nb * 512, be2 + nb * 512);
  }

  logits_kernel<<<B_ * T_, 64, 0, stream>>>(Xb, Wp, bp, (float*)d_out);
  memout_kernel<<<256, 256, 0, stream>>>(Xb, (float*)d_out + (size_t)B_ * T_ * 4);
}

// Round 14
// 593.175 us; speedup vs baseline: 1.3559x; 1.0264x over previous
//
#include <hip/hip_runtime.h>
#include <hip/hip_bf16.h>

typedef unsigned short ushort_t;
typedef __attribute__((ext_vector_type(8))) __bf16 bf16x8;
typedef __attribute__((ext_vector_type(4))) float f32x4;
typedef __attribute__((ext_vector_type(16))) float f32x16;
typedef __attribute__((ext_vector_type(2))) unsigned u32x2;
typedef __attribute__((ext_vector_type(4))) unsigned u32x4;

#define B_ 8
#define T_ 340
#define M_ 32
#define H_ 512
#define NH_ 8
#define DH_ 64
#define INFO_ 1020
#define L_ 1084
#define LP_ 1088
#define MROWS 8672
#define MPAD 8704
#define HMLP 2048

__device__ __forceinline__ ushort_t f2bf(float f) {
  unsigned u = __builtin_bit_cast(unsigned, f);
  unsigned r = (u + 0x7fffu + ((u >> 16) & 1u)) >> 16;
  return (ushort_t)r;
}

__device__ __forceinline__ float bflo(unsigned u) {
  return __builtin_bit_cast(float, u << 16);
}
__device__ __forceinline__ float bfhi(unsigned u) {
  return __builtin_bit_cast(float, u & 0xffff0000u);
}

__device__ __forceinline__ unsigned cvtpk_bf16(float lo, float hi) {
  unsigned r;
  asm volatile("v_cvt_pk_bf16_f32 %0, %1, %2" : "=v"(r) : "v"(lo), "v"(hi));
  return r;
}

__device__ __forceinline__ void gload16(const ushort_t* g, ushort_t* l) {
  __builtin_amdgcn_global_load_lds((const __attribute__((address_space(1))) unsigned*)g,
                                   (__attribute__((address_space(3))) unsigned*)l, 16, 0, 0);
}

// ---------------- zero pads (Q/K l-pads, Vt l-pads, Ob row-pads) ----------------
__global__ __launch_bounds__(256) void zero_pads_kernel(ushort_t* Qb, ushort_t* Kb,
                                                        ushort_t* Vt, ushort_t* Ob) {
  int idx = blockIdx.x * 256 + threadIdx.x;
  if (idx < 16384) {
    int bh = idx >> 8;
    int rest = idx & 255;
    int l = L_ + (rest >> 6);
    int d = rest & 63;
    size_t o = ((size_t)bh * LP_ + l) * DH_ + d;
    Qb[o] = 0;
    Kb[o] = 0;
    Vt[((size_t)bh * DH_ + d) * LP_ + l] = 0;
  } else if (idx < 32768) {
    int j = idx - 16384;
    Ob[(size_t)MROWS * H_ + j] = 0;
  }
}

// ---------------- f32 -> bf16 convert, 8 elems/thread ----------------
__global__ __launch_bounds__(256) void cvt8_kernel(const float* __restrict__ src,
                                                   ushort_t* __restrict__ dst, int n8) {
  int i = blockIdx.x * 256 + threadIdx.x;
  if (i >= n8) return;
  f32x4 a = ((const f32x4*)src)[2 * i];
  f32x4 b = ((const f32x4*)src)[2 * i + 1];
  u32x4 o;
  o.x = cvtpk_bf16(a[0], a[1]);
  o.y = cvtpk_bf16(a[2], a[3]);
  o.z = cvtpk_bf16(b[0], b[1]);
  o.w = cvtpk_bf16(b[2], b[3]);
  ((u32x4*)dst)[i] = o;
}

// ---------------- Wq/Wk/Wv -> concatenated bf16 [nb][1536][512], 8/thread ----------
__global__ __launch_bounds__(256) void cvtqkv_kernel(const float* __restrict__ q,
                                                     const float* __restrict__ k,
                                                     const float* __restrict__ v,
                                                     ushort_t* __restrict__ dst) {
  int i8 = blockIdx.x * 256 + threadIdx.x;
  if (i8 >= 131072) return;  // 4*512*512/8
  int i = i8 * 8;
  int nb = i >> 18;
  int rem = i & 262143;
  size_t base8 = ((size_t)nb * 786432 + rem) >> 3;
  const float* srcs[3] = {q, k, v};
#pragma unroll
  for (int w = 0; w < 3; w++) {
    f32x4 a = ((const f32x4*)srcs[w])[2 * i8];
    f32x4 b = ((const f32x4*)srcs[w])[2 * i8 + 1];
    u32x4 o;
    o.x = cvtpk_bf16(a[0], a[1]);
    o.y = cvtpk_bf16(a[2], a[3]);
    o.z = cvtpk_bf16(b[0], b[1]);
    o.w = cvtpk_bf16(b[2], b[3]);
    ((u32x4*)dst)[base8 + (size_t)w * 32768] = o;  // 262144/8
  }
}

__global__ __launch_bounds__(256) void biascat_kernel(const float* __restrict__ bq,
                                                      const float* __restrict__ bk,
                                                      const float* __restrict__ bv,
                                                      float* __restrict__ dst) {
  int i = blockIdx.x * 256 + threadIdx.x;
  if (i < 2048) {
    int nb = i >> 9, r = i & 511;
    float* d = dst + nb * 1536;
    d[r] = bq[i];
    d[512 + r] = bk[i];
    d[1024 + r] = bv[i];
  }
}

// ---------------- embedding + initial LN (bf16 residual out) ----------------
__global__ __launch_bounds__(256) void embed_ln_kernel(
    const float* __restrict__ returns, const float* __restrict__ actions,
    const float* __restrict__ t_table, const float* __restrict__ s_table,
    const float* __restrict__ Wr, const float* __restrict__ br,
    const float* __restrict__ Wa, const float* __restrict__ ba,
    const float* __restrict__ g, const float* __restrict__ be,
    const float* __restrict__ read_mem, const float* __restrict__ mem_tok,
    const int* __restrict__ states, const int* __restrict__ timestep,
    ushort_t* __restrict__ Xb) {
  const int row = blockIdx.x;
  const int tid = threadIdx.x;
  if (row >= MROWS) {
    Xb[(size_t)row * H_ + tid] = 0;
    Xb[(size_t)row * H_ + tid + 256] = 0;
    return;
  }
  const int b = row / L_, l = row - b * L_;
  float v[2];
#pragma unroll
  for (int s2 = 0; s2 < 2; s2++) {
    int hh = tid + s2 * 256;
    float val;
    if (l < M_) {
      val = read_mem[(size_t)l * H_ + hh];
    } else if (l >= M_ + INFO_) {
      val = mem_tok[(size_t)(l - M_ - INFO_) * H_ + hh];
    } else {
      int ii = l - M_;
      int t = ii / 3, c = ii - t * 3;
      int bt = b * T_ + t;
      if (c == 1) {
        val = s_table[(size_t)states[bt] * H_ + hh];
      } else {
        float te = t_table[(size_t)timestep[bt] * H_ + hh];
        val = (c == 0 ? returns[bt] * Wr[hh] + br[hh] : actions[bt] * Wa[hh] + ba[hh]) + te;
      }
    }
    v[s2] = val;
  }
  float sum = v[0] + v[1], sq = v[0] * v[0] + v[1] * v[1];
  __shared__ float sa[4], sb[4];
#pragma unroll
  for (int o = 1; o < 64; o <<= 1) {
    sum += __shfl_xor(sum, o);
    sq += __shfl_xor(sq, o);
  }
  int wv = tid >> 6, lane = tid & 63;
  if (lane == 0) { sa[wv] = sum; sb[wv] = sq; }
  __syncthreads();
  sum = sa[0] + sa[1] + sa[2] + sa[3];
  sq = sb[0] + sb[1] + sb[2] + sb[3];
  float mu = sum * (1.0f / H_);
  float var = sq * (1.0f / H_) - mu * mu;
  float rstd = rsqrtf(var + 1e-5f);
#pragma unroll
  for (int s2 = 0; s2 < 2; s2++) {
    int hh = tid + s2 * 256;
    float y = (v[s2] - mu) * rstd * g[hh] + be[hh];
    Xb[(size_t)row * H_ + hh] = f2bf(y);
  }
}

// ---------------- fused residual-add + LN, bf16 in-place ----------------
__global__ __launch_bounds__(256) void ln_add_kernel(ushort_t* __restrict__ Xb,
                                                     const ushort_t* __restrict__ Y,
                                                     const float* __restrict__ g,
                                                     const float* __restrict__ be) {
  const int row = blockIdx.x;
  const int tid = threadIdx.x;
  unsigned* xr = (unsigned*)(Xb + (size_t)row * H_);
  if (row >= MROWS) {
    xr[tid] = 0;
    return;
  }
  const unsigned* yr = (const unsigned*)(Y + (size_t)row * H_);
  unsigned xu = xr[tid], yu = yr[tid];
  float v0 = bflo(xu) + bflo(yu);
  float v1 = bfhi(xu) + bfhi(yu);
  float sum = v0 + v1, sq = v0 * v0 + v1 * v1;
  __shared__ float sa[4], sb[4];
#pragma unroll
  for (int o = 1; o < 64; o <<= 1) {
    sum += __shfl_xor(sum, o);
    sq += __shfl_xor(sq, o);
  }
  int wv = tid >> 6, lane = tid & 63;
  if (lane == 0) { sa[wv] = sum; sb[wv] = sq; }
  __syncthreads();
  sum = sa[0] + sa[1] + sa[2] + sa[3];
  sq = sb[0] + sb[1] + sb[2] + sb[3];
  float mu = sum * (1.0f / H_);
  float var = sq * (1.0f / H_) - mu * mu;
  float rstd = rsqrtf(var + 1e-5f);
  float g0 = g[2 * tid], g1v = g[2 * tid + 1];
  float b0 = be[2 * tid], b1v = be[2 * tid + 1];
  float n0 = (v0 - mu) * rstd * g0 + b0;
  float n1 = (v1 - mu) * rstd * g1v + b1v;
  xr[tid] = cvtpk_bf16(n0, n1);
}

// ---------------- GEMM v2: 512 threads / 8 waves, 128x128 tile, BK=64, dbuf LDS,
// counted vmcnt(4), XOR swizzle, chunked XCD mapping. 64KB LDS -> 2 blocks/CU
// (16 waves/CU). Waves 0-3 stage A, waves 4-7 stage B (4 gloads each).
// Wave (wm=wv>>2, wn=wv&3) computes rows wm*64.. cols wn*32.. of the tile.
// MODE 0: fused QKV, N=1536 -> Q(scaled)->(b,h,l,d), K->(b,h,l,d), V packed->(b,h,d,l)
// MODE 2: bf16 o0[m,n] = acc + bias          (Y for fused resid+LN)
// MODE 3: bf16 o0[m,n] = gelu(acc + bias), N=2048
template <int MODE>
__global__ __launch_bounds__(512, 2) void gemm_kernel(const ushort_t* __restrict__ A,
                                                      const ushort_t* __restrict__ W,
                                                      const float* __restrict__ bias,
                                                      void* __restrict__ o0,
                                                      void* __restrict__ o1,
                                                      void* __restrict__ o2, int Ntiles,
                                                      int K) {
  __shared__ ushort_t As[2][8192];  // 128 rows x 64 cols
  __shared__ ushort_t Bs[2][8192];  // 128 rows x 64 cols
  const int tid = threadIdx.x;
  const int job = (blockIdx.x & 7) * (gridDim.x >> 3) + (blockIdx.x >> 3);
  const int bx = job % Ntiles, by = job / Ntiles;
  const int m0 = by * 128, n0 = bx * 128;
  const int lane = tid & 63, wv = tid >> 6;
  const int wm = wv >> 2, wn = wv & 3;
  f32x4 acc[4][2] = {};

  // staging: waves 0-3 -> A rows wv*32..+32; waves 4-7 -> B rows (wv-4)*32..+32.
  // Each gload covers 8 rows (64 lanes x 16B); row = base + g2*8 + (lane>>3);
  // global k-chunk pre-swizzled: kg = (lane&7) ^ (row&7).
  const int srow = lane >> 3;
  const int kg = (lane & 7) ^ srow;
  const bool isA = wv < 4;
  const int wvr = isA ? wv : wv - 4;
  const ushort_t* gsrc[4];
#pragma unroll
  for (int g2 = 0; g2 < 4; g2++) {
    int row = wvr * 32 + g2 * 8 + srow;
    gsrc[g2] = (isA ? A + (size_t)(m0 + row) * K : W + (size_t)(n0 + row) * K) + kg * 8;
  }
  ushort_t* ldsd[2];
  ldsd[0] = (isA ? &As[0][0] : &Bs[0][0]) + wvr * 2048;
  ldsd[1] = (isA ? &As[1][0] : &Bs[1][0]) + wvr * 2048;

  const int NT = K >> 6;

#pragma unroll
  for (int g2 = 0; g2 < 4; g2++) gload16(gsrc[g2], ldsd[0] + g2 * 512);

  const int q = lane >> 4, lr = lane & 15;
  const int s0 = q ^ (lr & 7);
  const int s1 = (4 + q) ^ (lr & 7);

  auto compute_tile = [&](int cur) {
    bf16x8 af[4][2], bfr[2][2];
#pragma unroll
    for (int mi = 0; mi < 4; mi++) {
      const ushort_t* rp = &As[cur][(wm * 64 + mi * 16 + lr) * 64];
      af[mi][0] = *(const bf16x8*)(rp + s0 * 8);
      af[mi][1] = *(const bf16x8*)(rp + s1 * 8);
    }
#pragma unroll
    for (int ni = 0; ni < 2; ni++) {
      const ushort_t* rp = &Bs[cur][(wn * 32 + ni * 16 + lr) * 64];
      bfr[ni][0] = *(const bf16x8*)(rp + s0 * 8);
      bfr[ni][1] = *(const bf16x8*)(rp + s1 * 8);
    }
#pragma unroll
    for (int kc = 0; kc < 2; kc++)
#pragma unroll
      for (int mi = 0; mi < 4; mi++)
#pragma unroll
        for (int ni = 0; ni < 2; ni++)
          acc[mi][ni] =
              __builtin_amdgcn_mfma_f32_16x16x32_bf16(af[mi][kc], bfr[ni][kc], acc[mi][ni], 0, 0, 0);
  };

  for (int kt = 0; kt < NT - 1; kt++) {
    const int cur = kt & 1, nxt = cur ^ 1;
    const int k0n = (kt + 1) << 6;
#pragma unroll
    for (int g2 = 0; g2 < 4; g2++) gload16(gsrc[g2] + k0n, ldsd[nxt] + g2 * 512);
    // wait only for CURRENT tile's 4 loads; next tile's 4 stay in flight
    asm volatile("s_waitcnt vmcnt(4)" ::: "memory");
    __builtin_amdgcn_s_barrier();
    asm volatile("" ::: "memory");
    compute_tile(cur);
    asm volatile("" ::: "memory");
    __builtin_amdgcn_s_barrier();
  }
  {
    asm volatile("s_waitcnt vmcnt(0)" ::: "memory");
    __builtin_amdgcn_s_barrier();
    asm volatile("" ::: "memory");
    compute_tile((NT - 1) & 1);
  }

  // epilogue: 4-row groups are 4-aligned; L_=1084 and MROWS are multiples of 4,
  // so a group never crosses a batch boundary or the MROWS edge.
#pragma unroll
  for (int mi = 0; mi < 4; mi++) {
    const int mbase = m0 + wm * 64 + mi * 16 + ((lane >> 4) << 2);
    const bool mok = mbase < MROWS;
    int bb = 0, lbase = 0;
    if (MODE == 0) {
      bb = mbase / L_;
      lbase = mbase - bb * L_;
    }
#pragma unroll
    for (int ni = 0; ni < 2; ni++) {
      const int n = n0 + wn * 32 + ni * 16 + (lane & 15);
      float v[4];
#pragma unroll
      for (int r = 0; r < 4; r++) v[r] = acc[mi][ni][r] + bias[n];
      if (MODE == 0) {
        if (mok) {
          const int which = n >> 9, nn = n & 511;
          const int hh = nn >> 6, d = nn & 63;
          if (which == 0) {
            ushort_t* o = (ushort_t*)o0 + (((size_t)(bb * NH_ + hh)) * LP_ + lbase) * DH_ + d;
#pragma unroll
            for (int r = 0; r < 4; r++)
              o[(size_t)r * DH_] = f2bf(v[r] * 0.18033688011112043f);
          } else if (which == 1) {
            ushort_t* o = (ushort_t*)o1 + (((size_t)(bb * NH_ + hh)) * LP_ + lbase) * DH_ + d;
#pragma unroll
            for (int r = 0; r < 4; r++) o[(size_t)r * DH_] = f2bf(v[r]);
          } else {
            u32x2 w2;
            w2.x = cvtpk_bf16(v[0], v[1]);
            w2.y = cvtpk_bf16(v[2], v[3]);
            *(u32x2*)((ushort_t*)o2 + (((size_t)(bb * NH_ + hh)) * DH_ + d) * LP_ + lbase) = w2;
          }
        }
      } else if (MODE == 2) {
        if (mok) {
#pragma unroll
          for (int r = 0; r < 4; r++)
            ((ushort_t*)o0)[(size_t)(mbase + r) * H_ + n] = f2bf(v[r]);
        }
      } else {
#pragma unroll
        for (int r = 0; r < 4; r++) {
          float ge = 0.5f * v[r] * (1.0f + erff(v[r] * 0.70710678f));
          ((ushort_t*)o0)[(size_t)(mbase + r) * HMLP + n] = f2bf(ge);
        }
      }
    }
  }
}

// ---------------- flash attention v7: KVBLK=64 — chunk PAIRS per barrier window ----
__global__ __launch_bounds__(256, 3) void attn_kernel(const ushort_t* __restrict__ Qb,
                                                      const ushort_t* __restrict__ Kb,
                                                      const ushort_t* __restrict__ Vt,
                                                      ushort_t* __restrict__ Ob) {
  __shared__ ushort_t Klds[2][4096];
  __shared__ ushort_t Vlds[2][4096];
  const int tid = threadIdx.x;
  const int lane = tid & 63, wv = tid >> 6;
  const int xcd = blockIdx.x & 7, slot = blockIdx.x >> 3;
  const int g = slot >> 3, bhi = slot & 7;
  const int bh = (bhi << 3) | xcd;
  const int t = 33 - 4 * g - wv;
  const bool active = (t >= 0);
  const int b = bh >> 3, h = bh & 7;
  const int qb = t * 32;
  const int lq = lane & 31, hi = lane >> 5;
  const int nk_own = active ? ((t == 33) ? 34 : (t + 1)) : 0;
  const int nkmax = (g == 0) ? 34 : (34 - 4 * g);  // always even
  const int nw = nkmax >> 1;
  const int cmask = (t == 0) ? -1 : (nk_own - 1);
  const int i = qb + lq;

  const ushort_t* Qp = Qb + (size_t)bh * LP_ * DH_;
  const ushort_t* Kp = Kb + (size_t)bh * LP_ * DH_;
  const ushort_t* Vp = Vt + (size_t)bh * DH_ * LP_;

  const ushort_t* KsrcB =
      Kp + (size_t)(8 * wv + (lane >> 3)) * DH_ + (((lane & 7) ^ ((lane >> 3) & 7)) * 8);
  const ushort_t* VsrcB =
      Vp + (size_t)(16 * wv + (lane >> 2)) * LP_ + (((lane & 3) ^ ((lane >> 3) & 3)) * 8);

  auto stageW = [&](int w, int buf) {
    const int c0 = 2 * w;
    gload16(KsrcB + (size_t)c0 * 2048, &Klds[buf][wv * 512]);
    gload16(KsrcB + (size_t)(c0 + 1) * 2048, &Klds[buf][2048 + wv * 512]);
    gload16(VsrcB + c0 * 32, &Vlds[buf][wv * 512]);
    gload16(VsrcB + (c0 + 1) * 32, &Vlds[buf][2048 + wv * 512]);
  };

  bf16x8 qf[4];
  if (active) {
#pragma unroll
    for (int dc = 0; dc < 4; dc++)
      qf[dc] = *(const bf16x8*)(Qp + (size_t)(qb + lq) * DH_ + dc * 16 + hi * 8);
  }

  stageW(0, 0);

  f32x16 o0 = {}, o1 = {};
  float lsum = 0.f;

  int koff[4], voff[4];
#pragma unroll
  for (int dc = 0; dc < 4; dc++) koff[dc] = lq * 64 + (((dc * 2 + hi) ^ (lq & 7)) * 8);
#pragma unroll
  for (int f = 0; f < 4; f++) {
    int dt = f >> 1, cc = f & 1;
    voff[f] = (dt * 32 + lq) * 32 + ((((cc * 2 + hi) ^ ((lq >> 1) & 3))) * 8);
  }

  auto tilestep = [&](int c, const ushort_t* Kbase, const ushort_t* Vbase) {
    bf16x8 kf[4], vf[4];
#pragma unroll
    for (int dc = 0; dc < 4; dc++) kf[dc] = *(const bf16x8*)&Kbase[koff[dc]];
#pragma unroll
    for (int f = 0; f < 4; f++) vf[f] = *(const bf16x8*)&Vbase[voff[f]];

    f32x16 s = {};
#pragma unroll
    for (int dc = 0; dc < 4; dc++)
      s = __builtin_amdgcn_mfma_f32_32x32x16_bf16(kf[dc], qf[dc], s, 0, 0, 0);
    float p[16];
    if (c == cmask) {
#pragma unroll
      for (int r = 0; r < 16; r++) {
        int jcol = c * 32 + (r & 3) + 8 * (r >> 2) + 4 * hi;
        bool ok = (jcol < L_) && ((jcol < M_) || (i >= M_ + INFO_) || (jcol <= i));
        p[r] = ok ? __builtin_amdgcn_exp2f(s[r]) : 0.f;
      }
    } else {
#pragma unroll
      for (int r = 0; r < 16; r++) p[r] = __builtin_amdgcn_exp2f(s[r]);
    }
    float u0 = (p[0] + p[1]) + (p[2] + p[3]);
    float u1 = (p[4] + p[5]) + (p[6] + p[7]);
    float u2 = (p[8] + p[9]) + (p[10] + p[11]);
    float u3 = (p[12] + p[13]) + (p[14] + p[15]);
    lsum += (u0 + u1) + (u2 + u3);
    bf16x8 pf[2];
#pragma unroll
    for (int cc = 0; cc < 2; cc++) {
      unsigned A01 = cvtpk_bf16(p[8 * cc + 0], p[8 * cc + 1]);
      unsigned A23 = cvtpk_bf16(p[8 * cc + 2], p[8 * cc + 3]);
      unsigned B45 = cvtpk_bf16(p[8 * cc + 4], p[8 * cc + 5]);
      unsigned B67 = cvtpk_bf16(p[8 * cc + 6], p[8 * cc + 7]);
      u32x2 r0 = __builtin_amdgcn_permlane32_swap(A01, B45, false, false);
      u32x2 r1 = __builtin_amdgcn_permlane32_swap(A23, B67, false, false);
      u32x4 w = {r0.x, r1.x, r0.y, r1.y};
      pf[cc] = __builtin_bit_cast(bf16x8, w);
    }
    o0 = __builtin_amdgcn_mfma_f32_32x32x16_bf16(vf[0], pf[0], o0, 0, 0, 0);
    o0 = __builtin_amdgcn_mfma_f32_32x32x16_bf16(vf[1], pf[1], o0, 0, 0, 0);
    o1 = __builtin_amdgcn_mfma_f32_32x32x16_bf16(vf[2], pf[0], o1, 0, 0, 0);
    o1 = __builtin_amdgcn_mfma_f32_32x32x16_bf16(vf[3], pf[1], o1, 0, 0, 0);
  };

  for (int w = 0; w < nw; w++) {
    const int cur = w & 1;
    if (w + 1 < nw) {
      stageW(w + 1, cur ^ 1);
      asm volatile("s_waitcnt vmcnt(4)" ::: "memory");
    } else {
      asm volatile("s_waitcnt vmcnt(0)" ::: "memory");
    }
    __builtin_amdgcn_s_barrier();
    asm volatile("" ::: "memory");

    const int c0 = 2 * w;
    if (c0 < nk_own) tilestep(c0, &Klds[cur][0], &Vlds[cur][0]);
    if (c0 + 1 < nk_own) tilestep(c0 + 1, &Klds[cur][2048], &Vlds[cur][2048]);

    asm volatile("" ::: "memory");
    __builtin_amdgcn_s_barrier();
  }

  if (active) {
    u32x2 tt = __builtin_amdgcn_permlane32_swap(__builtin_bit_cast(unsigned, lsum),
                                                __builtin_bit_cast(unsigned, lsum), false, false);
    lsum = __builtin_bit_cast(float, tt.x) + __builtin_bit_cast(float, tt.y);
    if (i < L_) {
      const float inv = 1.0f / lsum;
      ushort_t* orow = Ob + ((size_t)(b * L_ + i)) * H_ + h * DH_;
#pragma unroll
      for (int dt = 0; dt < 2; dt++) {
#pragma unroll
        for (int q2 = 0; q2 < 4; q2++) {
          float v0 = (dt ? o1[4 * q2 + 0] : o0[4 * q2 + 0]) * inv;
          float v1 = (dt ? o1[4 * q2 + 1] : o0[4 * q2 + 1]) * inv;
          float v2 = (dt ? o1[4 * q2 + 2] : o0[4 * q2 + 2]) * inv;
          float v3 = (dt ? o1[4 * q2 + 3] : o0[4 * q2 + 3]) * inv;
          int dbase = dt * 32 + 8 * q2 + 4 * hi;
          *(unsigned*)(orow + dbase) = cvtpk_bf16(v0, v1);
          *(unsigned*)(orow + dbase + 2) = cvtpk_bf16(v2, v3);
        }
      }
    }
  }
}

// ---------------- heads (bf16 residual input) ----------------
__global__ __launch_bounds__(64) void logits_kernel(const ushort_t* __restrict__ Xb,
                                                    const float* __restrict__ Wp,
                                                    const float* __restrict__ bp,
                                                    float* __restrict__ out) {
  const int bt = blockIdx.x;
  const int b = bt / T_, t = bt - b * T_;
  const int lane = threadIdx.x;
  const ushort_t* xr = Xb + ((size_t)(b * L_ + M_ + 3 * t + 1)) * H_ + lane * 8;
  u32x4 xv = *(const u32x4*)xr;
  float x0[8];
#pragma unroll
  for (int ii = 0; ii < 4; ii++) {
    unsigned u = xv[ii];
    x0[2 * ii] = bflo(u);
    x0[2 * ii + 1] = bfhi(u);
  }
#pragma unroll
  for (int a = 0; a < 4; a++) {
    const float* wr2 = Wp + (size_t)a * H_ + lane * 8;
    float p = 0.f;
#pragma unroll
    for (int ii = 0; ii < 8; ii++) p += x0[ii] * wr2[ii];
#pragma unroll
    for (int o = 1; o < 64; o <<= 1) p += __shfl_xor(p, o);
    if (lane == 0) out[(size_t)bt * 4 + a] = p + bp[a];
  }
}

__global__ __launch_bounds__(256) void memout_kernel(const ushort_t* __restrict__ Xb,
                                                     float* __restrict__ out) {
  int idx = blockIdx.x * 256 + threadIdx.x;
  if (idx < B_ * M_ * H_ / 2) {
    int e = idx * 2;
    int b = e >> 14;
    int rest = e & 16383;
    int r = rest >> 9;
    int hh = rest & 511;
    unsigned u = *(const unsigned*)&Xb[((size_t)(b * L_ + M_ + INFO_ + r)) * H_ + hh];
    out[e] = bflo(u);
    out[e + 1] = bfhi(u);
  }
}

// ---------------- launcher ----------------
extern "C" void kernel_launch(void* const* d_in, const int* in_sizes, int n_in, void* d_out,
                              int out_size, void* d_ws, size_t ws_size, hipStream_t stream) {
  const float* returns = (const float*)d_in[0];
  const float* actions = (const float*)d_in[1];
  const float* t_table = (const float*)d_in[2];
  const float* s_table = (const float*)d_in[3];
  const float* Wr = (const float*)d_in[4];
  const float* br = (const float*)d_in[5];
  const float* Wa = (const float*)d_in[6];
  const float* ba = (const float*)d_in[7];
  const float* ln_e_g = (const float*)d_in[8];
  const float* ln_e_b = (const float*)d_in[9];
  const float* read_mem = (const float*)d_in[10];
  const float* mem_tok = (const float*)d_in[11];
  const float* Wq = (const float*)d_in[12];
  const float* bq = (const float*)d_in[13];
  const float* Wk = (const float*)d_in[14];
  const float* bk = (const float*)d_in[15];
  const float* Wv = (const float*)d_in[16];
  const float* bv = (const float*)d_in[17];
  const float* Wo = (const float*)d_in[18];
  const float* bo = (const float*)d_in[19];
  const float* W1 = (const float*)d_in[20];
  const float* b1 = (const float*)d_in[21];
  const float* W2 = (const float*)d_in[22];
  const float* b2 = (const float*)d_in[23];
  const float* g1 = (const float*)d_in[24];
  const float* be1 = (const float*)d_in[25];
  const float* g2 = (const float*)d_in[26];
  const float* be2 = (const float*)d_in[27];
  const float* Wp = (const float*)d_in[28];
  const float* bp = (const float*)d_in[29];
  const int* states = (const int*)d_in[30];
  const int* timestep = (const int*)d_in[31];

  char* ws = (char*)d_ws;
  size_t off = 0;
  auto alloc = [&](size_t bytes) -> char* {
    char* p = ws + off;
    off += (bytes + 255) & ~(size_t)255;
    return p;
  };
  ushort_t* Xb = (ushort_t*)alloc((size_t)MPAD * H_ * 2);
  ushort_t* Y = (ushort_t*)alloc((size_t)MPAD * H_ * 2);
  ushort_t* Qb = (ushort_t*)alloc((size_t)B_ * NH_ * LP_ * DH_ * 2);
  ushort_t* Kb2 = (ushort_t*)alloc((size_t)B_ * NH_ * LP_ * DH_ * 2);
  ushort_t* Vt = (ushort_t*)alloc((size_t)B_ * NH_ * DH_ * LP_ * 2);
  ushort_t* Ob = (ushort_t*)alloc((size_t)MPAD * H_ * 2);
  ushort_t* Hm = (ushort_t*)alloc((size_t)MPAD * HMLP * 2);
  ushort_t* Wqkvb = (ushort_t*)alloc((size_t)4 * 1536 * 512 * 2);
  ushort_t* Wob = (ushort_t*)alloc((size_t)4 * 512 * 512 * 2);
  ushort_t* W1b = (ushort_t*)alloc((size_t)4 * 2048 * 512 * 2);
  ushort_t* W2b = (ushort_t*)alloc((size_t)4 * 512 * 2048 * 2);
  float* biascat = (float*)alloc((size_t)4 * 1536 * 4);

  zero_pads_kernel<<<128, 256, 0, stream>>>(Qb, Kb2, Vt, Ob);
  cvtqkv_kernel<<<512, 256, 0, stream>>>(Wq, Wk, Wv, Wqkvb);
  biascat_kernel<<<8, 256, 0, stream>>>(bq, bk, bv, biascat);
  cvt8_kernel<<<512, 256, 0, stream>>>(Wo, Wob, 4 * 512 * 512 / 8);
  cvt8_kernel<<<2048, 256, 0, stream>>>(W1, W1b, 4 * 2048 * 512 / 8);
  cvt8_kernel<<<2048, 256, 0, stream>>>(W2, W2b, 4 * 512 * 2048 / 8);

  embed_ln_kernel<<<MPAD, 256, 0, stream>>>(returns, actions, t_table, s_table, Wr, br, Wa,
                                            ba, ln_e_g, ln_e_b, read_mem, mem_tok, states,
                                            timestep, Xb);

  for (int nb = 0; nb < 4; ++nb) {
    const size_t wo512 = (size_t)nb * 512 * 512;
    const size_t woqkv = (size_t)nb * 1536 * 512;
    const size_t wo1 = (size_t)nb * 2048 * 512;
    gemm_kernel<0><<<68 * 12, 512, 0, stream>>>(Xb, Wqkvb + woqkv, biascat + nb * 1536, Qb,
                                                Kb2, Vt, 12, 512);
    attn_kernel<<<576, 256, 0, stream>>>(Qb, Kb2, Vt, Ob);
    gemm_kernel<2><<<68 * 4, 512, 0, stream>>>(Ob, Wob + wo512, bo + nb * 512, Y, nullptr,
                                               nullptr, 4, 512);
    ln_add_kernel<<<MPAD, 256, 0, stream>>>(Xb, Y, g1 + nb * 512, be1 + nb * 512);
    gemm_kernel<3><<<68 * 16, 512, 0, stream>>>(Xb, W1b + wo1, b1 + nb * 2048, Hm, nullptr,
                                                nullptr, 16, 512);
    gemm_kernel<2><<<68 * 4, 512, 0, stream>>>(Hm, W2b + wo1, b2 + nb * 512, Y, nullptr,
                                               nullptr, 4, 2048);
    ln_add_kernel<<<MPAD, 256, 0, stream>>>(Xb, Y, g2 + nb * 512, be2 + nb * 512);
  }

  logits_kernel<<<B_ * T_, 64, 0, stream>>>(Xb, Wp, bp, (float*)d_out);
  memout_kernel<<<256, 256, 0, stream>>>(Xb, (float*)d_out + (size_t)B_ * T_ * 4);
}

// Round 15
// 565.228 us; speedup vs baseline: 1.4229x; 1.0494x over previous
//
#include <hip/hip_runtime.h>
#include <hip/hip_bf16.h>

typedef unsigned short ushort_t;
typedef __attribute__((ext_vector_type(8))) __bf16 bf16x8;
typedef __attribute__((ext_vector_type(4))) float f32x4;
typedef __attribute__((ext_vector_type(16))) float f32x16;
typedef __attribute__((ext_vector_type(2))) unsigned u32x2;
typedef __attribute__((ext_vector_type(4))) unsigned u32x4;

#define B_ 8
#define T_ 340
#define M_ 32
#define H_ 512
#define NH_ 8
#define DH_ 64
#define INFO_ 1020
#define L_ 1084
#define LP_ 1088
#define MROWS 8672
#define MPAD 8704
#define HMLP 2048

__device__ __forceinline__ ushort_t f2bf(float f) {
  unsigned u = __builtin_bit_cast(unsigned, f);
  unsigned r = (u + 0x7fffu + ((u >> 16) & 1u)) >> 16;
  return (ushort_t)r;
}

__device__ __forceinline__ float bflo(unsigned u) {
  return __builtin_bit_cast(float, u << 16);
}
__device__ __forceinline__ float bfhi(unsigned u) {
  return __builtin_bit_cast(float, u & 0xffff0000u);
}

__device__ __forceinline__ unsigned cvtpk_bf16(float lo, float hi) {
  unsigned r;
  asm volatile("v_cvt_pk_bf16_f32 %0, %1, %2" : "=v"(r) : "v"(lo), "v"(hi));
  return r;
}

__device__ __forceinline__ void gload16(const ushort_t* g, ushort_t* l) {
  __builtin_amdgcn_global_load_lds((const __attribute__((address_space(1))) unsigned*)g,
                                   (__attribute__((address_space(3))) unsigned*)l, 16, 0, 0);
}

// ---------------- zero pads (Q/K l-pads, Vt l-pads, Ob row-pads) ----------------
__global__ __launch_bounds__(256) void zero_pads_kernel(ushort_t* Qb, ushort_t* Kb,
                                                        ushort_t* Vt, ushort_t* Ob) {
  int idx = blockIdx.x * 256 + threadIdx.x;
  if (idx < 16384) {
    int bh = idx >> 8;
    int rest = idx & 255;
    int l = L_ + (rest >> 6);
    int d = rest & 63;
    size_t o = ((size_t)bh * LP_ + l) * DH_ + d;
    Qb[o] = 0;
    Kb[o] = 0;
    Vt[((size_t)bh * DH_ + d) * LP_ + l] = 0;
  } else if (idx < 32768) {
    int j = idx - 16384;
    Ob[(size_t)MROWS * H_ + j] = 0;
  }
}

// ---------------- f32 -> bf16 convert, 8 elems/thread ----------------
__global__ __launch_bounds__(256) void cvt8_kernel(const float* __restrict__ src,
                                                   ushort_t* __restrict__ dst, int n8) {
  int i = blockIdx.x * 256 + threadIdx.x;
  if (i >= n8) return;
  f32x4 a = ((const f32x4*)src)[2 * i];
  f32x4 b = ((const f32x4*)src)[2 * i + 1];
  u32x4 o;
  o.x = cvtpk_bf16(a[0], a[1]);
  o.y = cvtpk_bf16(a[2], a[3]);
  o.z = cvtpk_bf16(b[0], b[1]);
  o.w = cvtpk_bf16(b[2], b[3]);
  ((u32x4*)dst)[i] = o;
}

// ---------------- Wq/Wk/Wv -> concatenated bf16 [nb][1536][512], 8/thread ----------
__global__ __launch_bounds__(256) void cvtqkv_kernel(const float* __restrict__ q,
                                                     const float* __restrict__ k,
                                                     const float* __restrict__ v,
                                                     ushort_t* __restrict__ dst) {
  int i8 = blockIdx.x * 256 + threadIdx.x;
  if (i8 >= 131072) return;  // 4*512*512/8
  int i = i8 * 8;
  int nb = i >> 18;
  int rem = i & 262143;
  size_t base8 = ((size_t)nb * 786432 + rem) >> 3;
  const float* srcs[3] = {q, k, v};
#pragma unroll
  for (int w = 0; w < 3; w++) {
    f32x4 a = ((const f32x4*)srcs[w])[2 * i8];
    f32x4 b = ((const f32x4*)srcs[w])[2 * i8 + 1];
    u32x4 o;
    o.x = cvtpk_bf16(a[0], a[1]);
    o.y = cvtpk_bf16(a[2], a[3]);
    o.z = cvtpk_bf16(b[0], b[1]);
    o.w = cvtpk_bf16(b[2], b[3]);
    ((u32x4*)dst)[base8 + (size_t)w * 32768] = o;  // 262144/8
  }
}

__global__ __launch_bounds__(256) void biascat_kernel(const float* __restrict__ bq,
                                                      const float* __restrict__ bk,
                                                      const float* __restrict__ bv,
                                                      float* __restrict__ dst) {
  int i = blockIdx.x * 256 + threadIdx.x;
  if (i < 2048) {
    int nb = i >> 9, r = i & 511;
    float* d = dst + nb * 1536;
    d[r] = bq[i];
    d[512 + r] = bk[i];
    d[1024 + r] = bv[i];
  }
}

// ---------------- embedding + initial LN: wave-per-row, 4 rows/block ----------------
__global__ __launch_bounds__(256) void embed_ln_kernel(
    const float* __restrict__ returns, const float* __restrict__ actions,
    const float* __restrict__ t_table, const float* __restrict__ s_table,
    const float* __restrict__ Wr, const float* __restrict__ br,
    const float* __restrict__ Wa, const float* __restrict__ ba,
    const float* __restrict__ g, const float* __restrict__ be,
    const float* __restrict__ read_mem, const float* __restrict__ mem_tok,
    const int* __restrict__ states, const int* __restrict__ timestep,
    ushort_t* __restrict__ Xb) {
  const int wv = threadIdx.x >> 6, lane = threadIdx.x & 63;
  const int row = blockIdx.x * 4 + wv;
  u32x4* xo = (u32x4*)(Xb + (size_t)row * H_) + lane;
  if (row >= MROWS) {
    u32x4 z = {0u, 0u, 0u, 0u};
    *xo = z;
    return;
  }
  const int b = row / L_, l = row - b * L_;
  const int hh = lane * 8;
  float v[8];
  if (l < M_) {
    const float* p = read_mem + (size_t)l * H_ + hh;
    f32x4 a = *(const f32x4*)p, c = *(const f32x4*)(p + 4);
#pragma unroll
    for (int e = 0; e < 4; e++) {
      v[e] = a[e];
      v[4 + e] = c[e];
    }
  } else if (l >= M_ + INFO_) {
    const float* p = mem_tok + (size_t)(l - M_ - INFO_) * H_ + hh;
    f32x4 a = *(const f32x4*)p, c = *(const f32x4*)(p + 4);
#pragma unroll
    for (int e = 0; e < 4; e++) {
      v[e] = a[e];
      v[4 + e] = c[e];
    }
  } else {
    int ii = l - M_;
    int t = ii / 3, c2 = ii - t * 3;
    int bt = b * T_ + t;
    if (c2 == 1) {
      const float* p = s_table + (size_t)states[bt] * H_ + hh;
      f32x4 a = *(const f32x4*)p, c = *(const f32x4*)(p + 4);
#pragma unroll
      for (int e = 0; e < 4; e++) {
        v[e] = a[e];
        v[4 + e] = c[e];
      }
    } else {
      const float* tp = t_table + (size_t)timestep[bt] * H_ + hh;
      f32x4 t0 = *(const f32x4*)tp, t1 = *(const f32x4*)(tp + 4);
      float sc = (c2 == 0) ? returns[bt] : actions[bt];
      const float* wp = (c2 == 0) ? Wr : Wa;
      const float* bp2 = (c2 == 0) ? br : ba;
      f32x4 w0 = *(const f32x4*)(wp + hh), w1 = *(const f32x4*)(wp + hh + 4);
      f32x4 b0 = *(const f32x4*)(bp2 + hh), b1 = *(const f32x4*)(bp2 + hh + 4);
#pragma unroll
      for (int e = 0; e < 4; e++) {
        v[e] = sc * w0[e] + b0[e] + t0[e];
        v[4 + e] = sc * w1[e] + b1[e] + t1[e];
      }
    }
  }
  float sum = 0.f, sq = 0.f;
#pragma unroll
  for (int e = 0; e < 8; e++) {
    sum += v[e];
    sq += v[e] * v[e];
  }
#pragma unroll
  for (int o = 1; o < 64; o <<= 1) {
    sum += __shfl_xor(sum, o);
    sq += __shfl_xor(sq, o);
  }
  float mu = sum * (1.0f / H_);
  float var = sq * (1.0f / H_) - mu * mu;
  float rstd = rsqrtf(var + 1e-5f);
  f32x4 g0 = *(const f32x4*)(g + hh), g1 = *(const f32x4*)(g + hh + 4);
  f32x4 e0 = *(const f32x4*)(be + hh), e1 = *(const f32x4*)(be + hh + 4);
  float y[8];
#pragma unroll
  for (int e = 0; e < 4; e++) {
    y[e] = (v[e] - mu) * rstd * g0[e] + e0[e];
    y[4 + e] = (v[4 + e] - mu) * rstd * g1[e] + e1[e];
  }
  u32x4 o;
  o.x = cvtpk_bf16(y[0], y[1]);
  o.y = cvtpk_bf16(y[2], y[3]);
  o.z = cvtpk_bf16(y[4], y[5]);
  o.w = cvtpk_bf16(y[6], y[7]);
  *xo = o;
}

// ---------------- fused residual-add + LN: wave-per-row, 4 rows/block ----------------
__global__ __launch_bounds__(256) void ln_add_kernel(ushort_t* __restrict__ Xb,
                                                     const ushort_t* __restrict__ Y,
                                                     const float* __restrict__ g,
                                                     const float* __restrict__ be) {
  const int wv = threadIdx.x >> 6, lane = threadIdx.x & 63;
  const int row = blockIdx.x * 4 + wv;
  u32x4* xp = (u32x4*)(Xb + (size_t)row * H_) + lane;
  if (row >= MROWS) {
    u32x4 z = {0u, 0u, 0u, 0u};
    *xp = z;
    return;
  }
  const u32x4 xu = *xp;
  const u32x4 yu = *((const u32x4*)(Y + (size_t)row * H_) + lane);
  float v[8];
#pragma unroll
  for (int e = 0; e < 4; e++) {
    v[2 * e] = bflo(xu[e]) + bflo(yu[e]);
    v[2 * e + 1] = bfhi(xu[e]) + bfhi(yu[e]);
  }
  float sum = 0.f, sq = 0.f;
#pragma unroll
  for (int e = 0; e < 8; e++) {
    sum += v[e];
    sq += v[e] * v[e];
  }
#pragma unroll
  for (int o = 1; o < 64; o <<= 1) {
    sum += __shfl_xor(sum, o);
    sq += __shfl_xor(sq, o);
  }
  float mu = sum * (1.0f / H_);
  float var = sq * (1.0f / H_) - mu * mu;
  float rstd = rsqrtf(var + 1e-5f);
  const int hh = lane * 8;
  f32x4 g0 = *(const f32x4*)(g + hh), g1 = *(const f32x4*)(g + hh + 4);
  f32x4 e0 = *(const f32x4*)(be + hh), e1 = *(const f32x4*)(be + hh + 4);
  float y[8];
#pragma unroll
  for (int e = 0; e < 4; e++) {
    y[e] = (v[e] - mu) * rstd * g0[e] + e0[e];
    y[4 + e] = (v[4 + e] - mu) * rstd * g1[e] + e1[e];
  }
  // note: v is interleaved lo/hi pairs: v[2e]=elem hh+2e, v[2e+1]=elem hh+2e+1
  // recompute with correct mapping: elem index within lane block = 2e and 2e+1
  u32x4 o;
  {
    float yy[8];
#pragma unroll
    for (int e = 0; e < 4; e++) {
      float glo = g0[0], dummy = 0.f;
      (void)glo;
      (void)dummy;
    }
    // direct mapping: element j (0..7) value v[j]; gamma/beta element hh+j
    float gv[8] = {g0[0], g0[1], g0[2], g0[3], g1[0], g1[1], g1[2], g1[3]};
    float bv[8] = {e0[0], e0[1], e0[2], e0[3], e1[0], e1[1], e1[2], e1[3]};
#pragma unroll
    for (int j = 0; j < 8; j++) yy[j] = (v[j] - mu) * rstd * gv[j] + bv[j];
    o.x = cvtpk_bf16(yy[0], yy[1]);
    o.y = cvtpk_bf16(yy[2], yy[3]);
    o.z = cvtpk_bf16(yy[4], yy[5]);
    o.w = cvtpk_bf16(yy[6], yy[7]);
  }
  *xp = o;
}

// ---------------- GEMM v2: 512 threads / 8 waves, 128x128 tile, BK=64, dbuf LDS,
// counted vmcnt(4), XOR swizzle, chunked XCD mapping. 64KB LDS -> 2 blocks/CU.
template <int MODE>
__global__ __launch_bounds__(512, 2) void gemm_kernel(const ushort_t* __restrict__ A,
                                                      const ushort_t* __restrict__ W,
                                                      const float* __restrict__ bias,
                                                      void* __restrict__ o0,
                                                      void* __restrict__ o1,
                                                      void* __restrict__ o2, int Ntiles,
                                                      int K) {
  __shared__ ushort_t As[2][8192];
  __shared__ ushort_t Bs[2][8192];
  const int tid = threadIdx.x;
  const int job = (blockIdx.x & 7) * (gridDim.x >> 3) + (blockIdx.x >> 3);
  const int bx = job % Ntiles, by = job / Ntiles;
  const int m0 = by * 128, n0 = bx * 128;
  const int lane = tid & 63, wv = tid >> 6;
  const int wm = wv >> 2, wn = wv & 3;
  f32x4 acc[4][2] = {};

  const int srow = lane >> 3;
  const int kg = (lane & 7) ^ srow;
  const bool isA = wv < 4;
  const int wvr = isA ? wv : wv - 4;
  const ushort_t* gsrc[4];
#pragma unroll
  for (int g2 = 0; g2 < 4; g2++) {
    int row = wvr * 32 + g2 * 8 + srow;
    gsrc[g2] = (isA ? A + (size_t)(m0 + row) * K : W + (size_t)(n0 + row) * K) + kg * 8;
  }
  ushort_t* ldsd[2];
  ldsd[0] = (isA ? &As[0][0] : &Bs[0][0]) + wvr * 2048;
  ldsd[1] = (isA ? &As[1][0] : &Bs[1][0]) + wvr * 2048;

  const int NT = K >> 6;

#pragma unroll
  for (int g2 = 0; g2 < 4; g2++) gload16(gsrc[g2], ldsd[0] + g2 * 512);

  const int q = lane >> 4, lr = lane & 15;
  const int s0 = q ^ (lr & 7);
  const int s1 = (4 + q) ^ (lr & 7);

  auto compute_tile = [&](int cur) {
    bf16x8 af[4][2], bfr[2][2];
#pragma unroll
    for (int mi = 0; mi < 4; mi++) {
      const ushort_t* rp = &As[cur][(wm * 64 + mi * 16 + lr) * 64];
      af[mi][0] = *(const bf16x8*)(rp + s0 * 8);
      af[mi][1] = *(const bf16x8*)(rp + s1 * 8);
    }
#pragma unroll
    for (int ni = 0; ni < 2; ni++) {
      const ushort_t* rp = &Bs[cur][(wn * 32 + ni * 16 + lr) * 64];
      bfr[ni][0] = *(const bf16x8*)(rp + s0 * 8);
      bfr[ni][1] = *(const bf16x8*)(rp + s1 * 8);
    }
#pragma unroll
    for (int kc = 0; kc < 2; kc++)
#pragma unroll
      for (int mi = 0; mi < 4; mi++)
#pragma unroll
        for (int ni = 0; ni < 2; ni++)
          acc[mi][ni] =
              __builtin_amdgcn_mfma_f32_16x16x32_bf16(af[mi][kc], bfr[ni][kc], acc[mi][ni], 0, 0, 0);
  };

  for (int kt = 0; kt < NT - 1; kt++) {
    const int cur = kt & 1, nxt = cur ^ 1;
    const int k0n = (kt + 1) << 6;
#pragma unroll
    for (int g2 = 0; g2 < 4; g2++) gload16(gsrc[g2] + k0n, ldsd[nxt] + g2 * 512);
    asm volatile("s_waitcnt vmcnt(4)" ::: "memory");
    __builtin_amdgcn_s_barrier();
    asm volatile("" ::: "memory");
    compute_tile(cur);
    asm volatile("" ::: "memory");
    __builtin_amdgcn_s_barrier();
  }
  {
    asm volatile("s_waitcnt vmcnt(0)" ::: "memory");
    __builtin_amdgcn_s_barrier();
    asm volatile("" ::: "memory");
    compute_tile((NT - 1) & 1);
  }

#pragma unroll
  for (int mi = 0; mi < 4; mi++) {
    const int mbase = m0 + wm * 64 + mi * 16 + ((lane >> 4) << 2);
    const bool mok = mbase < MROWS;
    int bb = 0, lbase = 0;
    if (MODE == 0) {
      bb = mbase / L_;
      lbase = mbase - bb * L_;
    }
#pragma unroll
    for (int ni = 0; ni < 2; ni++) {
      const int n = n0 + wn * 32 + ni * 16 + (lane & 15);
      float v[4];
#pragma unroll
      for (int r = 0; r < 4; r++) v[r] = acc[mi][ni][r] + bias[n];
      if (MODE == 0) {
        if (mok) {
          const int which = n >> 9, nn = n & 511;
          const int hh = nn >> 6, d = nn & 63;
          if (which == 0) {
            ushort_t* o = (ushort_t*)o0 + (((size_t)(bb * NH_ + hh)) * LP_ + lbase) * DH_ + d;
#pragma unroll
            for (int r = 0; r < 4; r++)
              o[(size_t)r * DH_] = f2bf(v[r] * 0.18033688011112043f);
          } else if (which == 1) {
            ushort_t* o = (ushort_t*)o1 + (((size_t)(bb * NH_ + hh)) * LP_ + lbase) * DH_ + d;
#pragma unroll
            for (int r = 0; r < 4; r++) o[(size_t)r * DH_] = f2bf(v[r]);
          } else {
            u32x2 w2;
            w2.x = cvtpk_bf16(v[0], v[1]);
            w2.y = cvtpk_bf16(v[2], v[3]);
            *(u32x2*)((ushort_t*)o2 + (((size_t)(bb * NH_ + hh)) * DH_ + d) * LP_ + lbase) = w2;
          }
        }
      } else if (MODE == 2) {
        if (mok) {
#pragma unroll
          for (int r = 0; r < 4; r++)
            ((ushort_t*)o0)[(size_t)(mbase + r) * H_ + n] = f2bf(v[r]);
        }
      } else {
#pragma unroll
        for (int r = 0; r < 4; r++) {
          float ge = 0.5f * v[r] * (1.0f + erff(v[r] * 0.70710678f));
          ((ushort_t*)o0)[(size_t)(mbase + r) * HMLP + n] = f2bf(ge);
        }
      }
    }
  }
}

// ---------------- flash attention v7: KVBLK=64 — chunk PAIRS per barrier window ----
__global__ __launch_bounds__(256, 3) void attn_kernel(const ushort_t* __restrict__ Qb,
                                                      const ushort_t* __restrict__ Kb,
                                                      const ushort_t* __restrict__ Vt,
                                                      ushort_t* __restrict__ Ob) {
  __shared__ ushort_t Klds[2][4096];
  __shared__ ushort_t Vlds[2][4096];
  const int tid = threadIdx.x;
  const int lane = tid & 63, wv = tid >> 6;
  const int xcd = blockIdx.x & 7, slot = blockIdx.x >> 3;
  const int g = slot >> 3, bhi = slot & 7;
  const int bh = (bhi << 3) | xcd;
  const int t = 33 - 4 * g - wv;
  const bool active = (t >= 0);
  const int b = bh >> 3, h = bh & 7;
  const int qb = t * 32;
  const int lq = lane & 31, hi = lane >> 5;
  const int nk_own = active ? ((t == 33) ? 34 : (t + 1)) : 0;
  const int nkmax = (g == 0) ? 34 : (34 - 4 * g);  // always even
  const int nw = nkmax >> 1;
  const int cmask = (t == 0) ? -1 : (nk_own - 1);
  const int i = qb + lq;

  const ushort_t* Qp = Qb + (size_t)bh * LP_ * DH_;
  const ushort_t* Kp = Kb + (size_t)bh * LP_ * DH_;
  const ushort_t* Vp = Vt + (size_t)bh * DH_ * LP_;

  const ushort_t* KsrcB =
      Kp + (size_t)(8 * wv + (lane >> 3)) * DH_ + (((lane & 7) ^ ((lane >> 3) & 7)) * 8);
  const ushort_t* VsrcB =
      Vp + (size_t)(16 * wv + (lane >> 2)) * LP_ + (((lane & 3) ^ ((lane >> 3) & 3)) * 8);

  auto stageW = [&](int w, int buf) {
    const int c0 = 2 * w;
    gload16(KsrcB + (size_t)c0 * 2048, &Klds[buf][wv * 512]);
    gload16(KsrcB + (size_t)(c0 + 1) * 2048, &Klds[buf][2048 + wv * 512]);
    gload16(VsrcB + c0 * 32, &Vlds[buf][wv * 512]);
    gload16(VsrcB + (c0 + 1) * 32, &Vlds[buf][2048 + wv * 512]);
  };

  bf16x8 qf[4];
  if (active) {
#pragma unroll
    for (int dc = 0; dc < 4; dc++)
      qf[dc] = *(const bf16x8*)(Qp + (size_t)(qb + lq) * DH_ + dc * 16 + hi * 8);
  }

  stageW(0, 0);

  f32x16 o0 = {}, o1 = {};
  float lsum = 0.f;

  int koff[4], voff[4];
#pragma unroll
  for (int dc = 0; dc < 4; dc++) koff[dc] = lq * 64 + (((dc * 2 + hi) ^ (lq & 7)) * 8);
#pragma unroll
  for (int f = 0; f < 4; f++) {
    int dt = f >> 1, cc = f & 1;
    voff[f] = (dt * 32 + lq) * 32 + ((((cc * 2 + hi) ^ ((lq >> 1) & 3))) * 8);
  }

  auto tilestep = [&](int c, const ushort_t* Kbase, const ushort_t* Vbase) {
    bf16x8 kf[4], vf[4];
#pragma unroll
    for (int dc = 0; dc < 4; dc++) kf[dc] = *(const bf16x8*)&Kbase[koff[dc]];
#pragma unroll
    for (int f = 0; f < 4; f++) vf[f] = *(const bf16x8*)&Vbase[voff[f]];

    f32x16 s = {};
#pragma unroll
    for (int dc = 0; dc < 4; dc++)
      s = __builtin_amdgcn_mfma_f32_32x32x16_bf16(kf[dc], qf[dc], s, 0, 0, 0);
    float p[16];
    if (c == cmask) {
#pragma unroll
      for (int r = 0; r < 16; r++) {
        int jcol = c * 32 + (r & 3) + 8 * (r >> 2) + 4 * hi;
        bool ok = (jcol < L_) && ((jcol < M_) || (i >= M_ + INFO_) || (jcol <= i));
        p[r] = ok ? __builtin_amdgcn_exp2f(s[r]) : 0.f;
      }
    } else {
#pragma unroll
      for (int r = 0; r < 16; r++) p[r] = __builtin_amdgcn_exp2f(s[r]);
    }
    float u0 = (p[0] + p[1]) + (p[2] + p[3]);
    float u1 = (p[4] + p[5]) + (p[6] + p[7]);
    float u2 = (p[8] + p[9]) + (p[10] + p[11]);
    float u3 = (p[12] + p[13]) + (p[14] + p[15]);
    lsum += (u0 + u1) + (u2 + u3);
    bf16x8 pf[2];
#pragma unroll
    for (int cc = 0; cc < 2; cc++) {
      unsigned A01 = cvtpk_bf16(p[8 * cc + 0], p[8 * cc + 1]);
      unsigned A23 = cvtpk_bf16(p[8 * cc + 2], p[8 * cc + 3]);
      unsigned B45 = cvtpk_bf16(p[8 * cc + 4], p[8 * cc + 5]);
      unsigned B67 = cvtpk_bf16(p[8 * cc + 6], p[8 * cc + 7]);
      u32x2 r0 = __builtin_amdgcn_permlane32_swap(A01, B45, false, false);
      u32x2 r1 = __builtin_amdgcn_permlane32_swap(A23, B67, false, false);
      u32x4 w = {r0.x, r1.x, r0.y, r1.y};
      pf[cc] = __builtin_bit_cast(bf16x8, w);
    }
    o0 = __builtin_amdgcn_mfma_f32_32x32x16_bf16(vf[0], pf[0], o0, 0, 0, 0);
    o0 = __builtin_amdgcn_mfma_f32_32x32x16_bf16(vf[1], pf[1], o0, 0, 0, 0);
    o1 = __builtin_amdgcn_mfma_f32_32x32x16_bf16(vf[2], pf[0], o1, 0, 0, 0);
    o1 = __builtin_amdgcn_mfma_f32_32x32x16_bf16(vf[3], pf[1], o1, 0, 0, 0);
  };

  for (int w = 0; w < nw; w++) {
    const int cur = w & 1;
    if (w + 1 < nw) {
      stageW(w + 1, cur ^ 1);
      asm volatile("s_waitcnt vmcnt(4)" ::: "memory");
    } else {
      asm volatile("s_waitcnt vmcnt(0)" ::: "memory");
    }
    __builtin_amdgcn_s_barrier();
    asm volatile("" ::: "memory");

    const int c0 = 2 * w;
    if (c0 < nk_own) tilestep(c0, &Klds[cur][0], &Vlds[cur][0]);
    if (c0 + 1 < nk_own) tilestep(c0 + 1, &Klds[cur][2048], &Vlds[cur][2048]);

    asm volatile("" ::: "memory");
    __builtin_amdgcn_s_barrier();
  }

  if (active) {
    u32x2 tt = __builtin_amdgcn_permlane32_swap(__builtin_bit_cast(unsigned, lsum),
                                                __builtin_bit_cast(unsigned, lsum), false, false);
    lsum = __builtin_bit_cast(float, tt.x) + __builtin_bit_cast(float, tt.y);
    if (i < L_) {
      const float inv = 1.0f / lsum;
      ushort_t* orow = Ob + ((size_t)(b * L_ + i)) * H_ + h * DH_;
#pragma unroll
      for (int dt = 0; dt < 2; dt++) {
#pragma unroll
        for (int q2 = 0; q2 < 4; q2++) {
          float v0 = (dt ? o1[4 * q2 + 0] : o0[4 * q2 + 0]) * inv;
          float v1 = (dt ? o1[4 * q2 + 1] : o0[4 * q2 + 1]) * inv;
          float v2 = (dt ? o1[4 * q2 + 2] : o0[4 * q2 + 2]) * inv;
          float v3 = (dt ? o1[4 * q2 + 3] : o0[4 * q2 + 3]) * inv;
          int dbase = dt * 32 + 8 * q2 + 4 * hi;
          *(unsigned*)(orow + dbase) = cvtpk_bf16(v0, v1);
          *(unsigned*)(orow + dbase + 2) = cvtpk_bf16(v2, v3);
        }
      }
    }
  }
}

// ---------------- heads (bf16 residual input) ----------------
__global__ __launch_bounds__(64) void logits_kernel(const ushort_t* __restrict__ Xb,
                                                    const float* __restrict__ Wp,
                                                    const float* __restrict__ bp,
                                                    float* __restrict__ out) {
  const int bt = blockIdx.x;
  const int b = bt / T_, t = bt - b * T_;
  const int lane = threadIdx.x;
  const ushort_t* xr = Xb + ((size_t)(b * L_ + M_ + 3 * t + 1)) * H_ + lane * 8;
  u32x4 xv = *(const u32x4*)xr;
  float x0[8];
#pragma unroll
  for (int ii = 0; ii < 4; ii++) {
    unsigned u = xv[ii];
    x0[2 * ii] = bflo(u);
    x0[2 * ii + 1] = bfhi(u);
  }
#pragma unroll
  for (int a = 0; a < 4; a++) {
    const float* wr2 = Wp + (size_t)a * H_ + lane * 8;
    float p = 0.f;
#pragma unroll
    for (int ii = 0; ii < 8; ii++) p += x0[ii] * wr2[ii];
#pragma unroll
    for (int o = 1; o < 64; o <<= 1) p += __shfl_xor(p, o);
    if (lane == 0) out[(size_t)bt * 4 + a] = p + bp[a];
  }
}

__global__ __launch_bounds__(256) void memout_kernel(const ushort_t* __restrict__ Xb,
                                                     float* __restrict__ out) {
  int idx = blockIdx.x * 256 + threadIdx.x;
  if (idx < B_ * M_ * H_ / 2) {
    int e = idx * 2;
    int b = e >> 14;
    int rest = e & 16383;
    int r = rest >> 9;
    int hh = rest & 511;
    unsigned u = *(const unsigned*)&Xb[((size_t)(b * L_ + M_ + INFO_ + r)) * H_ + hh];
    out[e] = bflo(u);
    out[e + 1] = bfhi(u);
  }
}

// ---------------- launcher ----------------
extern "C" void kernel_launch(void* const* d_in, const int* in_sizes, int n_in, void* d_out,
                              int out_size, void* d_ws, size_t ws_size, hipStream_t stream) {
  const float* returns = (const float*)d_in[0];
  const float* actions = (const float*)d_in[1];
  const float* t_table = (const float*)d_in[2];
  const float* s_table = (const float*)d_in[3];
  const float* Wr = (const float*)d_in[4];
  const float* br = (const float*)d_in[5];
  const float* Wa = (const float*)d_in[6];
  const float* ba = (const float*)d_in[7];
  const float* ln_e_g = (const float*)d_in[8];
  const float* ln_e_b = (const float*)d_in[9];
  const float* read_mem = (const float*)d_in[10];
  const float* mem_tok = (const float*)d_in[11];
  const float* Wq = (const float*)d_in[12];
  const float* bq = (const float*)d_in[13];
  const float* Wk = (const float*)d_in[14];
  const float* bk = (const float*)d_in[15];
  const float* Wv = (const float*)d_in[16];
  const float* bv = (const float*)d_in[17];
  const float* Wo = (const float*)d_in[18];
  const float* bo = (const float*)d_in[19];
  const float* W1 = (const float*)d_in[20];
  const float* b1 = (const float*)d_in[21];
  const float* W2 = (const float*)d_in[22];
  const float* b2 = (const float*)d_in[23];
  const float* g1 = (const float*)d_in[24];
  const float* be1 = (const float*)d_in[25];
  const float* g2 = (const float*)d_in[26];
  const float* be2 = (const float*)d_in[27];
  const float* Wp = (const float*)d_in[28];
  const float* bp = (const float*)d_in[29];
  const int* states = (const int*)d_in[30];
  const int* timestep = (const int*)d_in[31];

  char* ws = (char*)d_ws;
  size_t off = 0;
  auto alloc = [&](size_t bytes) -> char* {
    char* p = ws + off;
    off += (bytes + 255) & ~(size_t)255;
    return p;
  };
  ushort_t* Xb = (ushort_t*)alloc((size_t)MPAD * H_ * 2);
  ushort_t* Y = (ushort_t*)alloc((size_t)MPAD * H_ * 2);
  ushort_t* Qb = (ushort_t*)alloc((size_t)B_ * NH_ * LP_ * DH_ * 2);
  ushort_t* Kb2 = (ushort_t*)alloc((size_t)B_ * NH_ * LP_ * DH_ * 2);
  ushort_t* Vt = (ushort_t*)alloc((size_t)B_ * NH_ * DH_ * LP_ * 2);
  ushort_t* Ob = (ushort_t*)alloc((size_t)MPAD * H_ * 2);
  ushort_t* Hm = (ushort_t*)alloc((size_t)MPAD * HMLP * 2);
  ushort_t* Wqkvb = (ushort_t*)alloc((size_t)4 * 1536 * 512 * 2);
  ushort_t* Wob = (ushort_t*)alloc((size_t)4 * 512 * 512 * 2);
  ushort_t* W1b = (ushort_t*)alloc((size_t)4 * 2048 * 512 * 2);
  ushort_t* W2b = (ushort_t*)alloc((size_t)4 * 512 * 2048 * 2);
  float* biascat = (float*)alloc((size_t)4 * 1536 * 4);

  zero_pads_kernel<<<128, 256, 0, stream>>>(Qb, Kb2, Vt, Ob);
  cvtqkv_kernel<<<512, 256, 0, stream>>>(Wq, Wk, Wv, Wqkvb);
  biascat_kernel<<<8, 256, 0, stream>>>(bq, bk, bv, biascat);
  cvt8_kernel<<<512, 256, 0, stream>>>(Wo, Wob, 4 * 512 * 512 / 8);
  cvt8_kernel<<<2048, 256, 0, stream>>>(W1, W1b, 4 * 2048 * 512 / 8);
  cvt8_kernel<<<2048, 256, 0, stream>>>(W2, W2b, 4 * 512 * 2048 / 8);

  embed_ln_kernel<<<MPAD / 4, 256, 0, stream>>>(returns, actions, t_table, s_table, Wr, br,
                                                Wa, ba, ln_e_g, ln_e_b, read_mem, mem_tok,
                                                states, timestep, Xb);

  for (int nb = 0; nb < 4; ++nb) {
    const size_t wo512 = (size_t)nb * 512 * 512;
    const size_t woqkv = (size_t)nb * 1536 * 512;
    const size_t wo1 = (size_t)nb * 2048 * 512;
    gemm_kernel<0><<<68 * 12, 512, 0, stream>>>(Xb, Wqkvb + woqkv, biascat + nb * 1536, Qb,
                                                Kb2, Vt, 12, 512);
    attn_kernel<<<576, 256, 0, stream>>>(Qb, Kb2, Vt, Ob);
    gemm_kernel<2><<<68 * 4, 512, 0, stream>>>(Ob, Wob + wo512, bo + nb * 512, Y, nullptr,
                                               nullptr, 4, 512);
    ln_add_kernel<<<MPAD / 4, 256, 0, stream>>>(Xb, Y, g1 + nb * 512, be1 + nb * 512);
    gemm_kernel<3><<<68 * 16, 512, 0, stream>>>(Xb, W1b + wo1, b1 + nb * 2048, Hm, nullptr,
                                                nullptr, 16, 512);
    gemm_kernel<2><<<68 * 4, 512, 0, stream>>>(Hm, W2b + wo1, b2 + nb * 512, Y, nullptr,
                                               nullptr, 4, 2048);
    ln_add_kernel<<<MPAD / 4, 256, 0, stream>>>(Xb, Y, g2 + nb * 512, be2 + nb * 512);
  }

  logits_kernel<<<B_ * T_, 64, 0, stream>>>(Xb, Wp, bp, (float*)d_out);
  memout_kernel<<<256, 256, 0, stream>>>(Xb, (float*)d_out + (size_t)B_ * T_ * 4);
}

// Round 16
// 560.929 us; speedup vs baseline: 1.4338x; 1.0077x over previous
//
#include <hip/hip_runtime.h>
#include <hip/hip_bf16.h>

typedef unsigned short ushort_t;
typedef __attribute__((ext_vector_type(8))) __bf16 bf16x8;
typedef __attribute__((ext_vector_type(4))) float f32x4;
typedef __attribute__((ext_vector_type(16))) float f32x16;
typedef __attribute__((ext_vector_type(2))) unsigned u32x2;
typedef __attribute__((ext_vector_type(4))) unsigned u32x4;

#define B_ 8
#define T_ 340
#define M_ 32
#define H_ 512
#define NH_ 8
#define DH_ 64
#define INFO_ 1020
#define L_ 1084
#define LP_ 1088
#define MROWS 8672
#define MPAD 8704
#define HMLP 2048

__device__ __forceinline__ ushort_t f2bf(float f) {
  unsigned u = __builtin_bit_cast(unsigned, f);
  unsigned r = (u + 0x7fffu + ((u >> 16) & 1u)) >> 16;
  return (ushort_t)r;
}

__device__ __forceinline__ float bflo(unsigned u) {
  return __builtin_bit_cast(float, u << 16);
}
__device__ __forceinline__ float bfhi(unsigned u) {
  return __builtin_bit_cast(float, u & 0xffff0000u);
}

__device__ __forceinline__ unsigned cvtpk_bf16(float lo, float hi) {
  unsigned r;
  asm volatile("v_cvt_pk_bf16_f32 %0, %1, %2" : "=v"(r) : "v"(lo), "v"(hi));
  return r;
}

__device__ __forceinline__ void gload16(const ushort_t* g, ushort_t* l) {
  __builtin_amdgcn_global_load_lds((const __attribute__((address_space(1))) unsigned*)g,
                                   (__attribute__((address_space(3))) unsigned*)l, 16, 0, 0);
}

// ---------------- zero pads (Q/K l-pads, Vt l-pads, Ob row-pads) ----------------
__global__ __launch_bounds__(256) void zero_pads_kernel(ushort_t* Qb, ushort_t* Kb,
                                                        ushort_t* Vt, ushort_t* Ob) {
  int idx = blockIdx.x * 256 + threadIdx.x;
  if (idx < 16384) {
    int bh = idx >> 8;
    int rest = idx & 255;
    int l = L_ + (rest >> 6);
    int d = rest & 63;
    size_t o = ((size_t)bh * LP_ + l) * DH_ + d;
    Qb[o] = 0;
    Kb[o] = 0;
    Vt[((size_t)bh * DH_ + d) * LP_ + l] = 0;
  } else if (idx < 32768) {
    int j = idx - 16384;
    Ob[(size_t)MROWS * H_ + j] = 0;
  }
}

__global__ __launch_bounds__(256) void biascat_kernel(const float* __restrict__ bq,
                                                      const float* __restrict__ bk,
                                                      const float* __restrict__ bv,
                                                      float* __restrict__ dst) {
  int i = blockIdx.x * 256 + threadIdx.x;
  if (i < 2048) {
    int nb = i >> 9, r = i & 511;
    float* d = dst + nb * 1536;
    d[r] = bq[i];
    d[512 + r] = bk[i];
    d[1024 + r] = bv[i];
  }
}

// ---------------- fused weight convert: QKV-concat + Wo + W1 + W2 in ONE launch ----
// item space (u32x4 granules of 8 bf16):
//   [0,131072)        : QKV concat (3 loads/stores per item)
//   [131072,262144)   : Wo
//   [262144,786432)   : W1
//   [786432,1310720)  : W2
__global__ __launch_bounds__(256) void wcvt_kernel(
    const float* __restrict__ q, const float* __restrict__ k, const float* __restrict__ v,
    ushort_t* __restrict__ qkvdst, const float* __restrict__ wo, ushort_t* __restrict__ wodst,
    const float* __restrict__ w1, ushort_t* __restrict__ w1dst,
    const float* __restrict__ w2, ushort_t* __restrict__ w2dst) {
  const int stride = gridDim.x * 256;
  for (int i = blockIdx.x * 256 + threadIdx.x; i < 1310720; i += stride) {
    if (i < 131072) {
      const int i8 = i;
      const int ii = i8 * 8;
      const int nb = ii >> 18;
      const int rem = ii & 262143;
      const size_t base8 = ((size_t)nb * 786432 + rem) >> 3;
      const float* srcs[3] = {q, k, v};
#pragma unroll
      for (int w = 0; w < 3; w++) {
        f32x4 a = ((const f32x4*)srcs[w])[2 * i8];
        f32x4 b = ((const f32x4*)srcs[w])[2 * i8 + 1];
        u32x4 o;
        o.x = cvtpk_bf16(a[0], a[1]);
        o.y = cvtpk_bf16(a[2], a[3]);
        o.z = cvtpk_bf16(b[0], b[1]);
        o.w = cvtpk_bf16(b[2], b[3]);
        ((u32x4*)qkvdst)[base8 + (size_t)w * 32768] = o;
      }
    } else {
      const float* src;
      ushort_t* dst;
      int j;
      if (i < 262144) {
        j = i - 131072;
        src = wo;
        dst = wodst;
      } else if (i < 786432) {
        j = i - 262144;
        src = w1;
        dst = w1dst;
      } else {
        j = i - 786432;
        src = w2;
        dst = w2dst;
      }
      f32x4 a = ((const f32x4*)src)[2 * j];
      f32x4 b = ((const f32x4*)src)[2 * j + 1];
      u32x4 o;
      o.x = cvtpk_bf16(a[0], a[1]);
      o.y = cvtpk_bf16(a[2], a[3]);
      o.z = cvtpk_bf16(b[0], b[1]);
      o.w = cvtpk_bf16(b[2], b[3]);
      ((u32x4*)dst)[j] = o;
    }
  }
}

// ---------------- embedding + initial LN: wave-per-row, 4 rows/block ----------------
__global__ __launch_bounds__(256) void embed_ln_kernel(
    const float* __restrict__ returns, const float* __restrict__ actions,
    const float* __restrict__ t_table, const float* __restrict__ s_table,
    const float* __restrict__ Wr, const float* __restrict__ br,
    const float* __restrict__ Wa, const float* __restrict__ ba,
    const float* __restrict__ g, const float* __restrict__ be,
    const float* __restrict__ read_mem, const float* __restrict__ mem_tok,
    const int* __restrict__ states, const int* __restrict__ timestep,
    ushort_t* __restrict__ Xb) {
  const int wv = threadIdx.x >> 6, lane = threadIdx.x & 63;
  const int row = blockIdx.x * 4 + wv;
  u32x4* xo = (u32x4*)(Xb + (size_t)row * H_) + lane;
  if (row >= MROWS) {
    u32x4 z = {0u, 0u, 0u, 0u};
    *xo = z;
    return;
  }
  const int b = row / L_, l = row - b * L_;
  const int hh = lane * 8;
  float v[8];
  if (l < M_) {
    const float* p = read_mem + (size_t)l * H_ + hh;
    f32x4 a = *(const f32x4*)p, c = *(const f32x4*)(p + 4);
#pragma unroll
    for (int e = 0; e < 4; e++) {
      v[e] = a[e];
      v[4 + e] = c[e];
    }
  } else if (l >= M_ + INFO_) {
    const float* p = mem_tok + (size_t)(l - M_ - INFO_) * H_ + hh;
    f32x4 a = *(const f32x4*)p, c = *(const f32x4*)(p + 4);
#pragma unroll
    for (int e = 0; e < 4; e++) {
      v[e] = a[e];
      v[4 + e] = c[e];
    }
  } else {
    int ii = l - M_;
    int t = ii / 3, c2 = ii - t * 3;
    int bt = b * T_ + t;
    if (c2 == 1) {
      const float* p = s_table + (size_t)states[bt] * H_ + hh;
      f32x4 a = *(const f32x4*)p, c = *(const f32x4*)(p + 4);
#pragma unroll
      for (int e = 0; e < 4; e++) {
        v[e] = a[e];
        v[4 + e] = c[e];
      }
    } else {
      const float* tp = t_table + (size_t)timestep[bt] * H_ + hh;
      f32x4 t0 = *(const f32x4*)tp, t1 = *(const f32x4*)(tp + 4);
      float sc = (c2 == 0) ? returns[bt] : actions[bt];
      const float* wp = (c2 == 0) ? Wr : Wa;
      const float* bp2 = (c2 == 0) ? br : ba;
      f32x4 w0 = *(const f32x4*)(wp + hh), w1 = *(const f32x4*)(wp + hh + 4);
      f32x4 b0 = *(const f32x4*)(bp2 + hh), b1 = *(const f32x4*)(bp2 + hh + 4);
#pragma unroll
      for (int e = 0; e < 4; e++) {
        v[e] = sc * w0[e] + b0[e] + t0[e];
        v[4 + e] = sc * w1[e] + b1[e] + t1[e];
      }
    }
  }
  float sum = 0.f, sq = 0.f;
#pragma unroll
  for (int e = 0; e < 8; e++) {
    sum += v[e];
    sq += v[e] * v[e];
  }
#pragma unroll
  for (int o = 1; o < 64; o <<= 1) {
    sum += __shfl_xor(sum, o);
    sq += __shfl_xor(sq, o);
  }
  float mu = sum * (1.0f / H_);
  float var = sq * (1.0f / H_) - mu * mu;
  float rstd = rsqrtf(var + 1e-5f);
  f32x4 g0 = *(const f32x4*)(g + hh), g1 = *(const f32x4*)(g + hh + 4);
  f32x4 e0 = *(const f32x4*)(be + hh), e1 = *(const f32x4*)(be + hh + 4);
  float y[8];
#pragma unroll
  for (int e = 0; e < 4; e++) {
    y[e] = (v[e] - mu) * rstd * g0[e] + e0[e];
    y[4 + e] = (v[4 + e] - mu) * rstd * g1[e] + e1[e];
  }
  u32x4 o;
  o.x = cvtpk_bf16(y[0], y[1]);
  o.y = cvtpk_bf16(y[2], y[3]);
  o.z = cvtpk_bf16(y[4], y[5]);
  o.w = cvtpk_bf16(y[6], y[7]);
  *xo = o;
}

// ---------------- fused residual-add + LN: wave-per-row, 4 rows/block ----------------
__global__ __launch_bounds__(256) void ln_add_kernel(ushort_t* __restrict__ Xb,
                                                     const ushort_t* __restrict__ Y,
                                                     const float* __restrict__ g,
                                                     const float* __restrict__ be) {
  const int wv = threadIdx.x >> 6, lane = threadIdx.x & 63;
  const int row = blockIdx.x * 4 + wv;
  u32x4* xp = (u32x4*)(Xb + (size_t)row * H_) + lane;
  if (row >= MROWS) {
    u32x4 z = {0u, 0u, 0u, 0u};
    *xp = z;
    return;
  }
  const u32x4 xu = *xp;
  const u32x4 yu = *((const u32x4*)(Y + (size_t)row * H_) + lane);
  float v[8];
#pragma unroll
  for (int e = 0; e < 4; e++) {
    v[2 * e] = bflo(xu[e]) + bflo(yu[e]);
    v[2 * e + 1] = bfhi(xu[e]) + bfhi(yu[e]);
  }
  float sum = 0.f, sq = 0.f;
#pragma unroll
  for (int e = 0; e < 8; e++) {
    sum += v[e];
    sq += v[e] * v[e];
  }
#pragma unroll
  for (int o = 1; o < 64; o <<= 1) {
    sum += __shfl_xor(sum, o);
    sq += __shfl_xor(sq, o);
  }
  float mu = sum * (1.0f / H_);
  float var = sq * (1.0f / H_) - mu * mu;
  float rstd = rsqrtf(var + 1e-5f);
  const int hh = lane * 8;
  f32x4 g0 = *(const f32x4*)(g + hh), g1 = *(const f32x4*)(g + hh + 4);
  f32x4 e0 = *(const f32x4*)(be + hh), e1 = *(const f32x4*)(be + hh + 4);
  float gv[8] = {g0[0], g0[1], g0[2], g0[3], g1[0], g1[1], g1[2], g1[3]};
  float bv[8] = {e0[0], e0[1], e0[2], e0[3], e1[0], e1[1], e1[2], e1[3]};
  float yy[8];
#pragma unroll
  for (int j = 0; j < 8; j++) yy[j] = (v[j] - mu) * rstd * gv[j] + bv[j];
  u32x4 o;
  o.x = cvtpk_bf16(yy[0], yy[1]);
  o.y = cvtpk_bf16(yy[2], yy[3]);
  o.z = cvtpk_bf16(yy[4], yy[5]);
  o.w = cvtpk_bf16(yy[6], yy[7]);
  *xp = o;
}

// ---------------- GEMM v2: 512 threads / 8 waves, 128x128 tile, BK=64, dbuf LDS,
// counted vmcnt(4), XOR swizzle, chunked XCD mapping. 64KB LDS -> 2 blocks/CU.
template <int MODE>
__global__ __launch_bounds__(512, 2) void gemm_kernel(const ushort_t* __restrict__ A,
                                                      const ushort_t* __restrict__ W,
                                                      const float* __restrict__ bias,
                                                      void* __restrict__ o0,
                                                      void* __restrict__ o1,
                                                      void* __restrict__ o2, int Ntiles,
                                                      int K) {
  __shared__ ushort_t As[2][8192];
  __shared__ ushort_t Bs[2][8192];
  const int tid = threadIdx.x;
  const int job = (blockIdx.x & 7) * (gridDim.x >> 3) + (blockIdx.x >> 3);
  const int bx = job % Ntiles, by = job / Ntiles;
  const int m0 = by * 128, n0 = bx * 128;
  const int lane = tid & 63, wv = tid >> 6;
  const int wm = wv >> 2, wn = wv & 3;
  f32x4 acc[4][2] = {};

  const int srow = lane >> 3;
  const int kg = (lane & 7) ^ srow;
  const bool isA = wv < 4;
  const int wvr = isA ? wv : wv - 4;
  const ushort_t* gsrc[4];
#pragma unroll
  for (int g2 = 0; g2 < 4; g2++) {
    int row = wvr * 32 + g2 * 8 + srow;
    gsrc[g2] = (isA ? A + (size_t)(m0 + row) * K : W + (size_t)(n0 + row) * K) + kg * 8;
  }
  ushort_t* ldsd[2];
  ldsd[0] = (isA ? &As[0][0] : &Bs[0][0]) + wvr * 2048;
  ldsd[1] = (isA ? &As[1][0] : &Bs[1][0]) + wvr * 2048;

  const int NT = K >> 6;

#pragma unroll
  for (int g2 = 0; g2 < 4; g2++) gload16(gsrc[g2], ldsd[0] + g2 * 512);

  const int q = lane >> 4, lr = lane & 15;
  const int s0 = q ^ (lr & 7);
  const int s1 = (4 + q) ^ (lr & 7);

  auto compute_tile = [&](int cur) {
    bf16x8 af[4][2], bfr[2][2];
#pragma unroll
    for (int mi = 0; mi < 4; mi++) {
      const ushort_t* rp = &As[cur][(wm * 64 + mi * 16 + lr) * 64];
      af[mi][0] = *(const bf16x8*)(rp + s0 * 8);
      af[mi][1] = *(const bf16x8*)(rp + s1 * 8);
    }
#pragma unroll
    for (int ni = 0; ni < 2; ni++) {
      const ushort_t* rp = &Bs[cur][(wn * 32 + ni * 16 + lr) * 64];
      bfr[ni][0] = *(const bf16x8*)(rp + s0 * 8);
      bfr[ni][1] = *(const bf16x8*)(rp + s1 * 8);
    }
#pragma unroll
    for (int kc = 0; kc < 2; kc++)
#pragma unroll
      for (int mi = 0; mi < 4; mi++)
#pragma unroll
        for (int ni = 0; ni < 2; ni++)
          acc[mi][ni] =
              __builtin_amdgcn_mfma_f32_16x16x32_bf16(af[mi][kc], bfr[ni][kc], acc[mi][ni], 0, 0, 0);
  };

  for (int kt = 0; kt < NT - 1; kt++) {
    const int cur = kt & 1, nxt = cur ^ 1;
    const int k0n = (kt + 1) << 6;
#pragma unroll
    for (int g2 = 0; g2 < 4; g2++) gload16(gsrc[g2] + k0n, ldsd[nxt] + g2 * 512);
    asm volatile("s_waitcnt vmcnt(4)" ::: "memory");
    __builtin_amdgcn_s_barrier();
    asm volatile("" ::: "memory");
    compute_tile(cur);
    asm volatile("" ::: "memory");
    __builtin_amdgcn_s_barrier();
  }
  {
    asm volatile("s_waitcnt vmcnt(0)" ::: "memory");
    __builtin_amdgcn_s_barrier();
    asm volatile("" ::: "memory");
    compute_tile((NT - 1) & 1);
  }

#pragma unroll
  for (int mi = 0; mi < 4; mi++) {
    const int mbase = m0 + wm * 64 + mi * 16 + ((lane >> 4) << 2);
    const bool mok = mbase < MROWS;
    int bb = 0, lbase = 0;
    if (MODE == 0) {
      bb = mbase / L_;
      lbase = mbase - bb * L_;
    }
#pragma unroll
    for (int ni = 0; ni < 2; ni++) {
      const int n = n0 + wn * 32 + ni * 16 + (lane & 15);
      float v[4];
#pragma unroll
      for (int r = 0; r < 4; r++) v[r] = acc[mi][ni][r] + bias[n];
      if (MODE == 0) {
        if (mok) {
          const int which = n >> 9, nn = n & 511;
          const int hh = nn >> 6, d = nn & 63;
          if (which == 0) {
            ushort_t* o = (ushort_t*)o0 + (((size_t)(bb * NH_ + hh)) * LP_ + lbase) * DH_ + d;
#pragma unroll
            for (int r = 0; r < 4; r++)
              o[(size_t)r * DH_] = f2bf(v[r] * 0.18033688011112043f);
          } else if (which == 1) {
            ushort_t* o = (ushort_t*)o1 + (((size_t)(bb * NH_ + hh)) * LP_ + lbase) * DH_ + d;
#pragma unroll
            for (int r = 0; r < 4; r++) o[(size_t)r * DH_] = f2bf(v[r]);
          } else {
            u32x2 w2;
            w2.x = cvtpk_bf16(v[0], v[1]);
            w2.y = cvtpk_bf16(v[2], v[3]);
            *(u32x2*)((ushort_t*)o2 + (((size_t)(bb * NH_ + hh)) * DH_ + d) * LP_ + lbase) = w2;
          }
        }
      } else if (MODE == 2) {
        if (mok) {
#pragma unroll
          for (int r = 0; r < 4; r++)
            ((ushort_t*)o0)[(size_t)(mbase + r) * H_ + n] = f2bf(v[r]);
        }
      } else {
#pragma unroll
        for (int r = 0; r < 4; r++) {
          float ge = 0.5f * v[r] * (1.0f + erff(v[r] * 0.70710678f));
          ((ushort_t*)o0)[(size_t)(mbase + r) * HMLP + n] = f2bf(ge);
        }
      }
    }
  }
}

// ---------------- flash attention v7: KVBLK=64 — chunk PAIRS per barrier window ----
__global__ __launch_bounds__(256, 3) void attn_kernel(const ushort_t* __restrict__ Qb,
                                                      const ushort_t* __restrict__ Kb,
                                                      const ushort_t* __restrict__ Vt,
                                                      ushort_t* __restrict__ Ob) {
  __shared__ ushort_t Klds[2][4096];
  __shared__ ushort_t Vlds[2][4096];
  const int tid = threadIdx.x;
  const int lane = tid & 63, wv = tid >> 6;
  const int xcd = blockIdx.x & 7, slot = blockIdx.x >> 3;
  const int g = slot >> 3, bhi = slot & 7;
  const int bh = (bhi << 3) | xcd;
  const int t = 33 - 4 * g - wv;
  const bool active = (t >= 0);
  const int b = bh >> 3, h = bh & 7;
  const int qb = t * 32;
  const int lq = lane & 31, hi = lane >> 5;
  const int nk_own = active ? ((t == 33) ? 34 : (t + 1)) : 0;
  const int nkmax = (g == 0) ? 34 : (34 - 4 * g);  // always even
  const int nw = nkmax >> 1;
  const int cmask = (t == 0) ? -1 : (nk_own - 1);
  const int i = qb + lq;

  const ushort_t* Qp = Qb + (size_t)bh * LP_ * DH_;
  const ushort_t* Kp = Kb + (size_t)bh * LP_ * DH_;
  const ushort_t* Vp = Vt + (size_t)bh * DH_ * LP_;

  const ushort_t* KsrcB =
      Kp + (size_t)(8 * wv + (lane >> 3)) * DH_ + (((lane & 7) ^ ((lane >> 3) & 7)) * 8);
  const ushort_t* VsrcB =
      Vp + (size_t)(16 * wv + (lane >> 2)) * LP_ + (((lane & 3) ^ ((lane >> 3) & 3)) * 8);

  auto stageW = [&](int w, int buf) {
    const int c0 = 2 * w;
    gload16(KsrcB + (size_t)c0 * 2048, &Klds[buf][wv * 512]);
    gload16(KsrcB + (size_t)(c0 + 1) * 2048, &Klds[buf][2048 + wv * 512]);
    gload16(VsrcB + c0 * 32, &Vlds[buf][wv * 512]);
    gload16(VsrcB + (c0 + 1) * 32, &Vlds[buf][2048 + wv * 512]);
  };

  bf16x8 qf[4];
  if (active) {
#pragma unroll
    for (int dc = 0; dc < 4; dc++)
      qf[dc] = *(const bf16x8*)(Qp + (size_t)(qb + lq) * DH_ + dc * 16 + hi * 8);
  }

  stageW(0, 0);

  f32x16 o0 = {}, o1 = {};
  float lsum = 0.f;

  int koff[4], voff[4];
#pragma unroll
  for (int dc = 0; dc < 4; dc++) koff[dc] = lq * 64 + (((dc * 2 + hi) ^ (lq & 7)) * 8);
#pragma unroll
  for (int f = 0; f < 4; f++) {
    int dt = f >> 1, cc = f & 1;
    voff[f] = (dt * 32 + lq) * 32 + ((((cc * 2 + hi) ^ ((lq >> 1) & 3))) * 8);
  }

  auto tilestep = [&](int c, const ushort_t* Kbase, const ushort_t* Vbase) {
    bf16x8 kf[4], vf[4];
#pragma unroll
    for (int dc = 0; dc < 4; dc++) kf[dc] = *(const bf16x8*)&Kbase[koff[dc]];
#pragma unroll
    for (int f = 0; f < 4; f++) vf[f] = *(const bf16x8*)&Vbase[voff[f]];

    f32x16 s = {};
#pragma unroll
    for (int dc = 0; dc < 4; dc++)
      s = __builtin_amdgcn_mfma_f32_32x32x16_bf16(kf[dc], qf[dc], s, 0, 0, 0);
    float p[16];
    if (c == cmask) {
#pragma unroll
      for (int r = 0; r < 16; r++) {
        int jcol = c * 32 + (r & 3) + 8 * (r >> 2) + 4 * hi;
        bool ok = (jcol < L_) && ((jcol < M_) || (i >= M_ + INFO_) || (jcol <= i));
        p[r] = ok ? __builtin_amdgcn_exp2f(s[r]) : 0.f;
      }
    } else {
#pragma unroll
      for (int r = 0; r < 16; r++) p[r] = __builtin_amdgcn_exp2f(s[r]);
    }
    float u0 = (p[0] + p[1]) + (p[2] + p[3]);
    float u1 = (p[4] + p[5]) + (p[6] + p[7]);
    float u2 = (p[8] + p[9]) + (p[10] + p[11]);
    float u3 = (p[12] + p[13]) + (p[14] + p[15]);
    lsum += (u0 + u1) + (u2 + u3);
    bf16x8 pf[2];
#pragma unroll
    for (int cc = 0; cc < 2; cc++) {
      unsigned A01 = cvtpk_bf16(p[8 * cc + 0], p[8 * cc + 1]);
      unsigned A23 = cvtpk_bf16(p[8 * cc + 2], p[8 * cc + 3]);
      unsigned B45 = cvtpk_bf16(p[8 * cc + 4], p[8 * cc + 5]);
      unsigned B67 = cvtpk_bf16(p[8 * cc + 6], p[8 * cc + 7]);
      u32x2 r0 = __builtin_amdgcn_permlane32_swap(A01, B45, false, false);
      u32x2 r1 = __builtin_amdgcn_permlane32_swap(A23, B67, false, false);
      u32x4 w = {r0.x, r1.x, r0.y, r1.y};
      pf[cc] = __builtin_bit_cast(bf16x8, w);
    }
    o0 = __builtin_amdgcn_mfma_f32_32x32x16_bf16(vf[0], pf[0], o0, 0, 0, 0);
    o0 = __builtin_amdgcn_mfma_f32_32x32x16_bf16(vf[1], pf[1], o0, 0, 0, 0);
    o1 = __builtin_amdgcn_mfma_f32_32x32x16_bf16(vf[2], pf[0], o1, 0, 0, 0);
    o1 = __builtin_amdgcn_mfma_f32_32x32x16_bf16(vf[3], pf[1], o1, 0, 0, 0);
  };

  for (int w = 0; w < nw; w++) {
    const int cur = w & 1;
    if (w + 1 < nw) {
      stageW(w + 1, cur ^ 1);
      asm volatile("s_waitcnt vmcnt(4)" ::: "memory");
    } else {
      asm volatile("s_waitcnt vmcnt(0)" ::: "memory");
    }
    __builtin_amdgcn_s_barrier();
    asm volatile("" ::: "memory");

    const int c0 = 2 * w;
    if (c0 < nk_own) tilestep(c0, &Klds[cur][0], &Vlds[cur][0]);
    if (c0 + 1 < nk_own) tilestep(c0 + 1, &Klds[cur][2048], &Vlds[cur][2048]);

    asm volatile("" ::: "memory");
    __builtin_amdgcn_s_barrier();
  }

  if (active) {
    u32x2 tt = __builtin_amdgcn_permlane32_swap(__builtin_bit_cast(unsigned, lsum),
                                                __builtin_bit_cast(unsigned, lsum), false, false);
    lsum = __builtin_bit_cast(float, tt.x) + __builtin_bit_cast(float, tt.y);
    if (i < L_) {
      const float inv = 1.0f / lsum;
      ushort_t* orow = Ob + ((size_t)(b * L_ + i)) * H_ + h * DH_;
#pragma unroll
      for (int dt = 0; dt < 2; dt++) {
#pragma unroll
        for (int q2 = 0; q2 < 4; q2++) {
          float v0 = (dt ? o1[4 * q2 + 0] : o0[4 * q2 + 0]) * inv;
          float v1 = (dt ? o1[4 * q2 + 1] : o0[4 * q2 + 1]) * inv;
          float v2 = (dt ? o1[4 * q2 + 2] : o0[4 * q2 + 2]) * inv;
          float v3 = (dt ? o1[4 * q2 + 3] : o0[4 * q2 + 3]) * inv;
          int dbase = dt * 32 + 8 * q2 + 4 * hi;
          *(unsigned*)(orow + dbase) = cvtpk_bf16(v0, v1);
          *(unsigned*)(orow + dbase + 2) = cvtpk_bf16(v2, v3);
        }
      }
    }
  }
}

// ---------------- heads: wave-per-token logits (4 tokens/block) ----------------
__global__ __launch_bounds__(256) void logits_kernel(const ushort_t* __restrict__ Xb,
                                                     const float* __restrict__ Wp,
                                                     const float* __restrict__ bp,
                                                     float* __restrict__ out) {
  const int wv = threadIdx.x >> 6, lane = threadIdx.x & 63;
  const int bt = blockIdx.x * 4 + wv;
  if (bt >= B_ * T_) return;
  const int b = bt / T_, t = bt - b * T_;
  const ushort_t* xr = Xb + ((size_t)(b * L_ + M_ + 3 * t + 1)) * H_ + lane * 8;
  u32x4 xv = *(const u32x4*)xr;
  float x0[8];
#pragma unroll
  for (int ii = 0; ii < 4; ii++) {
    unsigned u = xv[ii];
    x0[2 * ii] = bflo(u);
    x0[2 * ii + 1] = bfhi(u);
  }
#pragma unroll
  for (int a = 0; a < 4; a++) {
    const float* wr2 = Wp + (size_t)a * H_ + lane * 8;
    float p = 0.f;
#pragma unroll
    for (int ii = 0; ii < 8; ii++) p += x0[ii] * wr2[ii];
#pragma unroll
    for (int o = 1; o < 64; o <<= 1) p += __shfl_xor(p, o);
    if (lane == 0) out[(size_t)bt * 4 + a] = p + bp[a];
  }
}

__global__ __launch_bounds__(256) void memout_kernel(const ushort_t* __restrict__ Xb,
                                                     float* __restrict__ out) {
  int idx = blockIdx.x * 256 + threadIdx.x;
  if (idx < B_ * M_ * H_ / 2) {
    int e = idx * 2;
    int b = e >> 14;
    int rest = e & 16383;
    int r = rest >> 9;
    int hh = rest & 511;
    unsigned u = *(const unsigned*)&Xb[((size_t)(b * L_ + M_ + INFO_ + r)) * H_ + hh];
    out[e] = bflo(u);
    out[e + 1] = bfhi(u);
  }
}

// ---------------- launcher ----------------
extern "C" void kernel_launch(void* const* d_in, const int* in_sizes, int n_in, void* d_out,
                              int out_size, void* d_ws, size_t ws_size, hipStream_t stream) {
  const float* returns = (const float*)d_in[0];
  const float* actions = (const float*)d_in[1];
  const float* t_table = (const float*)d_in[2];
  const float* s_table = (const float*)d_in[3];
  const float* Wr = (const float*)d_in[4];
  const float* br = (const float*)d_in[5];
  const float* Wa = (const float*)d_in[6];
  const float* ba = (const float*)d_in[7];
  const float* ln_e_g = (const float*)d_in[8];
  const float* ln_e_b = (const float*)d_in[9];
  const float* read_mem = (const float*)d_in[10];
  const float* mem_tok = (const float*)d_in[11];
  const float* Wq = (const float*)d_in[12];
  const float* bq = (const float*)d_in[13];
  const float* Wk = (const float*)d_in[14];
  const float* bk = (const float*)d_in[15];
  const float* Wv = (const float*)d_in[16];
  const float* bv = (const float*)d_in[17];
  const float* Wo = (const float*)d_in[18];
  const float* bo = (const float*)d_in[19];
  const float* W1 = (const float*)d_in[20];
  const float* b1 = (const float*)d_in[21];
  const float* W2 = (const float*)d_in[22];
  const float* b2 = (const float*)d_in[23];
  const float* g1 = (const float*)d_in[24];
  const float* be1 = (const float*)d_in[25];
  const float* g2 = (const float*)d_in[26];
  const float* be2 = (const float*)d_in[27];
  const float* Wp = (const float*)d_in[28];
  const float* bp = (const float*)d_in[29];
  const int* states = (const int*)d_in[30];
  const int* timestep = (const int*)d_in[31];

  char* ws = (char*)d_ws;
  size_t off = 0;
  auto alloc = [&](size_t bytes) -> char* {
    char* p = ws + off;
    off += (bytes + 255) & ~(size_t)255;
    return p;
  };
  ushort_t* Xb = (ushort_t*)alloc((size_t)MPAD * H_ * 2);
  ushort_t* Y = (ushort_t*)alloc((size_t)MPAD * H_ * 2);
  ushort_t* Qb = (ushort_t*)alloc((size_t)B_ * NH_ * LP_ * DH_ * 2);
  ushort_t* Kb2 = (ushort_t*)alloc((size_t)B_ * NH_ * LP_ * DH_ * 2);
  ushort_t* Vt = (ushort_t*)alloc((size_t)B_ * NH_ * DH_ * LP_ * 2);
  ushort_t* Ob = (ushort_t*)alloc((size_t)MPAD * H_ * 2);
  ushort_t* Hm = (ushort_t*)alloc((size_t)MPAD * HMLP * 2);
  ushort_t* Wqkvb = (ushort_t*)alloc((size_t)4 * 1536 * 512 * 2);
  ushort_t* Wob = (ushort_t*)alloc((size_t)4 * 512 * 512 * 2);
  ushort_t* W1b = (ushort_t*)alloc((size_t)4 * 2048 * 512 * 2);
  ushort_t* W2b = (ushort_t*)alloc((size_t)4 * 512 * 2048 * 2);
  float* biascat = (float*)alloc((size_t)4 * 1536 * 4);

  zero_pads_kernel<<<128, 256, 0, stream>>>(Qb, Kb2, Vt, Ob);
  biascat_kernel<<<8, 256, 0, stream>>>(bq, bk, bv, biascat);
  wcvt_kernel<<<2048, 256, 0, stream>>>(Wq, Wk, Wv, Wqkvb, Wo, Wob, W1, W1b, W2, W2b);

  embed_ln_kernel<<<MPAD / 4, 256, 0, stream>>>(returns, actions, t_table, s_table, Wr, br,
                                                Wa, ba, ln_e_g, ln_e_b, read_mem, mem_tok,
                                                states, timestep, Xb);

  for (int nb = 0; nb < 4; ++nb) {
    const size_t wo512 = (size_t)nb * 512 * 512;
    const size_t woqkv = (size_t)nb * 1536 * 512;
    const size_t wo1 = (size_t)nb * 2048 * 512;
    gemm_kernel<0><<<68 * 12, 512, 0, stream>>>(Xb, Wqkvb + woqkv, biascat + nb * 1536, Qb,
                                                Kb2, Vt, 12, 512);
    attn_kernel<<<576, 256, 0, stream>>>(Qb, Kb2, Vt, Ob);
    gemm_kernel<2><<<68 * 4, 512, 0, stream>>>(Ob, Wob + wo512, bo + nb * 512, Y, nullptr,
                                               nullptr, 4, 512);
    ln_add_kernel<<<MPAD / 4, 256, 0, stream>>>(Xb, Y, g1 + nb * 512, be1 + nb * 512);
    gemm_kernel<3><<<68 * 16, 512, 0, stream>>>(Xb, W1b + wo1, b1 + nb * 2048, Hm, nullptr,
                                                nullptr, 16, 512);
    gemm_kernel<2><<<68 * 4, 512, 0, stream>>>(Hm, W2b + wo1, b2 + nb * 512, Y, nullptr,
                                               nullptr, 4, 2048);
    ln_add_kernel<<<MPAD / 4, 256, 0, stream>>>(Xb, Y, g2 + nb * 512, be2 + nb * 512);
  }

  logits_kernel<<<680, 256, 0, stream>>>(Xb, Wp, bp, (float*)d_out);
  memout_kernel<<<256, 256, 0, stream>>>(Xb, (float*)d_out + (size_t)B_ * T_ * 4);
}